// Round 7
// baseline (733.849 us; speedup 1.0000x reference)
//
#include <hip/hip_runtime.h>
#include <math.h>
#include <stdint.h>

#define DEV static __device__ __forceinline__

typedef __bf16 bf16x8 __attribute__((ext_vector_type(8)));
typedef __bf16 bf16x4v __attribute__((ext_vector_type(4)));
typedef float f32x4 __attribute__((ext_vector_type(4)));

// problem dims
constexpr int Nn = 2048, Ll = 2048, Ee = 1024, Hh = 16;
constexpr float SCALE = 0.0625f;   // (4C)^-0.5 = 1/16

// ---------------- workspace layout (bytes) ----------------
constexpr size_t OFF_XN   = 0;                    // [4096][1024] bf16
constexpr size_t OFF_YNK  = 8388608;
constexpr size_t OFF_YNV  = 16777216;
constexpr size_t OFF_H12  = 25165824;             // [4096][4096] bf16
constexpr size_t OFF_H3   = 58720256;             // [4096][2048] bf16
constexpr size_t OFF_X1   = 75497472;             // [4096][1024] bf16
constexpr size_t OFF_X2   = 83886080;
constexpr size_t OFF_Y1   = 92274688;
constexpr size_t OFF_QWS  = 100663296;            // [B][H][N][256] bf16, pre-swizzled
constexpr size_t OFF_KWS  = 134217728;            // [B][H][L][256] bf16, pre-swizzled
constexpr size_t OFF_VWS  = 167772160;            // vT: [B*H][64][2048] bf16
constexpr size_t OFF_DNV  = 176160768;            // f32 [B*H*N]
constexpr size_t OFF_YPT  = 176422912;            // ypT [B][4][2048] bf16
constexpr size_t OFF_MSK  = 176685056;            // mask bf16 [2048][2048]
constexpr size_t OFF_AVZ  = 185073664;            // [4096][1088] bf16
constexpr size_t OFF_W1122= 193986560;            // [4096][1024] bf16 (w11 ; w21)
constexpr size_t OFF_W12  = 202375168;
constexpr size_t OFF_W22  = 206569472;
constexpr size_t OFF_WK1  = 210763776;
constexpr size_t OFF_WK2  = 214958080;
constexpr size_t OFF_WV   = 219152384;
constexpr size_t OFF_WP   = 221249536;            // [1024][1088] bf16
constexpr size_t OFF_EM   = 223477760;            // em bf16, 268 MB

DEV void gl2l(const void* g, void* l) {
  __builtin_amdgcn_global_load_lds((const __attribute__((address_space(1))) void*)g,
                                   (__attribute__((address_space(3))) void*)l, 16, 0, 0);
}

// exact-erf GELU via Abramowitz-Stegun 7.1.26 (|eps|<1.5e-7, way below bf16)
DEV float gelu_f(float v) {
  float x = v * 0.70710678118654752f;
  float ax = fabsf(x);
  float t = 1.f / fmaf(0.3275911f, ax, 1.f);
  float y = t * fmaf(t, fmaf(t, fmaf(t, fmaf(t, 1.061405429f, -1.453152027f),
                                     1.421413741f), -0.284496736f), 0.254829592f);
  float er = 1.f - y * __expf(-x * x);
  er = (x < 0.f) ? -er : er;
  return 0.5f * v * (1.f + er);
}

// ---------------- merged prep: weights + proj + mask + ypT ----------------
__launch_bounds__(256)
__global__ void prep_all(const float* __restrict__ s0, const float* __restrict__ s1,
                         const float* __restrict__ s2, const float* __restrict__ s3,
                         const float* __restrict__ s4, const float* __restrict__ s5,
                         const float* __restrict__ s6,
                         __bf16* __restrict__ d0, __bf16* __restrict__ d1,
                         __bf16* __restrict__ d2, __bf16* __restrict__ d3,
                         __bf16* __restrict__ d4, __bf16* __restrict__ d5,
                         __bf16* __restrict__ d6,
                         const float* __restrict__ pw1, const float* __restrict__ pw2,
                         __bf16* __restrict__ wp,
                         const float* __restrict__ mask, __bf16* __restrict__ mb,
                         const float* __restrict__ yp, __bf16* __restrict__ ypT) {
  int u = blockIdx.x * 256 + threadIdx.x;
  if (u < 3407872) {                       // 7 weight arrays, float4 units
    int seg = u >> 19, r = u & 524287;
    const float* s; __bf16* d;
    if      (seg == 0) { s = s0; d = d0; }
    else if (seg == 1) { s = s1; d = d1; }
    else if (seg == 2) { s = s2; d = d2; }
    else if (seg == 3) { s = s3; d = d3; }
    else if (seg == 4) { s = s4; d = d4; }
    else if (seg == 5) { s = s5; d = d5; }
    else               { s = s6; d = d6; }
    float4 v = ((const float4*)s)[r];
    bf16x4v o; o[0]=(__bf16)v.x; o[1]=(__bf16)v.y; o[2]=(__bf16)v.z; o[3]=(__bf16)v.w;
    ((bf16x4v*)d)[r] = o;
  } else if (u < 3686400) {                // fused proj weight [1024][1088]
    int p = u - 3407872;
    int row = p / 272, c4 = p - row * 272;
    float4 v = (c4 < 256) ? ((const float4*)pw1)[row * 256 + c4]
                          : ((const float4*)pw2)[row * 16 + (c4 - 256)];
    bf16x4v o; o[0]=(__bf16)v.x; o[1]=(__bf16)v.y; o[2]=(__bf16)v.z; o[3]=(__bf16)v.w;
    *(bf16x4v*)(wp + (size_t)row * 1088 + (c4 << 2)) = o;
  } else if (u < 4734976) {                // mask f32 -> bf16
    int q = u - 3686400;
    float4 v = ((const float4*)mask)[q];
    bf16x4v o; o[0]=(__bf16)v.x; o[1]=(__bf16)v.y; o[2]=(__bf16)v.z; o[3]=(__bf16)v.w;
    ((bf16x4v*)mb)[q] = o;
  } else {                                 // ypT [B][4][L]
    int t0 = (u - 4734976) << 2;
    #pragma unroll
    for (int k = 0; k < 4; k++) {
      int i = t0 + k;
      int b = i >> 13, d = (i >> 11) & 3, l = i & 2047;
      ypT[i] = (__bf16)yp[(((size_t)b << 11) + l) * 4 + d];
    }
  }
}

// ---------------- merged LayerNorm: x -> xn ; y -> (ynk, ynv) ----------------
__launch_bounds__(256)
__global__ void ln_all(const float* __restrict__ x, const float* __restrict__ y,
                       const float* __restrict__ qg, const float* __restrict__ qb,
                       const float* __restrict__ kg, const float* __restrict__ kb,
                       const float* __restrict__ vg, const float* __restrict__ vb,
                       __bf16* __restrict__ xn, __bf16* __restrict__ ynk,
                       __bf16* __restrict__ ynv) {
  const int t = blockIdx.x, tid = threadIdx.x;
  const bool isx = t < 4096;
  const int row = isx ? t : t - 4096;
  const float* src = (isx ? x : y) + (size_t)row * Ee;
  const float4 v = ((const float4*)src)[tid];
  float s = v.x + v.y + v.z + v.w;
  float q = v.x*v.x + v.y*v.y + v.z*v.z + v.w*v.w;
  #pragma unroll
  for (int o = 32; o > 0; o >>= 1) { s += __shfl_down(s, o); q += __shfl_down(q, o); }
  __shared__ float ls[4], lq[4];
  if ((tid & 63) == 0) { ls[tid >> 6] = s; lq[tid >> 6] = q; }
  __syncthreads();
  s = ls[0] + ls[1] + ls[2] + ls[3];
  q = lq[0] + lq[1] + lq[2] + lq[3];
  const float mu = s * (1.f / Ee);
  const float rstd = rsqrtf(q * (1.f / Ee) - mu * mu + 1e-5f);
  const int e0 = tid << 2;
  float h0 = (v.x - mu) * rstd, h1 = (v.y - mu) * rstd,
        h2 = (v.z - mu) * rstd, h3 = (v.w - mu) * rstd;
  if (isx) {
    bf16x4v o;
    o[0] = (__bf16)(h0 * qg[e0]   + qb[e0]);
    o[1] = (__bf16)(h1 * qg[e0+1] + qb[e0+1]);
    o[2] = (__bf16)(h2 * qg[e0+2] + qb[e0+2]);
    o[3] = (__bf16)(h3 * qg[e0+3] + qb[e0+3]);
    *(bf16x4v*)(xn + (size_t)row * Ee + e0) = o;
  } else {
    bf16x4v ok, ov;
    ok[0] = (__bf16)(h0 * kg[e0]   + kb[e0]);
    ok[1] = (__bf16)(h1 * kg[e0+1] + kb[e0+1]);
    ok[2] = (__bf16)(h2 * kg[e0+2] + kb[e0+2]);
    ok[3] = (__bf16)(h3 * kg[e0+3] + kb[e0+3]);
    ov[0] = (__bf16)(h0 * vg[e0]   + vb[e0]);
    ov[1] = (__bf16)(h1 * vg[e0+1] + vb[e0+1]);
    ov[2] = (__bf16)(h2 * vg[e0+2] + vb[e0+2]);
    ov[3] = (__bf16)(h3 * vg[e0+3] + vb[e0+3]);
    *(bf16x4v*)(ynk + (size_t)row * Ee + e0) = ok;
    *(bf16x4v*)(ynv + (size_t)row * Ee + e0) = ov;
  }
}

// ================= 256x256-tile GEMM core, counted-vmcnt 2-phase (T4) =================
// Raw s_barrier pairs + s_waitcnt vmcnt(4): this tile's 4 prefetch loads stay in flight
// across the barrier; the wait retires exactly the previous tile's 4 loads (vmcnt is
// oldest-first, m135). sched_barrier(0) fences ds_read hoisting across the barrier.
#define GEMM256_CORE(A_, lda_, W_, ldw_, K_)                                          \
  const int w = tid >> 6, lane = tid & 63, g = lane >> 4, li = lane & 15;             \
  const int wm = (w >> 2) << 7, wn = (w & 3) << 6;                                    \
  f32x4 acc[8][4];                                                                    \
  _Pragma("unroll")                                                                   \
  for (int i = 0; i < 8; i++)                                                         \
    _Pragma("unroll")                                                                 \
    for (int j = 0; j < 4; j++) acc[i][j] = (f32x4)0.f;                               \
  auto stage = [&](int buf, int kt) {                                                 \
    const int col0 = kt << 5;                                                         \
    _Pragma("unroll")                                                                 \
    for (int jj = 0; jj < 2; jj++) {                                                  \
      int c = (jj << 9) + tid;                                                        \
      int row = c >> 2, sl = c & 3;                                                   \
      int col = col0 + ((sl ^ (row & 3)) << 3);                                       \
      gl2l(A_ + (size_t)(m0 + row) * lda_ + col, As[buf] + ((c - lane) << 3));        \
      gl2l(W_ + (size_t)(n0 + row) * ldw_ + col, Bs[buf] + ((c - lane) << 3));        \
    }                                                                                 \
  };                                                                                  \
  const int NT = (K_) >> 5;                                                           \
  stage(0, 0);                                                                        \
  for (int kt = 0; kt < NT; kt++) {                                                   \
    const int cur = kt & 1;                                                           \
    if (kt + 1 < NT) {                                                                \
      stage(cur ^ 1, kt + 1);                                                         \
      asm volatile("s_waitcnt vmcnt(4)" ::: "memory");                                \
    } else {                                                                          \
      asm volatile("s_waitcnt vmcnt(0)" ::: "memory");                                \
    }                                                                                 \
    __builtin_amdgcn_s_barrier();                                                     \
    __builtin_amdgcn_sched_barrier(0);                                                \
    bf16x8 af[8], bw[4];                                                              \
    _Pragma("unroll")                                                                 \
    for (int i = 0; i < 8; i++) {                                                     \
      int ra = wm + (i << 4) + li;                                                    \
      af[i] = *(const bf16x8*)(As[cur] + ra * 32 + ((g ^ (ra & 3)) << 3));            \
    }                                                                                 \
    _Pragma("unroll")                                                                 \
    for (int j = 0; j < 4; j++) {                                                     \
      int rb = wn + (j << 4) + li;                                                    \
      bw[j] = *(const bf16x8*)(Bs[cur] + rb * 32 + ((g ^ (rb & 3)) << 3));            \
    }                                                                                 \
    _Pragma("unroll")                                                                 \
    for (int i = 0; i < 8; i++)                                                       \
      _Pragma("unroll")                                                               \
      for (int j = 0; j < 4; j++)                                                     \
        acc[i][j] = __builtin_amdgcn_mfma_f32_16x16x32_bf16(af[i], bw[j], acc[i][j], 0, 0, 0); \
    asm volatile("s_waitcnt lgkmcnt(0)" ::: "memory");                                \
    __builtin_amdgcn_sched_barrier(0);                                                \
    __builtin_amdgcn_s_barrier();                                                     \
  }

// Launch A: seg0 = xn@w1122 (N=4096, gelu, split bias) -> h12; seg1 = ynk@wk1 (N=2048, gelu) -> h3
__launch_bounds__(512, 2)
__global__ void gemm_mlp1(const __bf16* __restrict__ xn, const __bf16* __restrict__ ynk,
                          const __bf16* __restrict__ w1122, const __bf16* __restrict__ wk1,
                          const float* __restrict__ qb1, const float* __restrict__ qb2,
                          const float* __restrict__ kb1,
                          __bf16* __restrict__ h12, __bf16* __restrict__ h3) {
  __shared__ __align__(16) __bf16 As[2][256 * 32];
  __shared__ __align__(16) __bf16 Bs[2][256 * 32];
  const int tid = threadIdx.x, bid = blockIdx.x;
  const bool seg1 = bid >= 256;
  const __bf16* A; const __bf16* W; __bf16* out; int m0, n0, ldc;
  if (!seg1) { A = xn;  W = w1122; out = h12; ldc = 4096; m0 = (bid >> 4) << 8; n0 = (bid & 15) << 8; }
  else { int rr = bid - 256; A = ynk; W = wk1; out = h3; ldc = 2048; m0 = (rr >> 3) << 8; n0 = (rr & 7) << 8; }
  GEMM256_CORE(A, 1024, W, 1024, 1024)
  #pragma unroll
  for (int j = 0; j < 4; j++) {
    int n = n0 + wn + (j << 4) + li;
    float bias = seg1 ? kb1[n] : ((n < 2048) ? qb1[n] : qb2[n - 2048]);
    #pragma unroll
    for (int i = 0; i < 8; i++) {
      #pragma unroll
      for (int r = 0; r < 4; r++) {
        int m = m0 + wm + (i << 4) + (g << 2) + r;
        out[(size_t)m * ldc + n] = (__bf16)gelu_f(acc[i][j][r] + bias);
      }
    }
  }
}

// Launch B: seg0 x1=h1@w12, seg1 x2=h2@w22, seg2 y1=h3@wk2 (K=2048), seg3 vT=ynv@wv (K=1024)
__launch_bounds__(512, 2)
__global__ void gemm_mlp2(const __bf16* __restrict__ h12, const __bf16* __restrict__ h3,
                          const __bf16* __restrict__ ynv,
                          const __bf16* __restrict__ w12, const __bf16* __restrict__ w22,
                          const __bf16* __restrict__ wk2, const __bf16* __restrict__ wv,
                          const float* __restrict__ bx1, const float* __restrict__ bx2,
                          const float* __restrict__ by1, const float* __restrict__ bv,
                          __bf16* __restrict__ x1, __bf16* __restrict__ x2,
                          __bf16* __restrict__ y1, __bf16* __restrict__ vT) {
  __shared__ __align__(16) __bf16 As[2][256 * 32];
  __shared__ __align__(16) __bf16 Bs[2][256 * 32];
  const int tid = threadIdx.x, bid = blockIdx.x;
  const int seg = bid >> 6, rr = bid & 63;
  const int m0 = (rr >> 2) << 8, n0 = (rr & 3) << 8;
  const __bf16* A; const __bf16* W; const float* bias; __bf16* out; int lda, K;
  if      (seg == 0) { A = h12;        lda = 4096; W = w12; bias = bx1; out = x1; K = 2048; }
  else if (seg == 1) { A = h12 + 2048; lda = 4096; W = w22; bias = bx2; out = x2; K = 2048; }
  else if (seg == 2) { A = h3;         lda = 2048; W = wk2; bias = by1; out = y1; K = 2048; }
  else               { A = ynv;        lda = 1024; W = wv;  bias = bv;  out = vT; K = 1024; }
  GEMM256_CORE(A, lda, W, K, K)
  #pragma unroll
  for (int j = 0; j < 4; j++) {
    int n = n0 + wn + (j << 4) + li;
    float bs = bias[n];
    #pragma unroll
    for (int i = 0; i < 8; i++) {
      #pragma unroll
      for (int r = 0; r < 4; r++) {
        int m = m0 + wm + (i << 4) + (g << 2) + r;
        float v = acc[i][j][r] + bs;
        if (seg == 3) {        // vT: [B*H][64][2048]
          int bb = m >> 11, l = m & 2047, hh = n >> 6, cc = n & 63;
          vT[(((size_t)(bb * Hh + hh) * 64 + cc) << 11) + l] = (__bf16)v;
        } else {
          out[(size_t)m * 1024 + n] = (__bf16)v;
        }
      }
    }
  }
}

// ---------------- merged build q + k (vectorized swizzled stores) ----------------
__launch_bounds__(256)
__global__ void build_qk(const __bf16* __restrict__ x1, const __bf16* __restrict__ x2,
                         const float* __restrict__ xp,
                         const __bf16* __restrict__ y1, const float* __restrict__ yp,
                         const float* __restrict__ pw1, const float* __restrict__ pb1,
                         const float* __restrict__ pw2, const float* __restrict__ pb2,
                         __bf16* __restrict__ q_ws, __bf16* __restrict__ k_ws) {
  const bool isq = blockIdx.x < 2048;
  const int bid = isq ? blockIdx.x : blockIdx.x - 2048;
  const int t = (bid << 1) + (threadIdx.x >> 7);
  const int tl = threadIdx.x & 127;
  const int b = t >> 11, n = t & 2047;
  const int hh = tl >> 3, ch = tl & 7;
  const int e0 = (hh << 6) + (ch << 3);
  const float* pos = isq ? xp : yp;
  const float p0 = pos[(size_t)t*4], p1 = pos[(size_t)t*4+1],
              p2 = pos[(size_t)t*4+2], p3 = pos[(size_t)t*4+3];
  bf16x8 o0, o1, o2, o3;
  if (isq) {
    bf16x8 v1 = *(const bf16x8*)(x1 + (size_t)t * Ee + e0);
    bf16x8 v2 = *(const bf16x8*)(x2 + (size_t)t * Ee + e0);
    #pragma unroll
    for (int sub = 0; sub < 8; sub++) {
      int e = e0 + sub;
      float a1 = pw1[e*4]*p0 + pw1[e*4+1]*p1 + pw1[e*4+2]*p2 + pw1[e*4+3]*p3 + pb1[e];
      float a2 = pw2[e*4]*p0 + pw2[e*4+1]*p1 + pw2[e*4+2]*p2 + pw2[e*4+3]*p3 + pb2[e];
      float s1, c1, s2, c2;
      __sincosf(a1, &s1, &c1); __sincosf(a2, &s2, &c2);
      float xv1 = (float)v1[sub], xv2 = (float)v2[sub];
      o0[sub] = (__bf16)(xv1 * c1); o1[sub] = (__bf16)(xv1 * s1);
      o2[sub] = (__bf16)(xv2 * c2); o3[sub] = (__bf16)(xv2 * s2);
    }
  } else {
    bf16x8 v1 = *(const bf16x8*)(y1 + (size_t)t * Ee + e0);
    #pragma unroll
    for (int sub = 0; sub < 8; sub++) {
      int e = e0 + sub;
      float a1 = pw1[e*4]*p0 + pw1[e*4+1]*p1 + pw1[e*4+2]*p2 + pw1[e*4+3]*p3;
      float a2 = pw2[e*4]*p0 + pw2[e*4+1]*p1 + pw2[e*4+2]*p2 + pw2[e*4+3]*p3;
      float s1, c1, s2, c2;
      __sincosf(a1, &s1, &c1); __sincosf(a2, &s2, &c2);
      float yv = (float)v1[sub];
      o0[sub] = (__bf16)(yv * c1); o1[sub] = (__bf16)(yv * s1);
      o2[sub] = (__bf16)c2;        o3[sub] = (__bf16)s2;
    }
  }
  const int k = n & 7, bc = ch ^ k;
  __bf16* base = (isq ? q_ws : k_ws) + ((((size_t)b * Hh + hh) * Nn + n) << 8);
  *(bf16x8*)(base + ((bc          ) << 3)) = o0;
  *(bf16x8*)(base + (((8  ^ k) ^ ch) << 3)) = o1;
  *(bf16x8*)(base + (((16 ^ k) ^ ch) << 3)) = o2;
  *(bf16x8*)(base + (((24 ^ k) ^ ch) << 3)) = o3;
}

// ---------------- fused flash attention (single QK^T pass, no max) ----------------
// 256 q-rows/block, 8 waves x 32 rows (2 frags), KVBLK=32, double-buffered staging.
// grid = 256 blocks = exactly 1/CU. K-fragment LDS reads shared across both row-frags.
__launch_bounds__(512, 1)
__global__ void attn_fused(const __bf16* __restrict__ q_ws, const __bf16* __restrict__ k_ws,
                           const __bf16* __restrict__ vT_ws, const __bf16* __restrict__ ypT_g,
                           const __bf16* __restrict__ mask_bf, const float* __restrict__ xp,
                           __bf16* __restrict__ em_g, float* __restrict__ dinv_g,
                           __bf16* __restrict__ avz) {
  __shared__ __align__(16) __bf16 kq[2][32 * 256];   // 32 KB
  __shared__ __align__(16) __bf16 ms[2][256 * 32];   // 32 KB
  __shared__ __align__(16) __bf16 vt[2][64 * 40];    // 10 KB
  __shared__ __align__(16) __bf16 pT[256 * 40];      // 20 KB
  __shared__ __align__(16) __bf16 ypl[2][16 * 40];   // 2.5 KB
  const int tid = threadIdx.x, w = tid >> 6, lane = tid & 63, g = lane >> 4, li = lane & 15;
  const int logical = ((blockIdx.x & 7) << 5) + (blockIdx.x >> 3);  // XCD-chunked
  const int bh = logical >> 3, nt = logical & 7;
  const int b = bh >> 4, h = bh & 15;
  const int n0 = nt << 8;
  const __bf16* qb = q_ws + (((size_t)bh * Nn + n0) << 8);
  const __bf16* kb = k_ws + (((size_t)bh * Ll) << 8);
  const __bf16* vb = vT_ws + ((size_t)bh << 17);
  const __bf16* yb = ypT_g + ((size_t)b << 13);
  const __bf16* mb = mask_bf + ((size_t)n0 << 11);

  // Q fragments (32 rows/wave, 2 frags) direct from pre-swizzled global
  bf16x8 aq[2][8];
  #pragma unroll
  for (int rf = 0; rf < 2; rf++) {
    const int nloc = (w << 5) + (rf << 4) + li;
    #pragma unroll
    for (int s = 0; s < 8; s++)
      aq[rf][s] = *(const bf16x8*)(qb + ((size_t)nloc << 8) + ((((s << 2) + g) ^ (nloc & 7)) << 3));
  }
  // zero ypl rows 4..15 (both buffers)
  for (int i = tid; i < 960; i += 512) {
    int buf = i / 480, idx = i - buf * 480;
    ypl[buf][160 + idx] = (__bf16)0.f;
  }
  // prologue: stage tile 0
  {
    const int vc = tid >> 3, vl = (tid & 7) << 2;
    bf16x4v vreg = *(const bf16x4v*)(vb + ((size_t)vc << 11) + vl);
    bf16x4v ypreg;
    if (tid < 32) ypreg = *(const bf16x4v*)(yb + ((size_t)(tid >> 3) << 11) + ((tid & 7) << 2));
    #pragma unroll
    for (int j = 0; j < 2; j++) {
      int c = (j << 9) + tid;
      gl2l(kb + (size_t)(c >> 5) * 256 + ((c & 31) << 3), kq[0] + ((c - lane) << 3));
      gl2l(mb + (size_t)(c >> 2) * 2048 + ((c & 3) << 3), ms[0] + ((c - lane) << 3));
    }
    *(bf16x4v*)(vt[0] + vc * 40 + vl) = vreg;
    if (tid < 32) *(bf16x4v*)(ypl[0] + (tid >> 3) * 40 + ((tid & 7) << 2)) = ypreg;
  }
  __syncthreads();

  float se[2][4], te[2][4];
  f32x4 accv[2][4], accp[2];
  #pragma unroll
  for (int rf = 0; rf < 2; rf++) {
    #pragma unroll
    for (int r = 0; r < 4; r++) { se[rf][r] = 0.f; te[rf][r] = 0.f; }
    #pragma unroll
    for (int cb = 0; cb < 4; cb++) accv[rf][cb] = (f32x4)0.f;
    accp[rf] = (f32x4)0.f;
  }

  for (int t = 0; t < 64; ++t) {
    const int l0 = t << 5, cur = t & 1, nxt = cur ^ 1;
    const bool more = (t < 63);
    bf16x4v vreg, ypreg;
    if (more) {
      const int l1 = l0 + 32;
      vreg = *(const bf16x4v*)(vb + ((size_t)(tid >> 3) << 11) + l1 + ((tid & 7) << 2));
      if (tid < 32) ypreg = *(const bf16x4v*)(yb + ((size_t)(tid >> 3) << 11) + l1 + ((tid & 7) << 2));
      #pragma unroll
      for (int j = 0; j < 2; j++) {
        int c = (j << 9) + tid;
        gl2l(kb + (size_t)(l1 + (c >> 5)) * 256 + ((c & 31) << 3), kq[nxt] + ((c - lane) << 3));
        gl2l(mb + (size_t)(c >> 2) * 2048 + l1 + ((c & 3) << 3), ms[nxt] + ((c - lane) << 3));
      }
    }
    // QK^T: K-fragment reads shared across both row-fragments (16 b128 for 32 MFMA)
    f32x4 Cs[2][2];
    Cs[0][0] = (f32x4)0.f; Cs[0][1] = (f32x4)0.f; Cs[1][0] = (f32x4)0.f; Cs[1][1] = (f32x4)0.f;
    #pragma unroll
    for (int lb = 0; lb < 2; lb++) {
      const int kr = (lb << 4) + li;
      #pragma unroll
      for (int s = 0; s < 8; s++) {
        bf16x8 bk = *(const bf16x8*)(kq[cur] + kr * 256 + ((((s << 2) + g) ^ (kr & 7)) << 3));
        Cs[0][lb] = __builtin_amdgcn_mfma_f32_16x16x32_bf16(aq[0][s], bk, Cs[0][lb], 0, 0, 0);
        Cs[1][lb] = __builtin_amdgcn_mfma_f32_16x16x32_bf16(aq[1][s], bk, Cs[1][lb], 0, 0, 0);
      }
    }
    // exp + mask (LDS) + sums + pT
    #pragma unroll
    for (int rf = 0; rf < 2; rf++) {
      #pragma unroll
      for (int lb = 0; lb < 2; lb++) {
        #pragma unroll
        for (int r = 0; r < 4; r++) {
          const int row = (w << 5) + (rf << 4) + (g << 2) + r;
          float e = __expf(Cs[rf][lb][r] * SCALE);
          float mkv = (float)ms[cur][row * 32 + (lb << 4) + li];
          float em = e * mkv;
          se[rf][r] += e; te[rf][r] += em;
          pT[row * 40 + (lb << 4) + li] = (__bf16)em;
        }
      }
    }
    asm volatile("s_waitcnt lgkmcnt(0)" ::: "memory");
    __builtin_amdgcn_sched_barrier(0);
    // em global store (2 b128 per lane; wave-private rows)
    #pragma unroll
    for (int j = 0; j < 2; j++) {
      int q = (j << 6) + lane;
      int row = q >> 2, ch = q & 3;
      bf16x8 pv = *(const bf16x8*)(pT + ((w << 5) + row) * 40 + (ch << 3));
      *(bf16x8*)(em_g + ((size_t)bh << 22) + ((size_t)(n0 + (w << 5) + row) << 11) + l0 + (ch << 3)) = pv;
    }
    // PV + attn@yp (V/yp frags shared across row-frags)
    bf16x8 vv[4];
    #pragma unroll
    for (int cb = 0; cb < 4; cb++)
      vv[cb] = *(const bf16x8*)(vt[cur] + ((cb << 4) + li) * 40 + (g << 3));
    bf16x8 yy = *(const bf16x8*)(ypl[cur] + li * 40 + (g << 3));
    #pragma unroll
    for (int rf = 0; rf < 2; rf++) {
      bf16x8 pa = *(const bf16x8*)(pT + ((w << 5) + (rf << 4) + li) * 40 + (g << 3));
      #pragma unroll
      for (int cb = 0; cb < 4; cb++)
        accv[rf][cb] = __builtin_amdgcn_mfma_f32_16x16x32_bf16(pa, vv[cb], accv[rf][cb], 0, 0, 0);
      accp[rf] = __builtin_amdgcn_mfma_f32_16x16x32_bf16(pa, yy, accp[rf], 0, 0, 0);
    }
    if (more) {
      *(bf16x4v*)(vt[nxt] + (tid >> 3) * 40 + ((tid & 7) << 2)) = vreg;
      if (tid < 32) *(bf16x4v*)(ypl[nxt] + (tid >> 3) * 40 + ((tid & 7) << 2)) = ypreg;
    }
    __syncthreads();
  }

  // epilogue: reduce sums, write dinv + avz
  #pragma unroll
  for (int rf = 0; rf < 2; rf++) {
    #pragma unroll
    for (int r = 0; r < 4; r++) {
      float s = se[rf][r], tt = te[rf][r];
      #pragma unroll
      for (int o = 1; o < 16; o <<= 1) { s += __shfl_xor(s, o); tt += __shfl_xor(tt, o); }
      float dinv = 1.f / (tt + 1e-8f * s);
      const int n = n0 + (w << 5) + (rf << 4) + (g << 2) + r;
      if (li == 0) dinv_g[((size_t)bh << 11) + n] = dinv;
      #pragma unroll
      for (int cb = 0; cb < 4; cb++)
        avz[((size_t)b * Nn + n) * 1088 + (h << 6) + (cb << 4) + li] = (__bf16)(accv[rf][cb][r] * dinv);
      if (li < 4) {
        float z = accp[rf][r] * dinv - xp[(((size_t)b * Nn + n) << 2) + li];
        avz[((size_t)b * Nn + n) * 1088 + 1024 + (h << 2) + li] = (__bf16)z;
      }
    }
  }
}

// ---------------- merged finalize + output projection ----------------
// blocks 0..511: 128x64-tile GEMM out0 = avz @ wp^T + b1 + b2 (counted vmcnt(3))
// blocks 512..2559: attn = em * dinv streaming + xp passthrough.
// The 9 GF of projection MFMA hides under the 805 MB BW-bound stream.
__launch_bounds__(256)
__global__ void fin_proj(const __bf16* __restrict__ A, const __bf16* __restrict__ W,
                         const float* __restrict__ bias1, const float* __restrict__ bias2,
                         float* __restrict__ out,
                         const __bf16* __restrict__ em_g, const float* __restrict__ dinv_g,
                         float* __restrict__ attn_out,
                         const float* __restrict__ xp, float* __restrict__ xp_out) {
  constexpr int N = 1024, K = 1088;
  __shared__ __align__(16) __bf16 As[2][128 * 32];
  __shared__ __align__(16) __bf16 Bs[2][64 * 32];
  const int tid = threadIdx.x;
  if (blockIdx.x >= 512) {
    // ---- streaming finalize segment ----
    const int sbid = blockIdx.x - 512;
    if (sbid < 64) {
      int idx = sbid * 256 + tid;   // 16384 float4 units
      ((float4*)xp_out)[idx] = ((const float4*)xp)[idx];
    }
    for (size_t i8 = sbid * 256ul + tid; i8 < 16777216ul; i8 += 524288ul) {
      bf16x8 v = ((const bf16x8*)em_g)[i8];
      float dv = dinv_g[i8 >> 8];
      float4 o0, o1;
      o0.x = (float)v[0] * dv; o0.y = (float)v[1] * dv; o0.z = (float)v[2] * dv; o0.w = (float)v[3] * dv;
      o1.x = (float)v[4] * dv; o1.y = (float)v[5] * dv; o1.z = (float)v[6] * dv; o1.w = (float)v[7] * dv;
      ((float4*)attn_out)[i8 * 2]     = o0;
      ((float4*)attn_out)[i8 * 2 + 1] = o1;
    }
    return;
  }
  // ---- GEMM segment ----
  const int w = tid >> 6, lane = tid & 63, g = lane >> 4, li = lane & 15;
  const int bt = blockIdx.x >> 4;
  const int m0 = bt << 7, n0 = (blockIdx.x & 15) << 6;
  const int wm = (w >> 1) << 6, wn = (w & 1) << 5;
  f32x4 acc[4][2];
  #pragma unroll
  for (int i = 0; i < 4; i++) { acc[i][0] = (f32x4)0.f; acc[i][1] = (f32x4)0.f; }
  auto stage = [&](int buf, int kt) {
    const int col0 = kt << 5;
    #pragma unroll
    for (int j = 0; j < 2; j++) {
      int c = (j << 8) + tid;
      int row = c >> 2, sl = c & 3;
      int col = col0 + ((sl ^ (row & 3)) << 3);
      gl2l(A + (size_t)(m0 + row) * K + col, As[buf] + ((c - lane) << 3));
    }
    {
      int c = tid;
      int row = c >> 2, sl = c & 3;
      int col = col0 + ((sl ^ (row & 3)) << 3);
      gl2l(W + (size_t)(n0 + row) * K + col, Bs[buf] + ((c - lane) << 3));
    }
  };
  const int NT = K >> 5;   // 34
  stage(0, 0);
  for (int kt = 0; kt < NT; kt++) {
    const int cur = kt & 1;
    if (kt + 1 < NT) {
      stage(cur ^ 1, kt + 1);
      asm volatile("s_waitcnt vmcnt(3)" ::: "memory");
    } else {
      asm volatile("s_waitcnt vmcnt(0)" ::: "memory");
    }
    __builtin_amdgcn_s_barrier();
    __builtin_amdgcn_sched_barrier(0);
    bf16x8 af[4], bw[2];
    #pragma unroll
    for (int i = 0; i < 4; i++) {
      int ra = wm + (i << 4) + li;
      af[i] = *(const bf16x8*)(As[cur] + ra * 32 + ((g ^ (ra & 3)) << 3));
    }
    #pragma unroll
    for (int j = 0; j < 2; j++) {
      int rb = wn + (j << 4) + li;
      bw[j] = *(const bf16x8*)(Bs[cur] + rb * 32 + ((g ^ (rb & 3)) << 3));
    }
    #pragma unroll
    for (int i = 0; i < 4; i++)
      #pragma unroll
      for (int j = 0; j < 2; j++)
        acc[i][j] = __builtin_amdgcn_mfma_f32_16x16x32_bf16(af[i], bw[j], acc[i][j], 0, 0, 0);
    asm volatile("s_waitcnt lgkmcnt(0)" ::: "memory");
    __builtin_amdgcn_sched_barrier(0);
    __builtin_amdgcn_s_barrier();
  }
  #pragma unroll
  for (int j = 0; j < 2; j++) {
    int n = n0 + wn + (j << 4) + li;
    float bias = bias1[n] + bias2[n];
    #pragma unroll
    for (int i = 0; i < 4; i++) {
      #pragma unroll
      for (int r = 0; r < 4; r++) {
        int m = m0 + wm + (i << 4) + (g << 2) + r;
        out[(size_t)m * N + n] = acc[i][j][r] + bias;
      }
    }
  }
}

// ---------------- host ----------------
extern "C" void kernel_launch(void* const* d_in, const int* in_sizes, int n_in,
                              void* d_out, int out_size, void* d_ws, size_t ws_size,
                              hipStream_t stream) {
  (void)in_sizes; (void)n_in; (void)out_size; (void)ws_size;
  const float* x       = (const float*)d_in[0];
  const float* xp      = (const float*)d_in[1];
  const float* y       = (const float*)d_in[2];
  const float* yp      = (const float*)d_in[3];
  const float* mask    = (const float*)d_in[4];
  const float* p_w1    = (const float*)d_in[5];
  const float* p_b1    = (const float*)d_in[6];
  const float* p_w2    = (const float*)d_in[7];
  const float* p_b2    = (const float*)d_in[8];
  const float* q_ln_g  = (const float*)d_in[9];
  const float* q_ln_b  = (const float*)d_in[10];
  const float* q_m1_w1 = (const float*)d_in[11];
  const float* q_m1_b1 = (const float*)d_in[12];
  const float* q_m1_w2 = (const float*)d_in[13];
  const float* q_m1_b2 = (const float*)d_in[14];
  const float* q_m2_w1 = (const float*)d_in[15];
  const float* q_m2_b1 = (const float*)d_in[16];
  const float* q_m2_w2 = (const float*)d_in[17];
  const float* q_m2_b2 = (const float*)d_in[18];
  const float* k_ln_g  = (const float*)d_in[19];
  const float* k_ln_b  = (const float*)d_in[20];
  const float* k_m1_w1 = (const float*)d_in[21];
  const float* k_m1_b1 = (const float*)d_in[22];
  const float* k_m1_w2 = (const float*)d_in[23];
  const float* k_m1_b2 = (const float*)d_in[24];
  const float* v_ln_g  = (const float*)d_in[25];
  const float* v_ln_b  = (const float*)d_in[26];
  const float* v_w     = (const float*)d_in[27];
  const float* v_b     = (const float*)d_in[28];
  const float* proj1_w = (const float*)d_in[29];
  const float* proj1_b = (const float*)d_in[30];
  const float* proj2_w = (const float*)d_in[31];
  const float* proj2_b = (const float*)d_in[32];

  char* ws = (char*)d_ws;
  __bf16* xn    = (__bf16*)(ws + OFF_XN);
  __bf16* ynk   = (__bf16*)(ws + OFF_YNK);
  __bf16* ynv   = (__bf16*)(ws + OFF_YNV);
  __bf16* h12   = (__bf16*)(ws + OFF_H12);
  __bf16* h3    = (__bf16*)(ws + OFF_H3);
  __bf16* x1    = (__bf16*)(ws + OFF_X1);
  __bf16* x2    = (__bf16*)(ws + OFF_X2);
  __bf16* y1    = (__bf16*)(ws + OFF_Y1);
  __bf16* q_ws  = (__bf16*)(ws + OFF_QWS);
  __bf16* k_ws  = (__bf16*)(ws + OFF_KWS);
  __bf16* vT_ws = (__bf16*)(ws + OFF_VWS);
  float*  dinv  = (float*)(ws + OFF_DNV);
  __bf16* ypT   = (__bf16*)(ws + OFF_YPT);
  __bf16* mskb  = (__bf16*)(ws + OFF_MSK);
  __bf16* avz   = (__bf16*)(ws + OFF_AVZ);
  __bf16* w1122 = (__bf16*)(ws + OFF_W1122);
  __bf16* w12   = (__bf16*)(ws + OFF_W12);
  __bf16* w22   = (__bf16*)(ws + OFF_W22);
  __bf16* wk1   = (__bf16*)(ws + OFF_WK1);
  __bf16* wk2   = (__bf16*)(ws + OFF_WK2);
  __bf16* wv    = (__bf16*)(ws + OFF_WV);
  __bf16* wp    = (__bf16*)(ws + OFF_WP);
  __bf16* em    = (__bf16*)(ws + OFF_EM);

  float* out0     = (float*)d_out;
  float* attn_out = out0 + (size_t)4194304;
  float* xp_out   = out0 + (size_t)138412032;

  // 1. prep (weights + fused proj + mask bf16 + ypT)
  prep_all<<<18512, 256, 0, stream>>>(q_m1_w1, q_m2_w1, q_m1_w2, q_m2_w2, k_m1_w1, k_m1_w2, v_w,
                                      w1122, w1122 + 2097152, w12, w22, wk1, wk2, wv,
                                      proj1_w, proj2_w, wp, mask, mskb, yp, ypT);
  // 2. layernorms
  ln_all<<<8192, 256, 0, stream>>>(x, y, q_ln_g, q_ln_b, k_ln_g, k_ln_b, v_ln_g, v_ln_b,
                                   xn, ynk, ynv);
  // 3. mlp stage 1 (merged, 256^2 tiles, GELU, counted-vmcnt pipeline)
  gemm_mlp1<<<384, 512, 0, stream>>>(xn, ynk, w1122, wk1, q_m1_b1, q_m2_b1, k_m1_b1, h12, h3);
  // 4. mlp stage 2 + V projection (merged, 256^2 tiles)
  gemm_mlp2<<<256, 512, 0, stream>>>(h12, h3, ynv, w12, w22, wk2, wv,
                                     q_m1_b2, q_m2_b2, k_m1_b2, v_b, x1, x2, y1, vT_ws);
  // 5. q/k assembly (merged; pos-encoder matmul + trig, vectorized swizzled stores)
  build_qk<<<4096, 256, 0, stream>>>(x1, x2, xp, y1, yp, p_w1, p_b1, p_w2, p_b2, q_ws, k_ws);
  // 6. fused flash attention (256 q-rows/block, 1 block/CU)
  attn_fused<<<256, 512, 0, stream>>>(q_ws, k_ws, vT_ws, ypT, mskb, xp, em, dinv, avz);
  // 7. merged finalize (attn = em*dinv + xp passthrough) + output projection
  fin_proj<<<2560, 256, 0, stream>>>(avz, wp, proj1_b, proj2_b, out0,
                                     em, dinv, attn_out, xp, xp_out);
}

// Round 8
// 697.543 us; speedup vs baseline: 1.0520x; 1.0520x over previous
//
#include <hip/hip_runtime.h>
#include <math.h>
#include <stdint.h>

#define DEV static __device__ __forceinline__

typedef __bf16 bf16x8 __attribute__((ext_vector_type(8)));
typedef __bf16 bf16x4v __attribute__((ext_vector_type(4)));
typedef float f32x4 __attribute__((ext_vector_type(4)));

// problem dims
constexpr int Nn = 2048, Ll = 2048, Ee = 1024, Hh = 16;
constexpr float SCALE = 0.0625f;   // (4C)^-0.5 = 1/16

// ---------------- workspace layout (bytes) ----------------
constexpr size_t OFF_XN   = 0;                    // [4096][1024] bf16
constexpr size_t OFF_YNK  = 8388608;
constexpr size_t OFF_YNV  = 16777216;
constexpr size_t OFF_H12  = 25165824;             // [4096][4096] bf16
constexpr size_t OFF_H3   = 58720256;             // [4096][2048] bf16
constexpr size_t OFF_X1   = 75497472;             // [4096][1024] bf16
constexpr size_t OFF_X2   = 83886080;
constexpr size_t OFF_Y1   = 92274688;
constexpr size_t OFF_QWS  = 100663296;            // [B][H][N][256] bf16, pre-swizzled
constexpr size_t OFF_KWS  = 134217728;            // [B][H][L][256] bf16, pre-swizzled
constexpr size_t OFF_VWS  = 167772160;            // vT: [B*H][64][2048] bf16
constexpr size_t OFF_DNV  = 176160768;            // f32 [B*H*N]
constexpr size_t OFF_YPT  = 176422912;            // ypT [B][4][2048] bf16
constexpr size_t OFF_MSK  = 176685056;            // mask bf16 [2048][2048]
constexpr size_t OFF_AVZ  = 185073664;            // [4096][1088] bf16
constexpr size_t OFF_W1122= 193986560;            // [4096][1024] bf16 (w11 ; w21)
constexpr size_t OFF_W12  = 202375168;
constexpr size_t OFF_W22  = 206569472;
constexpr size_t OFF_WK1  = 210763776;
constexpr size_t OFF_WK2  = 214958080;
constexpr size_t OFF_WV   = 219152384;
constexpr size_t OFF_WP   = 221249536;            // [1024][1088] bf16
constexpr size_t OFF_EM   = 223477760;            // em bf16, 268 MB

DEV void gl2l(const void* g, void* l) {
  __builtin_amdgcn_global_load_lds((const __attribute__((address_space(1))) void*)g,
                                   (__attribute__((address_space(3))) void*)l, 16, 0, 0);
}

// exact-erf GELU via Abramowitz-Stegun 7.1.26 (|eps|<1.5e-7, way below bf16)
DEV float gelu_f(float v) {
  float x = v * 0.70710678118654752f;
  float ax = fabsf(x);
  float t = 1.f / fmaf(0.3275911f, ax, 1.f);
  float y = t * fmaf(t, fmaf(t, fmaf(t, fmaf(t, 1.061405429f, -1.453152027f),
                                     1.421413741f), -0.284496736f), 0.254829592f);
  float er = 1.f - y * __expf(-x * x);
  er = (x < 0.f) ? -er : er;
  return 0.5f * v * (1.f + er);
}

// ---------------- merged prep: weights + proj + mask + ypT ----------------
__launch_bounds__(256)
__global__ void prep_all(const float* __restrict__ s0, const float* __restrict__ s1,
                         const float* __restrict__ s2, const float* __restrict__ s3,
                         const float* __restrict__ s4, const float* __restrict__ s5,
                         const float* __restrict__ s6,
                         __bf16* __restrict__ d0, __bf16* __restrict__ d1,
                         __bf16* __restrict__ d2, __bf16* __restrict__ d3,
                         __bf16* __restrict__ d4, __bf16* __restrict__ d5,
                         __bf16* __restrict__ d6,
                         const float* __restrict__ pw1, const float* __restrict__ pw2,
                         __bf16* __restrict__ wp,
                         const float* __restrict__ mask, __bf16* __restrict__ mb,
                         const float* __restrict__ yp, __bf16* __restrict__ ypT) {
  int u = blockIdx.x * 256 + threadIdx.x;
  if (u < 3407872) {                       // 7 weight arrays, float4 units
    int seg = u >> 19, r = u & 524287;
    const float* s; __bf16* d;
    if      (seg == 0) { s = s0; d = d0; }
    else if (seg == 1) { s = s1; d = d1; }
    else if (seg == 2) { s = s2; d = d2; }
    else if (seg == 3) { s = s3; d = d3; }
    else if (seg == 4) { s = s4; d = d4; }
    else if (seg == 5) { s = s5; d = d5; }
    else               { s = s6; d = d6; }
    float4 v = ((const float4*)s)[r];
    bf16x4v o; o[0]=(__bf16)v.x; o[1]=(__bf16)v.y; o[2]=(__bf16)v.z; o[3]=(__bf16)v.w;
    ((bf16x4v*)d)[r] = o;
  } else if (u < 3686400) {                // fused proj weight [1024][1088]
    int p = u - 3407872;
    int row = p / 272, c4 = p - row * 272;
    float4 v = (c4 < 256) ? ((const float4*)pw1)[row * 256 + c4]
                          : ((const float4*)pw2)[row * 16 + (c4 - 256)];
    bf16x4v o; o[0]=(__bf16)v.x; o[1]=(__bf16)v.y; o[2]=(__bf16)v.z; o[3]=(__bf16)v.w;
    *(bf16x4v*)(wp + (size_t)row * 1088 + (c4 << 2)) = o;
  } else if (u < 4734976) {                // mask f32 -> bf16
    int q = u - 3686400;
    float4 v = ((const float4*)mask)[q];
    bf16x4v o; o[0]=(__bf16)v.x; o[1]=(__bf16)v.y; o[2]=(__bf16)v.z; o[3]=(__bf16)v.w;
    ((bf16x4v*)mb)[q] = o;
  } else {                                 // ypT [B][4][L]
    int t0 = (u - 4734976) << 2;
    #pragma unroll
    for (int k = 0; k < 4; k++) {
      int i = t0 + k;
      int b = i >> 13, d = (i >> 11) & 3, l = i & 2047;
      ypT[i] = (__bf16)yp[(((size_t)b << 11) + l) * 4 + d];
    }
  }
}

// ---------------- merged LayerNorm: x -> xn ; y -> (ynk, ynv) ----------------
__launch_bounds__(256)
__global__ void ln_all(const float* __restrict__ x, const float* __restrict__ y,
                       const float* __restrict__ qg, const float* __restrict__ qb,
                       const float* __restrict__ kg, const float* __restrict__ kb,
                       const float* __restrict__ vg, const float* __restrict__ vb,
                       __bf16* __restrict__ xn, __bf16* __restrict__ ynk,
                       __bf16* __restrict__ ynv) {
  const int t = blockIdx.x, tid = threadIdx.x;
  const bool isx = t < 4096;
  const int row = isx ? t : t - 4096;
  const float* src = (isx ? x : y) + (size_t)row * Ee;
  const float4 v = ((const float4*)src)[tid];
  float s = v.x + v.y + v.z + v.w;
  float q = v.x*v.x + v.y*v.y + v.z*v.z + v.w*v.w;
  #pragma unroll
  for (int o = 32; o > 0; o >>= 1) { s += __shfl_down(s, o); q += __shfl_down(q, o); }
  __shared__ float ls[4], lq[4];
  if ((tid & 63) == 0) { ls[tid >> 6] = s; lq[tid >> 6] = q; }
  __syncthreads();
  s = ls[0] + ls[1] + ls[2] + ls[3];
  q = lq[0] + lq[1] + lq[2] + lq[3];
  const float mu = s * (1.f / Ee);
  const float rstd = rsqrtf(q * (1.f / Ee) - mu * mu + 1e-5f);
  const int e0 = tid << 2;
  float h0 = (v.x - mu) * rstd, h1 = (v.y - mu) * rstd,
        h2 = (v.z - mu) * rstd, h3 = (v.w - mu) * rstd;
  if (isx) {
    bf16x4v o;
    o[0] = (__bf16)(h0 * qg[e0]   + qb[e0]);
    o[1] = (__bf16)(h1 * qg[e0+1] + qb[e0+1]);
    o[2] = (__bf16)(h2 * qg[e0+2] + qb[e0+2]);
    o[3] = (__bf16)(h3 * qg[e0+3] + qb[e0+3]);
    *(bf16x4v*)(xn + (size_t)row * Ee + e0) = o;
  } else {
    bf16x4v ok, ov;
    ok[0] = (__bf16)(h0 * kg[e0]   + kb[e0]);
    ok[1] = (__bf16)(h1 * kg[e0+1] + kb[e0+1]);
    ok[2] = (__bf16)(h2 * kg[e0+2] + kb[e0+2]);
    ok[3] = (__bf16)(h3 * kg[e0+3] + kb[e0+3]);
    ov[0] = (__bf16)(h0 * vg[e0]   + vb[e0]);
    ov[1] = (__bf16)(h1 * vg[e0+1] + vb[e0+1]);
    ov[2] = (__bf16)(h2 * vg[e0+2] + vb[e0+2]);
    ov[3] = (__bf16)(h3 * vg[e0+3] + vb[e0+3]);
    *(bf16x4v*)(ynk + (size_t)row * Ee + e0) = ok;
    *(bf16x4v*)(ynv + (size_t)row * Ee + e0) = ov;
  }
}

// ================= BK=64 GEMM core (BM x 256 tile, 8 waves, 512 thr) =================
// BK=64 halves barrier count vs BK=32 at zero occupancy cost (already 1 block/CU).
// Rows are 128B = 8x 16B chunks, XOR-swizzled by (row&7) -> 2 lanes/bank-quad (free, m136).
// Counted vmcnt(BM/64+4): next tile's loads stay in flight across the barrier; the wait
// retires exactly the current tile's loads (oldest-first, m135). Staging targets the
// buffer whose reads completed at the previous iter's lgkmcnt(0)+barrier (race-free).
#define GEMM_CORE_BK64(BM_, A_, lda_, W_, ldw_, K_)                                   \
  const int w = tid >> 6, lane = tid & 63, g = lane >> 4, li = lane & 15;             \
  const int wm = (w >> 2) * (BM_ / 2), wn = (w & 3) << 6;                             \
  constexpr int MI = BM_ / 32;                                                        \
  f32x4 acc[MI][4];                                                                   \
  _Pragma("unroll")                                                                   \
  for (int i = 0; i < MI; i++)                                                        \
    _Pragma("unroll")                                                                 \
    for (int j = 0; j < 4; j++) acc[i][j] = (f32x4)0.f;                               \
  auto stage = [&](int buf, int kt) {                                                 \
    const int col0 = kt << 6;                                                         \
    _Pragma("unroll")                                                                 \
    for (int jj = 0; jj < BM_ / 64; jj++) {                                           \
      int c = (jj << 9) + tid;                                                        \
      int row = c >> 3, sl = c & 7;                                                   \
      int col = col0 + ((sl ^ (row & 7)) << 3);                                       \
      gl2l(A_ + (size_t)(m0 + row) * lda_ + col, (buf ? As1 : As0) + ((c - lane) << 3)); \
    }                                                                                 \
    _Pragma("unroll")                                                                 \
    for (int jj = 0; jj < 4; jj++) {                                                  \
      int c = (jj << 9) + tid;                                                        \
      int row = c >> 3, sl = c & 7;                                                   \
      int col = col0 + ((sl ^ (row & 7)) << 3);                                       \
      gl2l(W_ + (size_t)(n0 + row) * ldw_ + col, (buf ? Bs1 : Bs0) + ((c - lane) << 3)); \
    }                                                                                 \
  };                                                                                  \
  const int NT = (K_) >> 6;                                                           \
  stage(0, 0);                                                                        \
  for (int kt = 0; kt < NT; kt++) {                                                   \
    const int cur = kt & 1;                                                           \
    if (kt + 1 < NT) {                                                                \
      stage(cur ^ 1, kt + 1);                                                         \
      asm volatile("s_waitcnt vmcnt(%0)" :: "i"(BM_ / 64 + 4) : "memory");            \
    } else {                                                                          \
      asm volatile("s_waitcnt vmcnt(0)" ::: "memory");                                \
    }                                                                                 \
    __builtin_amdgcn_s_barrier();                                                     \
    __builtin_amdgcn_sched_barrier(0);                                                \
    const __bf16* Acur = cur ? As1 : As0;                                             \
    const __bf16* Bcur = cur ? Bs1 : Bs0;                                             \
    _Pragma("unroll")                                                                 \
    for (int ks = 0; ks < 2; ks++) {                                                  \
      bf16x8 af[MI], bw[4];                                                           \
      _Pragma("unroll")                                                               \
      for (int i = 0; i < MI; i++) {                                                  \
        int ra = wm + (i << 4) + li;                                                  \
        af[i] = *(const bf16x8*)(Acur + ra * 64 + ((((ks << 2) | g) ^ (ra & 7)) << 3)); \
      }                                                                               \
      _Pragma("unroll")                                                               \
      for (int j = 0; j < 4; j++) {                                                   \
        int rb = wn + (j << 4) + li;                                                  \
        bw[j] = *(const bf16x8*)(Bcur + rb * 64 + ((((ks << 2) | g) ^ (rb & 7)) << 3)); \
      }                                                                               \
      _Pragma("unroll")                                                               \
      for (int i = 0; i < MI; i++)                                                    \
        _Pragma("unroll")                                                             \
        for (int j = 0; j < 4; j++)                                                   \
          acc[i][j] = __builtin_amdgcn_mfma_f32_16x16x32_bf16(af[i], bw[j], acc[i][j], 0, 0, 0); \
    }                                                                                 \
    asm volatile("s_waitcnt lgkmcnt(0)" ::: "memory");                                \
    __builtin_amdgcn_sched_barrier(0);                                                \
    __builtin_amdgcn_s_barrier();                                                     \
  }

// Launch A: blocks 0..255: xn@w1122 (256x256 tiles, N=4096, gelu, split bias) -> h12
//           blocks 256..511: ynk@wk1 (128x256 tiles, N=2048, gelu) -> h3  [exact 2 rounds]
__launch_bounds__(512, 2)
__global__ void gemm_mlp1(const __bf16* __restrict__ xn, const __bf16* __restrict__ ynk,
                          const __bf16* __restrict__ w1122, const __bf16* __restrict__ wk1,
                          const float* __restrict__ qb1, const float* __restrict__ qb2,
                          const float* __restrict__ kb1,
                          __bf16* __restrict__ h12, __bf16* __restrict__ h3) {
  __shared__ __align__(16) __bf16 As0[256 * 64];
  __shared__ __align__(16) __bf16 As1[256 * 64];
  __shared__ __align__(16) __bf16 Bs0[256 * 64];
  __shared__ __align__(16) __bf16 Bs1[256 * 64];
  const int tid = threadIdx.x, bid = blockIdx.x;
  if (bid < 256) {
    const int m0 = (bid >> 4) << 8, n0 = (bid & 15) << 8;
    GEMM_CORE_BK64(256, xn, 1024, w1122, 1024, 1024)
    #pragma unroll
    for (int j = 0; j < 4; j++) {
      int n = n0 + wn + (j << 4) + li;
      float bias = (n < 2048) ? qb1[n] : qb2[n - 2048];
      #pragma unroll
      for (int i = 0; i < MI; i++) {
        #pragma unroll
        for (int r = 0; r < 4; r++) {
          int m = m0 + wm + (i << 4) + (g << 2) + r;
          h12[(size_t)m * 4096 + n] = (__bf16)gelu_f(acc[i][j][r] + bias);
        }
      }
    }
  } else {
    const int rr = bid - 256;
    const int m0 = (rr >> 3) << 7, n0 = (rr & 7) << 8;
    GEMM_CORE_BK64(128, ynk, 1024, wk1, 1024, 1024)
    #pragma unroll
    for (int j = 0; j < 4; j++) {
      int n = n0 + wn + (j << 4) + li;
      float bias = kb1[n];
      #pragma unroll
      for (int i = 0; i < MI; i++) {
        #pragma unroll
        for (int r = 0; r < 4; r++) {
          int m = m0 + wm + (i << 4) + (g << 2) + r;
          h3[(size_t)m * 2048 + n] = (__bf16)gelu_f(acc[i][j][r] + bias);
        }
      }
    }
  }
}

// Launch B: seg0 x1=h1@w12, seg1 x2=h2@w22, seg2 y1=h3@wk2 (K=2048), seg3 vT=ynv@wv (K=1024)
__launch_bounds__(512, 2)
__global__ void gemm_mlp2(const __bf16* __restrict__ h12, const __bf16* __restrict__ h3,
                          const __bf16* __restrict__ ynv,
                          const __bf16* __restrict__ w12, const __bf16* __restrict__ w22,
                          const __bf16* __restrict__ wk2, const __bf16* __restrict__ wv,
                          const float* __restrict__ bx1, const float* __restrict__ bx2,
                          const float* __restrict__ by1, const float* __restrict__ bv,
                          __bf16* __restrict__ x1, __bf16* __restrict__ x2,
                          __bf16* __restrict__ y1, __bf16* __restrict__ vT) {
  __shared__ __align__(16) __bf16 As0[256 * 64];
  __shared__ __align__(16) __bf16 As1[256 * 64];
  __shared__ __align__(16) __bf16 Bs0[256 * 64];
  __shared__ __align__(16) __bf16 Bs1[256 * 64];
  const int tid = threadIdx.x, bid = blockIdx.x;
  const int seg = bid >> 6, rr = bid & 63;
  const int m0 = (rr >> 2) << 8, n0 = (rr & 3) << 8;
  const __bf16* A; const __bf16* W; const float* bias; __bf16* out; int lda, K;
  if      (seg == 0) { A = h12;        lda = 4096; W = w12; bias = bx1; out = x1; K = 2048; }
  else if (seg == 1) { A = h12 + 2048; lda = 4096; W = w22; bias = bx2; out = x2; K = 2048; }
  else if (seg == 2) { A = h3;         lda = 2048; W = wk2; bias = by1; out = y1; K = 2048; }
  else               { A = ynv;        lda = 1024; W = wv;  bias = bv;  out = vT; K = 1024; }
  GEMM_CORE_BK64(256, A, lda, W, K, K)
  #pragma unroll
  for (int j = 0; j < 4; j++) {
    int n = n0 + wn + (j << 4) + li;
    float bs = bias[n];
    #pragma unroll
    for (int i = 0; i < MI; i++) {
      #pragma unroll
      for (int r = 0; r < 4; r++) {
        int m = m0 + wm + (i << 4) + (g << 2) + r;
        float v = acc[i][j][r] + bs;
        if (seg == 3) {        // vT: [B*H][64][2048]
          int bb = m >> 11, l = m & 2047, hh = n >> 6, cc = n & 63;
          vT[(((size_t)(bb * Hh + hh) * 64 + cc) << 11) + l] = (__bf16)v;
        } else {
          out[(size_t)m * 1024 + n] = (__bf16)v;
        }
      }
    }
  }
}

// ---------------- merged build q + k (vectorized swizzled stores) ----------------
__launch_bounds__(256)
__global__ void build_qk(const __bf16* __restrict__ x1, const __bf16* __restrict__ x2,
                         const float* __restrict__ xp,
                         const __bf16* __restrict__ y1, const float* __restrict__ yp,
                         const float* __restrict__ pw1, const float* __restrict__ pb1,
                         const float* __restrict__ pw2, const float* __restrict__ pb2,
                         __bf16* __restrict__ q_ws, __bf16* __restrict__ k_ws) {
  const bool isq = blockIdx.x < 2048;
  const int bid = isq ? blockIdx.x : blockIdx.x - 2048;
  const int t = (bid << 1) + (threadIdx.x >> 7);
  const int tl = threadIdx.x & 127;
  const int b = t >> 11, n = t & 2047;
  const int hh = tl >> 3, ch = tl & 7;
  const int e0 = (hh << 6) + (ch << 3);
  const float* pos = isq ? xp : yp;
  const float p0 = pos[(size_t)t*4], p1 = pos[(size_t)t*4+1],
              p2 = pos[(size_t)t*4+2], p3 = pos[(size_t)t*4+3];
  bf16x8 o0, o1, o2, o3;
  if (isq) {
    bf16x8 v1 = *(const bf16x8*)(x1 + (size_t)t * Ee + e0);
    bf16x8 v2 = *(const bf16x8*)(x2 + (size_t)t * Ee + e0);
    #pragma unroll
    for (int sub = 0; sub < 8; sub++) {
      int e = e0 + sub;
      float a1 = pw1[e*4]*p0 + pw1[e*4+1]*p1 + pw1[e*4+2]*p2 + pw1[e*4+3]*p3 + pb1[e];
      float a2 = pw2[e*4]*p0 + pw2[e*4+1]*p1 + pw2[e*4+2]*p2 + pw2[e*4+3]*p3 + pb2[e];
      float s1, c1, s2, c2;
      __sincosf(a1, &s1, &c1); __sincosf(a2, &s2, &c2);
      float xv1 = (float)v1[sub], xv2 = (float)v2[sub];
      o0[sub] = (__bf16)(xv1 * c1); o1[sub] = (__bf16)(xv1 * s1);
      o2[sub] = (__bf16)(xv2 * c2); o3[sub] = (__bf16)(xv2 * s2);
    }
  } else {
    bf16x8 v1 = *(const bf16x8*)(y1 + (size_t)t * Ee + e0);
    #pragma unroll
    for (int sub = 0; sub < 8; sub++) {
      int e = e0 + sub;
      float a1 = pw1[e*4]*p0 + pw1[e*4+1]*p1 + pw1[e*4+2]*p2 + pw1[e*4+3]*p3;
      float a2 = pw2[e*4]*p0 + pw2[e*4+1]*p1 + pw2[e*4+2]*p2 + pw2[e*4+3]*p3;
      float s1, c1, s2, c2;
      __sincosf(a1, &s1, &c1); __sincosf(a2, &s2, &c2);
      float yv = (float)v1[sub];
      o0[sub] = (__bf16)(yv * c1); o1[sub] = (__bf16)(yv * s1);
      o2[sub] = (__bf16)c2;        o3[sub] = (__bf16)s2;
    }
  }
  const int k = n & 7, bc = ch ^ k;
  __bf16* base = (isq ? q_ws : k_ws) + ((((size_t)b * Hh + hh) * Nn + n) << 8);
  *(bf16x8*)(base + ((bc          ) << 3)) = o0;
  *(bf16x8*)(base + (((8  ^ k) ^ ch) << 3)) = o1;
  *(bf16x8*)(base + (((16 ^ k) ^ ch) << 3)) = o2;
  *(bf16x8*)(base + (((24 ^ k) ^ ch) << 3)) = o3;
}

// ---------------- fused flash attention (single QK^T pass, no max) ----------------
// 256 q-rows/block, 8 waves x 32 rows (2 frags), KVBLK=32, double-buffered staging.
// grid = 256 blocks = exactly 1/CU. K-fragment LDS reads shared across both row-frags.
__launch_bounds__(512, 1)
__global__ void attn_fused(const __bf16* __restrict__ q_ws, const __bf16* __restrict__ k_ws,
                           const __bf16* __restrict__ vT_ws, const __bf16* __restrict__ ypT_g,
                           const __bf16* __restrict__ mask_bf, const float* __restrict__ xp,
                           __bf16* __restrict__ em_g, float* __restrict__ dinv_g,
                           __bf16* __restrict__ avz) {
  __shared__ __align__(16) __bf16 kq[2][32 * 256];   // 32 KB
  __shared__ __align__(16) __bf16 ms[2][256 * 32];   // 32 KB
  __shared__ __align__(16) __bf16 vt[2][64 * 40];    // 10 KB
  __shared__ __align__(16) __bf16 pT[256 * 40];      // 20 KB
  __shared__ __align__(16) __bf16 ypl[2][16 * 40];   // 2.5 KB
  const int tid = threadIdx.x, w = tid >> 6, lane = tid & 63, g = lane >> 4, li = lane & 15;
  const int logical = ((blockIdx.x & 7) << 5) + (blockIdx.x >> 3);  // XCD-chunked
  const int bh = logical >> 3, nt = logical & 7;
  const int b = bh >> 4, h = bh & 15;
  const int n0 = nt << 8;
  const __bf16* qb = q_ws + (((size_t)bh * Nn + n0) << 8);
  const __bf16* kb = k_ws + (((size_t)bh * Ll) << 8);
  const __bf16* vb = vT_ws + ((size_t)bh << 17);
  const __bf16* yb = ypT_g + ((size_t)b << 13);
  const __bf16* mb = mask_bf + ((size_t)n0 << 11);

  // Q fragments (32 rows/wave, 2 frags) direct from pre-swizzled global
  bf16x8 aq[2][8];
  #pragma unroll
  for (int rf = 0; rf < 2; rf++) {
    const int nloc = (w << 5) + (rf << 4) + li;
    #pragma unroll
    for (int s = 0; s < 8; s++)
      aq[rf][s] = *(const bf16x8*)(qb + ((size_t)nloc << 8) + ((((s << 2) + g) ^ (nloc & 7)) << 3));
  }
  // zero ypl rows 4..15 (both buffers)
  for (int i = tid; i < 960; i += 512) {
    int buf = i / 480, idx = i - buf * 480;
    ypl[buf][160 + idx] = (__bf16)0.f;
  }
  // prologue: stage tile 0
  {
    const int vc = tid >> 3, vl = (tid & 7) << 2;
    bf16x4v vreg = *(const bf16x4v*)(vb + ((size_t)vc << 11) + vl);
    bf16x4v ypreg;
    if (tid < 32) ypreg = *(const bf16x4v*)(yb + ((size_t)(tid >> 3) << 11) + ((tid & 7) << 2));
    #pragma unroll
    for (int j = 0; j < 2; j++) {
      int c = (j << 9) + tid;
      gl2l(kb + (size_t)(c >> 5) * 256 + ((c & 31) << 3), kq[0] + ((c - lane) << 3));
      gl2l(mb + (size_t)(c >> 2) * 2048 + ((c & 3) << 3), ms[0] + ((c - lane) << 3));
    }
    *(bf16x4v*)(vt[0] + vc * 40 + vl) = vreg;
    if (tid < 32) *(bf16x4v*)(ypl[0] + (tid >> 3) * 40 + ((tid & 7) << 2)) = ypreg;
  }
  __syncthreads();

  float se[2][4], te[2][4];
  f32x4 accv[2][4], accp[2];
  #pragma unroll
  for (int rf = 0; rf < 2; rf++) {
    #pragma unroll
    for (int r = 0; r < 4; r++) { se[rf][r] = 0.f; te[rf][r] = 0.f; }
    #pragma unroll
    for (int cb = 0; cb < 4; cb++) accv[rf][cb] = (f32x4)0.f;
    accp[rf] = (f32x4)0.f;
  }

  for (int t = 0; t < 64; ++t) {
    const int l0 = t << 5, cur = t & 1, nxt = cur ^ 1;
    const bool more = (t < 63);
    bf16x4v vreg, ypreg;
    if (more) {
      const int l1 = l0 + 32;
      vreg = *(const bf16x4v*)(vb + ((size_t)(tid >> 3) << 11) + l1 + ((tid & 7) << 2));
      if (tid < 32) ypreg = *(const bf16x4v*)(yb + ((size_t)(tid >> 3) << 11) + l1 + ((tid & 7) << 2));
      #pragma unroll
      for (int j = 0; j < 2; j++) {
        int c = (j << 9) + tid;
        gl2l(kb + (size_t)(l1 + (c >> 5)) * 256 + ((c & 31) << 3), kq[nxt] + ((c - lane) << 3));
        gl2l(mb + (size_t)(c >> 2) * 2048 + l1 + ((c & 3) << 3), ms[nxt] + ((c - lane) << 3));
      }
    }
    // QK^T: K-fragment reads shared across both row-fragments (16 b128 for 32 MFMA)
    f32x4 Cs[2][2];
    Cs[0][0] = (f32x4)0.f; Cs[0][1] = (f32x4)0.f; Cs[1][0] = (f32x4)0.f; Cs[1][1] = (f32x4)0.f;
    #pragma unroll
    for (int lb = 0; lb < 2; lb++) {
      const int kr = (lb << 4) + li;
      #pragma unroll
      for (int s = 0; s < 8; s++) {
        bf16x8 bk = *(const bf16x8*)(kq[cur] + kr * 256 + ((((s << 2) + g) ^ (kr & 7)) << 3));
        Cs[0][lb] = __builtin_amdgcn_mfma_f32_16x16x32_bf16(aq[0][s], bk, Cs[0][lb], 0, 0, 0);
        Cs[1][lb] = __builtin_amdgcn_mfma_f32_16x16x32_bf16(aq[1][s], bk, Cs[1][lb], 0, 0, 0);
      }
    }
    // exp + mask (LDS) + sums + pT
    #pragma unroll
    for (int rf = 0; rf < 2; rf++) {
      #pragma unroll
      for (int lb = 0; lb < 2; lb++) {
        #pragma unroll
        for (int r = 0; r < 4; r++) {
          const int row = (w << 5) + (rf << 4) + (g << 2) + r;
          float e = __expf(Cs[rf][lb][r] * SCALE);
          float mkv = (float)ms[cur][row * 32 + (lb << 4) + li];
          float em = e * mkv;
          se[rf][r] += e; te[rf][r] += em;
          pT[row * 40 + (lb << 4) + li] = (__bf16)em;
        }
      }
    }
    asm volatile("s_waitcnt lgkmcnt(0)" ::: "memory");
    __builtin_amdgcn_sched_barrier(0);
    // em global store (2 b128 per lane; wave-private rows)
    #pragma unroll
    for (int j = 0; j < 2; j++) {
      int q = (j << 6) + lane;
      int row = q >> 2, ch = q & 3;
      bf16x8 pv = *(const bf16x8*)(pT + ((w << 5) + row) * 40 + (ch << 3));
      *(bf16x8*)(em_g + ((size_t)bh << 22) + ((size_t)(n0 + (w << 5) + row) << 11) + l0 + (ch << 3)) = pv;
    }
    // PV + attn@yp (V/yp frags shared across row-frags)
    bf16x8 vv[4];
    #pragma unroll
    for (int cb = 0; cb < 4; cb++)
      vv[cb] = *(const bf16x8*)(vt[cur] + ((cb << 4) + li) * 40 + (g << 3));
    bf16x8 yy = *(const bf16x8*)(ypl[cur] + li * 40 + (g << 3));
    #pragma unroll
    for (int rf = 0; rf < 2; rf++) {
      bf16x8 pa = *(const bf16x8*)(pT + ((w << 5) + (rf << 4) + li) * 40 + (g << 3));
      #pragma unroll
      for (int cb = 0; cb < 4; cb++)
        accv[rf][cb] = __builtin_amdgcn_mfma_f32_16x16x32_bf16(pa, vv[cb], accv[rf][cb], 0, 0, 0);
      accp[rf] = __builtin_amdgcn_mfma_f32_16x16x32_bf16(pa, yy, accp[rf], 0, 0, 0);
    }
    if (more) {
      *(bf16x4v*)(vt[nxt] + (tid >> 3) * 40 + ((tid & 7) << 2)) = vreg;
      if (tid < 32) *(bf16x4v*)(ypl[nxt] + (tid >> 3) * 40 + ((tid & 7) << 2)) = ypreg;
    }
    __syncthreads();
  }

  // epilogue: reduce sums, write dinv + avz
  #pragma unroll
  for (int rf = 0; rf < 2; rf++) {
    #pragma unroll
    for (int r = 0; r < 4; r++) {
      float s = se[rf][r], tt = te[rf][r];
      #pragma unroll
      for (int o = 1; o < 16; o <<= 1) { s += __shfl_xor(s, o); tt += __shfl_xor(tt, o); }
      float dinv = 1.f / (tt + 1e-8f * s);
      const int n = n0 + (w << 5) + (rf << 4) + (g << 2) + r;
      if (li == 0) dinv_g[((size_t)bh << 11) + n] = dinv;
      #pragma unroll
      for (int cb = 0; cb < 4; cb++)
        avz[((size_t)b * Nn + n) * 1088 + (h << 6) + (cb << 4) + li] = (__bf16)(accv[rf][cb][r] * dinv);
      if (li < 4) {
        float z = accp[rf][r] * dinv - xp[(((size_t)b * Nn + n) << 2) + li];
        avz[((size_t)b * Nn + n) * 1088 + 1024 + (h << 2) + li] = (__bf16)z;
      }
    }
  }
}

// ---------------- merged finalize + output projection ----------------
// blocks 0..511: 128x64-tile GEMM out0 = avz @ wp^T + b1 + b2 (counted vmcnt(3))
// blocks 512..2559: attn = em * dinv streaming + xp passthrough.
__launch_bounds__(256)
__global__ void fin_proj(const __bf16* __restrict__ A, const __bf16* __restrict__ W,
                         const float* __restrict__ bias1, const float* __restrict__ bias2,
                         float* __restrict__ out,
                         const __bf16* __restrict__ em_g, const float* __restrict__ dinv_g,
                         float* __restrict__ attn_out,
                         const float* __restrict__ xp, float* __restrict__ xp_out) {
  constexpr int N = 1024, K = 1088;
  __shared__ __align__(16) __bf16 As[2][128 * 32];
  __shared__ __align__(16) __bf16 Bs[2][64 * 32];
  const int tid = threadIdx.x;
  if (blockIdx.x >= 512) {
    // ---- streaming finalize segment ----
    const int sbid = blockIdx.x - 512;
    if (sbid < 64) {
      int idx = sbid * 256 + tid;   // 16384 float4 units
      ((float4*)xp_out)[idx] = ((const float4*)xp)[idx];
    }
    for (size_t i8 = sbid * 256ul + tid; i8 < 16777216ul; i8 += 524288ul) {
      bf16x8 v = ((const bf16x8*)em_g)[i8];
      float dv = dinv_g[i8 >> 8];
      float4 o0, o1;
      o0.x = (float)v[0] * dv; o0.y = (float)v[1] * dv; o0.z = (float)v[2] * dv; o0.w = (float)v[3] * dv;
      o1.x = (float)v[4] * dv; o1.y = (float)v[5] * dv; o1.z = (float)v[6] * dv; o1.w = (float)v[7] * dv;
      ((float4*)attn_out)[i8 * 2]     = o0;
      ((float4*)attn_out)[i8 * 2 + 1] = o1;
    }
    return;
  }
  // ---- GEMM segment ----
  const int w = tid >> 6, lane = tid & 63, g = lane >> 4, li = lane & 15;
  const int bt = blockIdx.x >> 4;
  const int m0 = bt << 7, n0 = (blockIdx.x & 15) << 6;
  const int wm = (w >> 1) << 6, wn = (w & 1) << 5;
  f32x4 acc[4][2];
  #pragma unroll
  for (int i = 0; i < 4; i++) { acc[i][0] = (f32x4)0.f; acc[i][1] = (f32x4)0.f; }
  auto stage = [&](int buf, int kt) {
    const int col0 = kt << 5;
    #pragma unroll
    for (int j = 0; j < 2; j++) {
      int c = (j << 8) + tid;
      int row = c >> 2, sl = c & 3;
      int col = col0 + ((sl ^ (row & 3)) << 3);
      gl2l(A + (size_t)(m0 + row) * K + col, As[buf] + ((c - lane) << 3));
    }
    {
      int c = tid;
      int row = c >> 2, sl = c & 3;
      int col = col0 + ((sl ^ (row & 3)) << 3);
      gl2l(W + (size_t)(n0 + row) * K + col, Bs[buf] + ((c - lane) << 3));
    }
  };
  const int NT = K >> 5;   // 34
  stage(0, 0);
  for (int kt = 0; kt < NT; kt++) {
    const int cur = kt & 1;
    if (kt + 1 < NT) {
      stage(cur ^ 1, kt + 1);
      asm volatile("s_waitcnt vmcnt(3)" ::: "memory");
    } else {
      asm volatile("s_waitcnt vmcnt(0)" ::: "memory");
    }
    __builtin_amdgcn_s_barrier();
    __builtin_amdgcn_sched_barrier(0);
    bf16x8 af[4], bw[2];
    #pragma unroll
    for (int i = 0; i < 4; i++) {
      int ra = wm + (i << 4) + li;
      af[i] = *(const bf16x8*)(As[cur] + ra * 32 + ((g ^ (ra & 3)) << 3));
    }
    #pragma unroll
    for (int j = 0; j < 2; j++) {
      int rb = wn + (j << 4) + li;
      bw[j] = *(const bf16x8*)(Bs[cur] + rb * 32 + ((g ^ (rb & 3)) << 3));
    }
    #pragma unroll
    for (int i = 0; i < 4; i++)
      #pragma unroll
      for (int j = 0; j < 2; j++)
        acc[i][j] = __builtin_amdgcn_mfma_f32_16x16x32_bf16(af[i], bw[j], acc[i][j], 0, 0, 0);
    asm volatile("s_waitcnt lgkmcnt(0)" ::: "memory");
    __builtin_amdgcn_sched_barrier(0);
    __builtin_amdgcn_s_barrier();
  }
  #pragma unroll
  for (int j = 0; j < 2; j++) {
    int n = n0 + wn + (j << 4) + li;
    float bias = bias1[n] + bias2[n];
    #pragma unroll
    for (int i = 0; i < 4; i++) {
      #pragma unroll
      for (int r = 0; r < 4; r++) {
        int m = m0 + wm + (i << 4) + (g << 2) + r;
        out[(size_t)m * N + n] = acc[i][j][r] + bias;
      }
    }
  }
}

// ---------------- host ----------------
extern "C" void kernel_launch(void* const* d_in, const int* in_sizes, int n_in,
                              void* d_out, int out_size, void* d_ws, size_t ws_size,
                              hipStream_t stream) {
  (void)in_sizes; (void)n_in; (void)out_size; (void)ws_size;
  const float* x       = (const float*)d_in[0];
  const float* xp      = (const float*)d_in[1];
  const float* y       = (const float*)d_in[2];
  const float* yp      = (const float*)d_in[3];
  const float* mask    = (const float*)d_in[4];
  const float* p_w1    = (const float*)d_in[5];
  const float* p_b1    = (const float*)d_in[6];
  const float* p_w2    = (const float*)d_in[7];
  const float* p_b2    = (const float*)d_in[8];
  const float* q_ln_g  = (const float*)d_in[9];
  const float* q_ln_b  = (const float*)d_in[10];
  const float* q_m1_w1 = (const float*)d_in[11];
  const float* q_m1_b1 = (const float*)d_in[12];
  const float* q_m1_w2 = (const float*)d_in[13];
  const float* q_m1_b2 = (const float*)d_in[14];
  const float* q_m2_w1 = (const float*)d_in[15];
  const float* q_m2_b1 = (const float*)d_in[16];
  const float* q_m2_w2 = (const float*)d_in[17];
  const float* q_m2_b2 = (const float*)d_in[18];
  const float* k_ln_g  = (const float*)d_in[19];
  const float* k_ln_b  = (const float*)d_in[20];
  const float* k_m1_w1 = (const float*)d_in[21];
  const float* k_m1_b1 = (const float*)d_in[22];
  const float* k_m1_w2 = (const float*)d_in[23];
  const float* k_m1_b2 = (const float*)d_in[24];
  const float* v_ln_g  = (const float*)d_in[25];
  const float* v_ln_b  = (const float*)d_in[26];
  const float* v_w     = (const float*)d_in[27];
  const float* v_b     = (const float*)d_in[28];
  const float* proj1_w = (const float*)d_in[29];
  const float* proj1_b = (const float*)d_in[30];
  const float* proj2_w = (const float*)d_in[31];
  const float* proj2_b = (const float*)d_in[32];

  char* ws = (char*)d_ws;
  __bf16* xn    = (__bf16*)(ws + OFF_XN);
  __bf16* ynk   = (__bf16*)(ws + OFF_YNK);
  __bf16* ynv   = (__bf16*)(ws + OFF_YNV);
  __bf16* h12   = (__bf16*)(ws + OFF_H12);
  __bf16* h3    = (__bf16*)(ws + OFF_H3);
  __bf16* x1    = (__bf16*)(ws + OFF_X1);
  __bf16* x2    = (__bf16*)(ws + OFF_X2);
  __bf16* y1    = (__bf16*)(ws + OFF_Y1);
  __bf16* q_ws  = (__bf16*)(ws + OFF_QWS);
  __bf16* k_ws  = (__bf16*)(ws + OFF_KWS);
  __bf16* vT_ws = (__bf16*)(ws + OFF_VWS);
  float*  dinv  = (float*)(ws + OFF_DNV);
  __bf16* ypT   = (__bf16*)(ws + OFF_YPT);
  __bf16* mskb  = (__bf16*)(ws + OFF_MSK);
  __bf16* avz   = (__bf16*)(ws + OFF_AVZ);
  __bf16* w1122 = (__bf16*)(ws + OFF_W1122);
  __bf16* w12   = (__bf16*)(ws + OFF_W12);
  __bf16* w22   = (__bf16*)(ws + OFF_W22);
  __bf16* wk1   = (__bf16*)(ws + OFF_WK1);
  __bf16* wk2   = (__bf16*)(ws + OFF_WK2);
  __bf16* wv    = (__bf16*)(ws + OFF_WV);
  __bf16* wp    = (__bf16*)(ws + OFF_WP);
  __bf16* em    = (__bf16*)(ws + OFF_EM);

  float* out0     = (float*)d_out;
  float* attn_out = out0 + (size_t)4194304;
  float* xp_out   = out0 + (size_t)138412032;

  // 1. prep (weights + fused proj + mask bf16 + ypT)
  prep_all<<<18512, 256, 0, stream>>>(q_m1_w1, q_m2_w1, q_m1_w2, q_m2_w2, k_m1_w1, k_m1_w2, v_w,
                                      w1122, w1122 + 2097152, w12, w22, wk1, wk2, wv,
                                      proj1_w, proj2_w, wp, mask, mskb, yp, ypT);
  // 2. layernorms
  ln_all<<<8192, 256, 0, stream>>>(x, y, q_ln_g, q_ln_b, k_ln_g, k_ln_b, v_ln_g, v_ln_b,
                                   xn, ynk, ynv);
  // 3. mlp stage 1 (BK=64 pipeline; 256 big + 256 half tiles = exact 2 rounds)
  gemm_mlp1<<<512, 512, 0, stream>>>(xn, ynk, w1122, wk1, q_m1_b1, q_m2_b1, k_m1_b1, h12, h3);
  // 4. mlp stage 2 + V projection (BK=64 pipeline, 256 blocks = 1/CU)
  gemm_mlp2<<<256, 512, 0, stream>>>(h12, h3, ynv, w12, w22, wk2, wv,
                                     q_m1_b2, q_m2_b2, k_m1_b2, v_b, x1, x2, y1, vT_ws);
  // 5. q/k assembly (merged; pos-encoder matmul + trig, vectorized swizzled stores)
  build_qk<<<4096, 256, 0, stream>>>(x1, x2, xp, y1, yp, p_w1, p_b1, p_w2, p_b2, q_ws, k_ws);
  // 6. fused flash attention (256 q-rows/block, 1 block/CU)
  attn_fused<<<256, 512, 0, stream>>>(q_ws, k_ws, vT_ws, ypT, mskb, xp, em, dinv, avz);
  // 7. merged finalize (attn = em*dinv + xp passthrough) + output projection
  fin_proj<<<2560, 256, 0, stream>>>(avz, wp, proj1_b, proj2_b, out0,
                                     em, dinv, attn_out, xp, xp_out);
}

// Round 9
// 694.537 us; speedup vs baseline: 1.0566x; 1.0043x over previous
//
#include <hip/hip_runtime.h>
#include <math.h>
#include <stdint.h>

#define DEV static __device__ __forceinline__

typedef __bf16 bf16x8 __attribute__((ext_vector_type(8)));
typedef __bf16 bf16x4v __attribute__((ext_vector_type(4)));
typedef float f32x4 __attribute__((ext_vector_type(4)));

// problem dims
constexpr int Nn = 2048, Ll = 2048, Ee = 1024, Hh = 16;
constexpr float SCALE = 0.0625f;   // (4C)^-0.5 = 1/16

// ---------------- workspace layout (bytes) ----------------
constexpr size_t OFF_XN   = 0;                    // [4096][1024] bf16
constexpr size_t OFF_YNK  = 8388608;
constexpr size_t OFF_YNV  = 16777216;
constexpr size_t OFF_H12  = 25165824;             // [4096][4096] bf16
constexpr size_t OFF_H3   = 58720256;             // [4096][2048] bf16
constexpr size_t OFF_X1   = 75497472;             // [4096][1024] bf16
constexpr size_t OFF_X2   = 83886080;
constexpr size_t OFF_Y1   = 92274688;
constexpr size_t OFF_QWS  = 100663296;            // [B][H][N][256] bf16, pre-swizzled
constexpr size_t OFF_KWS  = 134217728;            // [B][H][L][256] bf16, pre-swizzled
constexpr size_t OFF_VWS  = 167772160;            // vT: [B*H][64][2048] bf16
constexpr size_t OFF_DNV  = 176160768;            // f32 [B*H*N]
constexpr size_t OFF_YPT  = 176422912;            // ypT [B][4][2048] bf16
constexpr size_t OFF_MSK  = 176685056;            // mask bf16 [2048][2048]
constexpr size_t OFF_AVZ  = 185073664;            // [4096][1088] bf16
constexpr size_t OFF_W1122= 193986560;            // [4096][1024] bf16 (w11 ; w21)
constexpr size_t OFF_W12  = 202375168;
constexpr size_t OFF_W22  = 206569472;
constexpr size_t OFF_WK1  = 210763776;
constexpr size_t OFF_WK2  = 214958080;
constexpr size_t OFF_WV   = 219152384;
constexpr size_t OFF_WP   = 221249536;            // [1024][1088] bf16
constexpr size_t OFF_EM   = 223477760;            // em bf16, 268 MB

DEV void gl2l(const void* g, void* l) {
  __builtin_amdgcn_global_load_lds((const __attribute__((address_space(1))) void*)g,
                                   (__attribute__((address_space(3))) void*)l, 16, 0, 0);
}

// exact-erf GELU via Abramowitz-Stegun 7.1.26 (|eps|<1.5e-7, way below bf16)
DEV float gelu_f(float v) {
  float x = v * 0.70710678118654752f;
  float ax = fabsf(x);
  float t = 1.f / fmaf(0.3275911f, ax, 1.f);
  float y = t * fmaf(t, fmaf(t, fmaf(t, fmaf(t, 1.061405429f, -1.453152027f),
                                     1.421413741f), -0.284496736f), 0.254829592f);
  float er = 1.f - y * __expf(-x * x);
  er = (x < 0.f) ? -er : er;
  return 0.5f * v * (1.f + er);
}

// ---------------- merged prep: weights + proj + mask + ypT ----------------
__launch_bounds__(256)
__global__ void prep_all(const float* __restrict__ s0, const float* __restrict__ s1,
                         const float* __restrict__ s2, const float* __restrict__ s3,
                         const float* __restrict__ s4, const float* __restrict__ s5,
                         const float* __restrict__ s6,
                         __bf16* __restrict__ d0, __bf16* __restrict__ d1,
                         __bf16* __restrict__ d2, __bf16* __restrict__ d3,
                         __bf16* __restrict__ d4, __bf16* __restrict__ d5,
                         __bf16* __restrict__ d6,
                         const float* __restrict__ pw1, const float* __restrict__ pw2,
                         __bf16* __restrict__ wp,
                         const float* __restrict__ mask, __bf16* __restrict__ mb,
                         const float* __restrict__ yp, __bf16* __restrict__ ypT) {
  int u = blockIdx.x * 256 + threadIdx.x;
  if (u < 3407872) {                       // 7 weight arrays, float4 units
    int seg = u >> 19, r = u & 524287;
    const float* s; __bf16* d;
    if      (seg == 0) { s = s0; d = d0; }
    else if (seg == 1) { s = s1; d = d1; }
    else if (seg == 2) { s = s2; d = d2; }
    else if (seg == 3) { s = s3; d = d3; }
    else if (seg == 4) { s = s4; d = d4; }
    else if (seg == 5) { s = s5; d = d5; }
    else               { s = s6; d = d6; }
    float4 v = ((const float4*)s)[r];
    bf16x4v o; o[0]=(__bf16)v.x; o[1]=(__bf16)v.y; o[2]=(__bf16)v.z; o[3]=(__bf16)v.w;
    ((bf16x4v*)d)[r] = o;
  } else if (u < 3686400) {                // fused proj weight [1024][1088]
    int p = u - 3407872;
    int row = p / 272, c4 = p - row * 272;
    float4 v = (c4 < 256) ? ((const float4*)pw1)[row * 256 + c4]
                          : ((const float4*)pw2)[row * 16 + (c4 - 256)];
    bf16x4v o; o[0]=(__bf16)v.x; o[1]=(__bf16)v.y; o[2]=(__bf16)v.z; o[3]=(__bf16)v.w;
    *(bf16x4v*)(wp + (size_t)row * 1088 + (c4 << 2)) = o;
  } else if (u < 4734976) {                // mask f32 -> bf16
    int q = u - 3686400;
    float4 v = ((const float4*)mask)[q];
    bf16x4v o; o[0]=(__bf16)v.x; o[1]=(__bf16)v.y; o[2]=(__bf16)v.z; o[3]=(__bf16)v.w;
    ((bf16x4v*)mb)[q] = o;
  } else {                                 // ypT [B][4][L]
    int t0 = (u - 4734976) << 2;
    #pragma unroll
    for (int k = 0; k < 4; k++) {
      int i = t0 + k;
      int b = i >> 13, d = (i >> 11) & 3, l = i & 2047;
      ypT[i] = (__bf16)yp[(((size_t)b << 11) + l) * 4 + d];
    }
  }
}

// ---------------- merged LayerNorm: x -> xn ; y -> (ynk, ynv) ----------------
__launch_bounds__(256)
__global__ void ln_all(const float* __restrict__ x, const float* __restrict__ y,
                       const float* __restrict__ qg, const float* __restrict__ qb,
                       const float* __restrict__ kg, const float* __restrict__ kb,
                       const float* __restrict__ vg, const float* __restrict__ vb,
                       __bf16* __restrict__ xn, __bf16* __restrict__ ynk,
                       __bf16* __restrict__ ynv) {
  const int t = blockIdx.x, tid = threadIdx.x;
  const bool isx = t < 4096;
  const int row = isx ? t : t - 4096;
  const float* src = (isx ? x : y) + (size_t)row * Ee;
  const float4 v = ((const float4*)src)[tid];
  float s = v.x + v.y + v.z + v.w;
  float q = v.x*v.x + v.y*v.y + v.z*v.z + v.w*v.w;
  #pragma unroll
  for (int o = 32; o > 0; o >>= 1) { s += __shfl_down(s, o); q += __shfl_down(q, o); }
  __shared__ float ls[4], lq[4];
  if ((tid & 63) == 0) { ls[tid >> 6] = s; lq[tid >> 6] = q; }
  __syncthreads();
  s = ls[0] + ls[1] + ls[2] + ls[3];
  q = lq[0] + lq[1] + lq[2] + lq[3];
  const float mu = s * (1.f / Ee);
  const float rstd = rsqrtf(q * (1.f / Ee) - mu * mu + 1e-5f);
  const int e0 = tid << 2;
  float h0 = (v.x - mu) * rstd, h1 = (v.y - mu) * rstd,
        h2 = (v.z - mu) * rstd, h3 = (v.w - mu) * rstd;
  if (isx) {
    bf16x4v o;
    o[0] = (__bf16)(h0 * qg[e0]   + qb[e0]);
    o[1] = (__bf16)(h1 * qg[e0+1] + qb[e0+1]);
    o[2] = (__bf16)(h2 * qg[e0+2] + qb[e0+2]);
    o[3] = (__bf16)(h3 * qg[e0+3] + qb[e0+3]);
    *(bf16x4v*)(xn + (size_t)row * Ee + e0) = o;
  } else {
    bf16x4v ok, ov;
    ok[0] = (__bf16)(h0 * kg[e0]   + kb[e0]);
    ok[1] = (__bf16)(h1 * kg[e0+1] + kb[e0+1]);
    ok[2] = (__bf16)(h2 * kg[e0+2] + kb[e0+2]);
    ok[3] = (__bf16)(h3 * kg[e0+3] + kb[e0+3]);
    ov[0] = (__bf16)(h0 * vg[e0]   + vb[e0]);
    ov[1] = (__bf16)(h1 * vg[e0+1] + vb[e0+1]);
    ov[2] = (__bf16)(h2 * vg[e0+2] + vb[e0+2]);
    ov[3] = (__bf16)(h3 * vg[e0+3] + vb[e0+3]);
    *(bf16x4v*)(ynk + (size_t)row * Ee + e0) = ok;
    *(bf16x4v*)(ynv + (size_t)row * Ee + e0) = ov;
  }
}

// ============ 4-phase interleaved GEMM pipeline (T3+T4+T5), BK=64, piece-major LDS ============
// Tile = BM x 256, 8 waves. Each BK=64 K-tile split into 2 k-pieces (32 cols) per operand,
// stored piece-major (As[buf][piece][BM*32]) so global_load_lds dst stays wave-linear.
// Per phase: {ds_read frag subtile; stage 1 piece; [vmcnt]; barrier; lgkmcnt(0); setprio(1);
// MI*2 MFMA (one kstep x n-quadrant); setprio(0); barrier}. Pieces staged 3 phases ahead of
// use; vmcnt(BM/128+2) at phases 1/3 retires exactly the pieces needed 3 phases later
// (oldest-first, m135). WAR: phase-2/3 stages overwrite current tile's k0 pieces, dead after
// phase 1's lgkmcnt(0)+barrier. A-frags loaded once per kstep, reused across both qn phases.

#define STAGE_A(BM_, A_, lda_, kt_, kh_, buf_)                                        \
  _Pragma("unroll")                                                                   \
  for (int jj = 0; jj < (BM_) / 128; jj++) {                                          \
    int c = (jj << 9) + tid;                                                          \
    int row_ = c >> 2, j_ = c & 3;                                                    \
    int col_ = ((kt_) << 6) + ((kh_) << 5) + ((j_ ^ (row_ & 3)) << 3);                \
    gl2l(A_ + (size_t)(m0 + row_) * (lda_) + col_,                                    \
         As + ((((buf_) << 1) + (kh_)) * ((BM_) * 32)) + (c << 3));                   \
  }

#define STAGE_B(W_, ldw_, kt_, kh_, buf_)                                             \
  _Pragma("unroll")                                                                   \
  for (int jj = 0; jj < 2; jj++) {                                                    \
    int c = (jj << 9) + tid;                                                          \
    int row_ = c >> 2, j_ = c & 3;                                                    \
    int col_ = ((kt_) << 6) + ((kh_) << 5) + ((j_ ^ (row_ & 3)) << 3);                \
    gl2l(W_ + (size_t)(n0 + row_) * (ldw_) + col_,                                    \
         Bs + ((((buf_) << 1) + (kh_)) * 8192) + (c << 3));                           \
  }

#define LOAD_A(BM_, buf_, ks_)                                                        \
  _Pragma("unroll")                                                                   \
  for (int i = 0; i < (BM_) / 32; i++) {                                              \
    int ra = wm + (i << 4) + li;                                                      \
    af[i] = *(const bf16x8*)(As + ((((buf_) << 1) + (ks_)) * ((BM_) * 32))            \
             + ra * 32 + ((g ^ (ra & 3)) << 3));                                      \
  }

#define LOAD_B(buf_, ks_, qn_)                                                        \
  _Pragma("unroll")                                                                   \
  for (int jj = 0; jj < 2; jj++) {                                                    \
    int rb = wn + ((qn_) << 5) + (jj << 4) + li;                                      \
    bw[jj] = *(const bf16x8*)(Bs + ((((buf_) << 1) + (ks_)) * 8192)                   \
             + rb * 32 + ((g ^ (rb & 3)) << 3));                                      \
  }

#define MFMA_Q(BM_, qn_)                                                              \
  __builtin_amdgcn_s_setprio(1);                                                      \
  _Pragma("unroll")                                                                   \
  for (int i = 0; i < (BM_) / 32; i++) {                                              \
    acc[i][((qn_) << 1)]     = __builtin_amdgcn_mfma_f32_16x16x32_bf16(af[i], bw[0], acc[i][((qn_) << 1)], 0, 0, 0);     \
    acc[i][((qn_) << 1) + 1] = __builtin_amdgcn_mfma_f32_16x16x32_bf16(af[i], bw[1], acc[i][((qn_) << 1) + 1], 0, 0, 0); \
  }                                                                                   \
  __builtin_amdgcn_s_setprio(0);

#define PH_SYNC                                                                       \
  __builtin_amdgcn_s_barrier();                                                       \
  asm volatile("s_waitcnt lgkmcnt(0)" ::: "memory");                                  \
  __builtin_amdgcn_sched_barrier(0);

#define PH_END __builtin_amdgcn_s_barrier();

#define GEMM_PIPE(BM_, A_, lda_, W_, ldw_, K_)                                        \
  const int w = tid >> 6, lane = tid & 63, g = lane >> 4, li = lane & 15;             \
  const int wm = (w >> 2) * ((BM_) / 2), wn = (w & 3) << 6;                           \
  constexpr int MI_ = (BM_) / 32;                                                     \
  constexpr int VMC = (BM_) / 128 + 2;                                                \
  f32x4 acc[MI_][4];                                                                  \
  _Pragma("unroll")                                                                   \
  for (int i = 0; i < MI_; i++)                                                       \
    _Pragma("unroll")                                                                 \
    for (int j = 0; j < 4; j++) acc[i][j] = (f32x4)0.f;                               \
  /* prologue: tile0 all 4 pieces + tile1 k0 pair */                                  \
  STAGE_A(BM_, A_, lda_, 0, 0, 0) STAGE_B(W_, ldw_, 0, 0, 0)                          \
  STAGE_A(BM_, A_, lda_, 0, 1, 0) STAGE_B(W_, ldw_, 0, 1, 0)                          \
  STAGE_A(BM_, A_, lda_, 1, 0, 1) STAGE_B(W_, ldw_, 1, 0, 1)                          \
  asm volatile("s_waitcnt vmcnt(%0)" :: "i"(VMC) : "memory");                         \
  __builtin_amdgcn_s_barrier();                                                       \
  const int NT = (K_) >> 6;                                                           \
  bf16x8 af[MI_], bw[2];                                                              \
  for (int t = 0; t < NT; t++) {                                                      \
    const int buf = t & 1, nbuf = buf ^ 1;                                            \
    const bool sB = (t + 1 < NT);   /* stage tile t+1 k1 pieces   */                  \
    const bool sA = (t + 2 < NT);   /* stage tile t+2 k0 pieces   */                  \
    /* phase 0: kstep0, qn0 */                                                        \
    LOAD_A(BM_, buf, 0) LOAD_B(buf, 0, 0)                                             \
    if (sB) { STAGE_A(BM_, A_, lda_, t + 1, 1, nbuf) }                                \
    PH_SYNC MFMA_Q(BM_, 0) PH_END                                                     \
    /* phase 1: kstep0, qn1 (reuse af) */                                             \
    LOAD_B(buf, 0, 1)                                                                 \
    if (sB) {                                                                         \
      STAGE_B(W_, ldw_, t + 1, 1, nbuf)                                               \
      asm volatile("s_waitcnt vmcnt(%0)" :: "i"(VMC) : "memory");                     \
    } else {                                                                          \
      asm volatile("s_waitcnt vmcnt(0)" ::: "memory");                                \
    }                                                                                 \
    PH_SYNC MFMA_Q(BM_, 1) PH_END                                                     \
    /* phase 2: kstep1, qn0 (k0 pieces of tile t now dead -> overwrite) */            \
    LOAD_A(BM_, buf, 1) LOAD_B(buf, 1, 0)                                             \
    if (sA) { STAGE_A(BM_, A_, lda_, t + 2, 0, buf) }                                 \
    PH_SYNC MFMA_Q(BM_, 0) PH_END                                                     \
    /* phase 3: kstep1, qn1 */                                                        \
    LOAD_B(buf, 1, 1)                                                                 \
    if (sA) {                                                                         \
      STAGE_B(W_, ldw_, t + 2, 0, buf)                                                \
      asm volatile("s_waitcnt vmcnt(%0)" :: "i"(VMC) : "memory");                     \
    } else if (t + 1 < NT) {                                                          \
      asm volatile("s_waitcnt vmcnt(0)" ::: "memory");                                \
    }                                                                                 \
    PH_SYNC MFMA_Q(BM_, 1) PH_END                                                     \
  }

// Launch A: blocks 0..255: xn@w1122 (256x256, N=4096, gelu, split bias) -> h12
//           blocks 256..511: ynk@wk1 (128x256, N=2048, gelu) -> h3
__launch_bounds__(512, 2)
__global__ void gemm_mlp1(const __bf16* __restrict__ xn, const __bf16* __restrict__ ynk,
                          const __bf16* __restrict__ w1122, const __bf16* __restrict__ wk1,
                          const float* __restrict__ qb1, const float* __restrict__ qb2,
                          const float* __restrict__ kb1,
                          __bf16* __restrict__ h12, __bf16* __restrict__ h3) {
  __shared__ __align__(16) __bf16 As[2 * 2 * 256 * 32];
  __shared__ __align__(16) __bf16 Bs[2 * 2 * 256 * 32];
  const int tid = threadIdx.x, bid = blockIdx.x;
  if (bid < 256) {
    const int m0 = (bid >> 4) << 8, n0 = (bid & 15) << 8;
    GEMM_PIPE(256, xn, 1024, w1122, 1024, 1024)
    #pragma unroll
    for (int j = 0; j < 4; j++) {
      int n = n0 + wn + (j << 4) + li;
      float bias = (n < 2048) ? qb1[n] : qb2[n - 2048];
      #pragma unroll
      for (int i = 0; i < MI_; i++) {
        #pragma unroll
        for (int r = 0; r < 4; r++) {
          int m = m0 + wm + (i << 4) + (g << 2) + r;
          h12[(size_t)m * 4096 + n] = (__bf16)gelu_f(acc[i][j][r] + bias);
        }
      }
    }
  } else {
    const int rr = bid - 256;
    const int m0 = (rr >> 3) << 7, n0 = (rr & 7) << 8;
    GEMM_PIPE(128, ynk, 1024, wk1, 1024, 1024)
    #pragma unroll
    for (int j = 0; j < 4; j++) {
      int n = n0 + wn + (j << 4) + li;
      float bias = kb1[n];
      #pragma unroll
      for (int i = 0; i < MI_; i++) {
        #pragma unroll
        for (int r = 0; r < 4; r++) {
          int m = m0 + wm + (i << 4) + (g << 2) + r;
          h3[(size_t)m * 2048 + n] = (__bf16)gelu_f(acc[i][j][r] + bias);
        }
      }
    }
  }
}

// Launch B: seg0 x1=h1@w12, seg1 x2=h2@w22, seg2 y1=h3@wk2 (K=2048), seg3 vT=ynv@wv (K=1024)
__launch_bounds__(512, 2)
__global__ void gemm_mlp2(const __bf16* __restrict__ h12, const __bf16* __restrict__ h3,
                          const __bf16* __restrict__ ynv,
                          const __bf16* __restrict__ w12, const __bf16* __restrict__ w22,
                          const __bf16* __restrict__ wk2, const __bf16* __restrict__ wv,
                          const float* __restrict__ bx1, const float* __restrict__ bx2,
                          const float* __restrict__ by1, const float* __restrict__ bv,
                          __bf16* __restrict__ x1, __bf16* __restrict__ x2,
                          __bf16* __restrict__ y1, __bf16* __restrict__ vT) {
  __shared__ __align__(16) __bf16 As[2 * 2 * 256 * 32];
  __shared__ __align__(16) __bf16 Bs[2 * 2 * 256 * 32];
  const int tid = threadIdx.x, bid = blockIdx.x;
  const int seg = bid >> 6, rr = bid & 63;
  const int m0 = (rr >> 2) << 8, n0 = (rr & 3) << 8;
  const __bf16* A; const __bf16* W; const float* bias; __bf16* out; int lda, K;
  if      (seg == 0) { A = h12;        lda = 4096; W = w12; bias = bx1; out = x1; K = 2048; }
  else if (seg == 1) { A = h12 + 2048; lda = 4096; W = w22; bias = bx2; out = x2; K = 2048; }
  else if (seg == 2) { A = h3;         lda = 2048; W = wk2; bias = by1; out = y1; K = 2048; }
  else               { A = ynv;        lda = 1024; W = wv;  bias = bv;  out = vT; K = 1024; }
  GEMM_PIPE(256, A, lda, W, K, K)
  #pragma unroll
  for (int j = 0; j < 4; j++) {
    int n = n0 + wn + (j << 4) + li;
    float bs = bias[n];
    #pragma unroll
    for (int i = 0; i < MI_; i++) {
      #pragma unroll
      for (int r = 0; r < 4; r++) {
        int m = m0 + wm + (i << 4) + (g << 2) + r;
        float v = acc[i][j][r] + bs;
        if (seg == 3) {        // vT: [B*H][64][2048]
          int bb = m >> 11, l = m & 2047, hh = n >> 6, cc = n & 63;
          vT[(((size_t)(bb * Hh + hh) * 64 + cc) << 11) + l] = (__bf16)v;
        } else {
          out[(size_t)m * 1024 + n] = (__bf16)v;
        }
      }
    }
  }
}

// ---------------- merged build q + k (vectorized swizzled stores) ----------------
__launch_bounds__(256)
__global__ void build_qk(const __bf16* __restrict__ x1, const __bf16* __restrict__ x2,
                         const float* __restrict__ xp,
                         const __bf16* __restrict__ y1, const float* __restrict__ yp,
                         const float* __restrict__ pw1, const float* __restrict__ pb1,
                         const float* __restrict__ pw2, const float* __restrict__ pb2,
                         __bf16* __restrict__ q_ws, __bf16* __restrict__ k_ws) {
  const bool isq = blockIdx.x < 2048;
  const int bid = isq ? blockIdx.x : blockIdx.x - 2048;
  const int t = (bid << 1) + (threadIdx.x >> 7);
  const int tl = threadIdx.x & 127;
  const int b = t >> 11, n = t & 2047;
  const int hh = tl >> 3, ch = tl & 7;
  const int e0 = (hh << 6) + (ch << 3);
  const float* pos = isq ? xp : yp;
  const float p0 = pos[(size_t)t*4], p1 = pos[(size_t)t*4+1],
              p2 = pos[(size_t)t*4+2], p3 = pos[(size_t)t*4+3];
  bf16x8 o0, o1, o2, o3;
  if (isq) {
    bf16x8 v1 = *(const bf16x8*)(x1 + (size_t)t * Ee + e0);
    bf16x8 v2 = *(const bf16x8*)(x2 + (size_t)t * Ee + e0);
    #pragma unroll
    for (int sub = 0; sub < 8; sub++) {
      int e = e0 + sub;
      float a1 = pw1[e*4]*p0 + pw1[e*4+1]*p1 + pw1[e*4+2]*p2 + pw1[e*4+3]*p3 + pb1[e];
      float a2 = pw2[e*4]*p0 + pw2[e*4+1]*p1 + pw2[e*4+2]*p2 + pw2[e*4+3]*p3 + pb2[e];
      float s1, c1, s2, c2;
      __sincosf(a1, &s1, &c1); __sincosf(a2, &s2, &c2);
      float xv1 = (float)v1[sub], xv2 = (float)v2[sub];
      o0[sub] = (__bf16)(xv1 * c1); o1[sub] = (__bf16)(xv1 * s1);
      o2[sub] = (__bf16)(xv2 * c2); o3[sub] = (__bf16)(xv2 * s2);
    }
  } else {
    bf16x8 v1 = *(const bf16x8*)(y1 + (size_t)t * Ee + e0);
    #pragma unroll
    for (int sub = 0; sub < 8; sub++) {
      int e = e0 + sub;
      float a1 = pw1[e*4]*p0 + pw1[e*4+1]*p1 + pw1[e*4+2]*p2 + pw1[e*4+3]*p3;
      float a2 = pw2[e*4]*p0 + pw2[e*4+1]*p1 + pw2[e*4+2]*p2 + pw2[e*4+3]*p3;
      float s1, c1, s2, c2;
      __sincosf(a1, &s1, &c1); __sincosf(a2, &s2, &c2);
      float yv = (float)v1[sub];
      o0[sub] = (__bf16)(yv * c1); o1[sub] = (__bf16)(yv * s1);
      o2[sub] = (__bf16)c2;        o3[sub] = (__bf16)s2;
    }
  }
  const int k = n & 7, bc = ch ^ k;
  __bf16* base = (isq ? q_ws : k_ws) + ((((size_t)b * Hh + hh) * Nn + n) << 8);
  *(bf16x8*)(base + ((bc          ) << 3)) = o0;
  *(bf16x8*)(base + (((8  ^ k) ^ ch) << 3)) = o1;
  *(bf16x8*)(base + (((16 ^ k) ^ ch) << 3)) = o2;
  *(bf16x8*)(base + (((24 ^ k) ^ ch) << 3)) = o3;
}

// ---------------- fused flash attention (single QK^T pass, no max) ----------------
__launch_bounds__(512, 1)
__global__ void attn_fused(const __bf16* __restrict__ q_ws, const __bf16* __restrict__ k_ws,
                           const __bf16* __restrict__ vT_ws, const __bf16* __restrict__ ypT_g,
                           const __bf16* __restrict__ mask_bf, const float* __restrict__ xp,
                           __bf16* __restrict__ em_g, float* __restrict__ dinv_g,
                           __bf16* __restrict__ avz) {
  __shared__ __align__(16) __bf16 kq[2][32 * 256];   // 32 KB
  __shared__ __align__(16) __bf16 ms[2][256 * 32];   // 32 KB
  __shared__ __align__(16) __bf16 vt[2][64 * 40];    // 10 KB
  __shared__ __align__(16) __bf16 pT[256 * 40];      // 20 KB
  __shared__ __align__(16) __bf16 ypl[2][16 * 40];   // 2.5 KB
  const int tid = threadIdx.x, w = tid >> 6, lane = tid & 63, g = lane >> 4, li = lane & 15;
  const int logical = ((blockIdx.x & 7) << 5) + (blockIdx.x >> 3);  // XCD-chunked
  const int bh = logical >> 3, nt = logical & 7;
  const int b = bh >> 4, h = bh & 15;
  const int n0 = nt << 8;
  const __bf16* qb = q_ws + (((size_t)bh * Nn + n0) << 8);
  const __bf16* kb = k_ws + (((size_t)bh * Ll) << 8);
  const __bf16* vb = vT_ws + ((size_t)bh << 17);
  const __bf16* yb = ypT_g + ((size_t)b << 13);
  const __bf16* mb = mask_bf + ((size_t)n0 << 11);

  bf16x8 aq[2][8];
  #pragma unroll
  for (int rf = 0; rf < 2; rf++) {
    const int nloc = (w << 5) + (rf << 4) + li;
    #pragma unroll
    for (int s = 0; s < 8; s++)
      aq[rf][s] = *(const bf16x8*)(qb + ((size_t)nloc << 8) + ((((s << 2) + g) ^ (nloc & 7)) << 3));
  }
  for (int i = tid; i < 960; i += 512) {
    int buf = i / 480, idx = i - buf * 480;
    ypl[buf][160 + idx] = (__bf16)0.f;
  }
  {
    const int vc = tid >> 3, vl = (tid & 7) << 2;
    bf16x4v vreg = *(const bf16x4v*)(vb + ((size_t)vc << 11) + vl);
    bf16x4v ypreg;
    if (tid < 32) ypreg = *(const bf16x4v*)(yb + ((size_t)(tid >> 3) << 11) + ((tid & 7) << 2));
    #pragma unroll
    for (int j = 0; j < 2; j++) {
      int c = (j << 9) + tid;
      gl2l(kb + (size_t)(c >> 5) * 256 + ((c & 31) << 3), kq[0] + ((c - lane) << 3));
      gl2l(mb + (size_t)(c >> 2) * 2048 + ((c & 3) << 3), ms[0] + ((c - lane) << 3));
    }
    *(bf16x4v*)(vt[0] + vc * 40 + vl) = vreg;
    if (tid < 32) *(bf16x4v*)(ypl[0] + (tid >> 3) * 40 + ((tid & 7) << 2)) = ypreg;
  }
  __syncthreads();

  float se[2][4], te[2][4];
  f32x4 accv[2][4], accp[2];
  #pragma unroll
  for (int rf = 0; rf < 2; rf++) {
    #pragma unroll
    for (int r = 0; r < 4; r++) { se[rf][r] = 0.f; te[rf][r] = 0.f; }
    #pragma unroll
    for (int cb = 0; cb < 4; cb++) accv[rf][cb] = (f32x4)0.f;
    accp[rf] = (f32x4)0.f;
  }

  for (int t = 0; t < 64; ++t) {
    const int l0 = t << 5, cur = t & 1, nxt = cur ^ 1;
    const bool more = (t < 63);
    bf16x4v vreg, ypreg;
    if (more) {
      const int l1 = l0 + 32;
      vreg = *(const bf16x4v*)(vb + ((size_t)(tid >> 3) << 11) + l1 + ((tid & 7) << 2));
      if (tid < 32) ypreg = *(const bf16x4v*)(yb + ((size_t)(tid >> 3) << 11) + l1 + ((tid & 7) << 2));
      #pragma unroll
      for (int j = 0; j < 2; j++) {
        int c = (j << 9) + tid;
        gl2l(kb + (size_t)(l1 + (c >> 5)) * 256 + ((c & 31) << 3), kq[nxt] + ((c - lane) << 3));
        gl2l(mb + (size_t)(c >> 2) * 2048 + l1 + ((c & 3) << 3), ms[nxt] + ((c - lane) << 3));
      }
    }
    f32x4 Cs[2][2];
    Cs[0][0] = (f32x4)0.f; Cs[0][1] = (f32x4)0.f; Cs[1][0] = (f32x4)0.f; Cs[1][1] = (f32x4)0.f;
    #pragma unroll
    for (int lb = 0; lb < 2; lb++) {
      const int kr = (lb << 4) + li;
      #pragma unroll
      for (int s = 0; s < 8; s++) {
        bf16x8 bk = *(const bf16x8*)(kq[cur] + kr * 256 + ((((s << 2) + g) ^ (kr & 7)) << 3));
        Cs[0][lb] = __builtin_amdgcn_mfma_f32_16x16x32_bf16(aq[0][s], bk, Cs[0][lb], 0, 0, 0);
        Cs[1][lb] = __builtin_amdgcn_mfma_f32_16x16x32_bf16(aq[1][s], bk, Cs[1][lb], 0, 0, 0);
      }
    }
    #pragma unroll
    for (int rf = 0; rf < 2; rf++) {
      #pragma unroll
      for (int lb = 0; lb < 2; lb++) {
        #pragma unroll
        for (int r = 0; r < 4; r++) {
          const int row = (w << 5) + (rf << 4) + (g << 2) + r;
          float e = __expf(Cs[rf][lb][r] * SCALE);
          float mkv = (float)ms[cur][row * 32 + (lb << 4) + li];
          float em = e * mkv;
          se[rf][r] += e; te[rf][r] += em;
          pT[row * 40 + (lb << 4) + li] = (__bf16)em;
        }
      }
    }
    asm volatile("s_waitcnt lgkmcnt(0)" ::: "memory");
    __builtin_amdgcn_sched_barrier(0);
    #pragma unroll
    for (int j = 0; j < 2; j++) {
      int q = (j << 6) + lane;
      int row = q >> 2, ch = q & 3;
      bf16x8 pv = *(const bf16x8*)(pT + ((w << 5) + row) * 40 + (ch << 3));
      *(bf16x8*)(em_g + ((size_t)bh << 22) + ((size_t)(n0 + (w << 5) + row) << 11) + l0 + (ch << 3)) = pv;
    }
    bf16x8 vv[4];
    #pragma unroll
    for (int cb = 0; cb < 4; cb++)
      vv[cb] = *(const bf16x8*)(vt[cur] + ((cb << 4) + li) * 40 + (g << 3));
    bf16x8 yy = *(const bf16x8*)(ypl[cur] + li * 40 + (g << 3));
    #pragma unroll
    for (int rf = 0; rf < 2; rf++) {
      bf16x8 pa = *(const bf16x8*)(pT + ((w << 5) + (rf << 4) + li) * 40 + (g << 3));
      #pragma unroll
      for (int cb = 0; cb < 4; cb++)
        accv[rf][cb] = __builtin_amdgcn_mfma_f32_16x16x32_bf16(pa, vv[cb], accv[rf][cb], 0, 0, 0);
      accp[rf] = __builtin_amdgcn_mfma_f32_16x16x32_bf16(pa, yy, accp[rf], 0, 0, 0);
    }
    if (more) {
      *(bf16x4v*)(vt[nxt] + (tid >> 3) * 40 + ((tid & 7) << 2)) = vreg;
      if (tid < 32) *(bf16x4v*)(ypl[nxt] + (tid >> 3) * 40 + ((tid & 7) << 2)) = ypreg;
    }
    __syncthreads();
  }

  #pragma unroll
  for (int rf = 0; rf < 2; rf++) {
    #pragma unroll
    for (int r = 0; r < 4; r++) {
      float s = se[rf][r], tt = te[rf][r];
      #pragma unroll
      for (int o = 1; o < 16; o <<= 1) { s += __shfl_xor(s, o); tt += __shfl_xor(tt, o); }
      float dinv = 1.f / (tt + 1e-8f * s);
      const int n = n0 + (w << 5) + (rf << 4) + (g << 2) + r;
      if (li == 0) dinv_g[((size_t)bh << 11) + n] = dinv;
      #pragma unroll
      for (int cb = 0; cb < 4; cb++)
        avz[((size_t)b * Nn + n) * 1088 + (h << 6) + (cb << 4) + li] = (__bf16)(accv[rf][cb][r] * dinv);
      if (li < 4) {
        float z = accp[rf][r] * dinv - xp[(((size_t)b * Nn + n) << 2) + li];
        avz[((size_t)b * Nn + n) * 1088 + 1024 + (h << 2) + li] = (__bf16)z;
      }
    }
  }
}

// ---------------- merged finalize + output projection ----------------
__launch_bounds__(256)
__global__ void fin_proj(const __bf16* __restrict__ A, const __bf16* __restrict__ W,
                         const float* __restrict__ bias1, const float* __restrict__ bias2,
                         float* __restrict__ out,
                         const __bf16* __restrict__ em_g, const float* __restrict__ dinv_g,
                         float* __restrict__ attn_out,
                         const float* __restrict__ xp, float* __restrict__ xp_out) {
  constexpr int N = 1024, K = 1088;
  __shared__ __align__(16) __bf16 As[2][128 * 32];
  __shared__ __align__(16) __bf16 Bs[2][64 * 32];
  const int tid = threadIdx.x;
  if (blockIdx.x >= 512) {
    const int sbid = blockIdx.x - 512;
    if (sbid < 64) {
      int idx = sbid * 256 + tid;
      ((float4*)xp_out)[idx] = ((const float4*)xp)[idx];
    }
    for (size_t i8 = sbid * 256ul + tid; i8 < 16777216ul; i8 += 524288ul) {
      bf16x8 v = ((const bf16x8*)em_g)[i8];
      float dv = dinv_g[i8 >> 8];
      float4 o0, o1;
      o0.x = (float)v[0] * dv; o0.y = (float)v[1] * dv; o0.z = (float)v[2] * dv; o0.w = (float)v[3] * dv;
      o1.x = (float)v[4] * dv; o1.y = (float)v[5] * dv; o1.z = (float)v[6] * dv; o1.w = (float)v[7] * dv;
      ((float4*)attn_out)[i8 * 2]     = o0;
      ((float4*)attn_out)[i8 * 2 + 1] = o1;
    }
    return;
  }
  const int w = tid >> 6, lane = tid & 63, g = lane >> 4, li = lane & 15;
  const int bt = blockIdx.x >> 4;
  const int m0 = bt << 7, n0 = (blockIdx.x & 15) << 6;
  const int wm = (w >> 1) << 6, wn = (w & 1) << 5;
  f32x4 acc[4][2];
  #pragma unroll
  for (int i = 0; i < 4; i++) { acc[i][0] = (f32x4)0.f; acc[i][1] = (f32x4)0.f; }
  auto stage = [&](int buf, int kt) {
    const int col0 = kt << 5;
    #pragma unroll
    for (int j = 0; j < 2; j++) {
      int c = (j << 8) + tid;
      int row = c >> 2, sl = c & 3;
      int col = col0 + ((sl ^ (row & 3)) << 3);
      gl2l(A + (size_t)(m0 + row) * K + col, As[buf] + ((c - lane) << 3));
    }
    {
      int c = tid;
      int row = c >> 2, sl = c & 3;
      int col = col0 + ((sl ^ (row & 3)) << 3);
      gl2l(W + (size_t)(n0 + row) * K + col, Bs[buf] + ((c - lane) << 3));
    }
  };
  const int NT = K >> 5;   // 34
  stage(0, 0);
  for (int kt = 0; kt < NT; kt++) {
    const int cur = kt & 1;
    if (kt + 1 < NT) {
      stage(cur ^ 1, kt + 1);
      asm volatile("s_waitcnt vmcnt(3)" ::: "memory");
    } else {
      asm volatile("s_waitcnt vmcnt(0)" ::: "memory");
    }
    __builtin_amdgcn_s_barrier();
    __builtin_amdgcn_sched_barrier(0);
    bf16x8 af[4], bw[2];
    #pragma unroll
    for (int i = 0; i < 4; i++) {
      int ra = wm + (i << 4) + li;
      af[i] = *(const bf16x8*)(As[cur] + ra * 32 + ((g ^ (ra & 3)) << 3));
    }
    #pragma unroll
    for (int j = 0; j < 2; j++) {
      int rb = wn + (j << 4) + li;
      bw[j] = *(const bf16x8*)(Bs[cur] + rb * 32 + ((g ^ (rb & 3)) << 3));
    }
    #pragma unroll
    for (int i = 0; i < 4; i++)
      #pragma unroll
      for (int j = 0; j < 2; j++)
        acc[i][j] = __builtin_amdgcn_mfma_f32_16x16x32_bf16(af[i], bw[j], acc[i][j], 0, 0, 0);
    asm volatile("s_waitcnt lgkmcnt(0)" ::: "memory");
    __builtin_amdgcn_sched_barrier(0);
    __builtin_amdgcn_s_barrier();
  }
  #pragma unroll
  for (int j = 0; j < 2; j++) {
    int n = n0 + wn + (j << 4) + li;
    float bias = bias1[n] + bias2[n];
    #pragma unroll
    for (int i = 0; i < 4; i++) {
      #pragma unroll
      for (int r = 0; r < 4; r++) {
        int m = m0 + wm + (i << 4) + (g << 2) + r;
        out[(size_t)m * N + n] = acc[i][j][r] + bias;
      }
    }
  }
}

// ---------------- host ----------------
extern "C" void kernel_launch(void* const* d_in, const int* in_sizes, int n_in,
                              void* d_out, int out_size, void* d_ws, size_t ws_size,
                              hipStream_t stream) {
  (void)in_sizes; (void)n_in; (void)out_size; (void)ws_size;
  const float* x       = (const float*)d_in[0];
  const float* xp      = (const float*)d_in[1];
  const float* y       = (const float*)d_in[2];
  const float* yp      = (const float*)d_in[3];
  const float* mask    = (const float*)d_in[4];
  const float* p_w1    = (const float*)d_in[5];
  const float* p_b1    = (const float*)d_in[6];
  const float* p_w2    = (const float*)d_in[7];
  const float* p_b2    = (const float*)d_in[8];
  const float* q_ln_g  = (const float*)d_in[9];
  const float* q_ln_b  = (const float*)d_in[10];
  const float* q_m1_w1 = (const float*)d_in[11];
  const float* q_m1_b1 = (const float*)d_in[12];
  const float* q_m1_w2 = (const float*)d_in[13];
  const float* q_m1_b2 = (const float*)d_in[14];
  const float* q_m2_w1 = (const float*)d_in[15];
  const float* q_m2_b1 = (const float*)d_in[16];
  const float* q_m2_w2 = (const float*)d_in[17];
  const float* q_m2_b2 = (const float*)d_in[18];
  const float* k_ln_g  = (const float*)d_in[19];
  const float* k_ln_b  = (const float*)d_in[20];
  const float* k_m1_w1 = (const float*)d_in[21];
  const float* k_m1_b1 = (const float*)d_in[22];
  const float* k_m1_w2 = (const float*)d_in[23];
  const float* k_m1_b2 = (const float*)d_in[24];
  const float* v_ln_g  = (const float*)d_in[25];
  const float* v_ln_b  = (const float*)d_in[26];
  const float* v_w     = (const float*)d_in[27];
  const float* v_b     = (const float*)d_in[28];
  const float* proj1_w = (const float*)d_in[29];
  const float* proj1_b = (const float*)d_in[30];
  const float* proj2_w = (const float*)d_in[31];
  const float* proj2_b = (const float*)d_in[32];

  char* ws = (char*)d_ws;
  __bf16* xn    = (__bf16*)(ws + OFF_XN);
  __bf16* ynk   = (__bf16*)(ws + OFF_YNK);
  __bf16* ynv   = (__bf16*)(ws + OFF_YNV);
  __bf16* h12   = (__bf16*)(ws + OFF_H12);
  __bf16* h3    = (__bf16*)(ws + OFF_H3);
  __bf16* x1    = (__bf16*)(ws + OFF_X1);
  __bf16* x2    = (__bf16*)(ws + OFF_X2);
  __bf16* y1    = (__bf16*)(ws + OFF_Y1);
  __bf16* q_ws  = (__bf16*)(ws + OFF_QWS);
  __bf16* k_ws  = (__bf16*)(ws + OFF_KWS);
  __bf16* vT_ws = (__bf16*)(ws + OFF_VWS);
  float*  dinv  = (float*)(ws + OFF_DNV);
  __bf16* ypT   = (__bf16*)(ws + OFF_YPT);
  __bf16* mskb  = (__bf16*)(ws + OFF_MSK);
  __bf16* avz   = (__bf16*)(ws + OFF_AVZ);
  __bf16* w1122 = (__bf16*)(ws + OFF_W1122);
  __bf16* w12   = (__bf16*)(ws + OFF_W12);
  __bf16* w22   = (__bf16*)(ws + OFF_W22);
  __bf16* wk1   = (__bf16*)(ws + OFF_WK1);
  __bf16* wk2   = (__bf16*)(ws + OFF_WK2);
  __bf16* wv    = (__bf16*)(ws + OFF_WV);
  __bf16* wp    = (__bf16*)(ws + OFF_WP);
  __bf16* em    = (__bf16*)(ws + OFF_EM);

  float* out0     = (float*)d_out;
  float* attn_out = out0 + (size_t)4194304;
  float* xp_out   = out0 + (size_t)138412032;

  // 1. prep (weights + fused proj + mask bf16 + ypT)
  prep_all<<<18512, 256, 0, stream>>>(q_m1_w1, q_m2_w1, q_m1_w2, q_m2_w2, k_m1_w1, k_m1_w2, v_w,
                                      w1122, w1122 + 2097152, w12, w22, wk1, wk2, wv,
                                      proj1_w, proj2_w, wp, mask, mskb, yp, ypT);
  // 2. layernorms
  ln_all<<<8192, 256, 0, stream>>>(x, y, q_ln_g, q_ln_b, k_ln_g, k_ln_b, v_ln_g, v_ln_b,
                                   xn, ynk, ynv);
  // 3. mlp stage 1 (4-phase interleaved pipeline)
  gemm_mlp1<<<512, 512, 0, stream>>>(xn, ynk, w1122, wk1, q_m1_b1, q_m2_b1, k_m1_b1, h12, h3);
  // 4. mlp stage 2 + V projection (4-phase interleaved pipeline, 256 blocks = 1/CU)
  gemm_mlp2<<<256, 512, 0, stream>>>(h12, h3, ynv, w12, w22, wk2, wv,
                                     q_m1_b2, q_m2_b2, k_m1_b2, v_b, x1, x2, y1, vT_ws);
  // 5. q/k assembly
  build_qk<<<4096, 256, 0, stream>>>(x1, x2, xp, y1, yp, p_w1, p_b1, p_w2, p_b2, q_ws, k_ws);
  // 6. fused flash attention (256 q-rows/block, 1 block/CU)
  attn_fused<<<256, 512, 0, stream>>>(q_ws, k_ws, vT_ws, ypT, mskb, xp, em, dinv, avz);
  // 7. merged finalize (attn = em*dinv + xp passthrough) + output projection
  fin_proj<<<2560, 256, 0, stream>>>(avz, wp, proj1_b, proj2_b, out0,
                                     em, dinv, attn_out, xp, xp_out);
}

// Round 10
// 689.098 us; speedup vs baseline: 1.0649x; 1.0079x over previous
//
#include <hip/hip_runtime.h>
#include <math.h>
#include <stdint.h>

#define DEV static __device__ __forceinline__

typedef __bf16 bf16x8 __attribute__((ext_vector_type(8)));
typedef __bf16 bf16x4v __attribute__((ext_vector_type(4)));
typedef float f32x4 __attribute__((ext_vector_type(4)));

// problem dims
constexpr int Nn = 2048, Ll = 2048, Ee = 1024, Hh = 16;
constexpr float SCALE = 0.0625f;   // (4C)^-0.5 = 1/16

// ---------------- workspace layout (bytes) ----------------
constexpr size_t OFF_XN   = 0;                    // [4096][1024] bf16
constexpr size_t OFF_YNK  = 8388608;
constexpr size_t OFF_YNV  = 16777216;
constexpr size_t OFF_H12  = 25165824;             // [4096][4096] bf16
constexpr size_t OFF_H3   = 58720256;             // [4096][2048] bf16
constexpr size_t OFF_X1   = 75497472;             // [4096][1024] bf16
constexpr size_t OFF_X2   = 83886080;
constexpr size_t OFF_Y1   = 92274688;
constexpr size_t OFF_QWS  = 100663296;            // [B][H][N][256] bf16, pre-swizzled
constexpr size_t OFF_KWS  = 134217728;            // [B][H][L][256] bf16, pre-swizzled
constexpr size_t OFF_VWS  = 167772160;            // vT: [B*H][64][2048] bf16
constexpr size_t OFF_DNV  = 176160768;            // f32 [B*H*N]
constexpr size_t OFF_YPT  = 176422912;            // ypT [B][4][2048] bf16
constexpr size_t OFF_MSK  = 176685056;            // mask bf16 [2048][2048]
constexpr size_t OFF_AVZ  = 185073664;            // [4096][1088] bf16
constexpr size_t OFF_W1122= 193986560;            // [4096][1024] bf16 (w11 ; w21)
constexpr size_t OFF_W12  = 202375168;
constexpr size_t OFF_W22  = 206569472;
constexpr size_t OFF_WK1  = 210763776;
constexpr size_t OFF_WK2  = 214958080;
constexpr size_t OFF_WV   = 219152384;
constexpr size_t OFF_WP   = 221249536;            // [1024][1088] bf16
constexpr size_t OFF_EM   = 223477760;            // em bf16, 268 MB

DEV void gl2l(const void* g, void* l) {
  __builtin_amdgcn_global_load_lds((const __attribute__((address_space(1))) void*)g,
                                   (__attribute__((address_space(3))) void*)l, 16, 0, 0);
}

// exact-erf GELU via Abramowitz-Stegun 7.1.26 (|eps|<1.5e-7, way below bf16)
DEV float gelu_f(float v) {
  float x = v * 0.70710678118654752f;
  float ax = fabsf(x);
  float t = 1.f / fmaf(0.3275911f, ax, 1.f);
  float y = t * fmaf(t, fmaf(t, fmaf(t, fmaf(t, 1.061405429f, -1.453152027f),
                                     1.421413741f), -0.284496736f), 0.254829592f);
  float er = 1.f - y * __expf(-x * x);
  er = (x < 0.f) ? -er : er;
  return 0.5f * v * (1.f + er);
}

// ---------------- merged prep (weights + proj + mask + ypT) + LayerNorms ----------------
// blocks 0..18511: prep work; blocks 18512..26703: LN rows (x then y).
__launch_bounds__(256)
__global__ void prep_ln(const float* __restrict__ s0, const float* __restrict__ s1,
                        const float* __restrict__ s2, const float* __restrict__ s3,
                        const float* __restrict__ s4, const float* __restrict__ s5,
                        const float* __restrict__ s6,
                        __bf16* __restrict__ d0, __bf16* __restrict__ d1,
                        __bf16* __restrict__ d2, __bf16* __restrict__ d3,
                        __bf16* __restrict__ d4, __bf16* __restrict__ d5,
                        __bf16* __restrict__ d6,
                        const float* __restrict__ pw1, const float* __restrict__ pw2,
                        __bf16* __restrict__ wp,
                        const float* __restrict__ mask, __bf16* __restrict__ mb,
                        const float* __restrict__ yp, __bf16* __restrict__ ypT,
                        const float* __restrict__ x, const float* __restrict__ y,
                        const float* __restrict__ qg, const float* __restrict__ qb,
                        const float* __restrict__ kg, const float* __restrict__ kb,
                        const float* __restrict__ vg, const float* __restrict__ vb,
                        __bf16* __restrict__ xn, __bf16* __restrict__ ynk,
                        __bf16* __restrict__ ynv) {
  const int tid = threadIdx.x;
  if (blockIdx.x >= 18512) {
    // ---------- LayerNorm segment ----------
    const int t = blockIdx.x - 18512;
    const bool isx = t < 4096;
    const int row = isx ? t : t - 4096;
    const float* src = (isx ? x : y) + (size_t)row * Ee;
    const float4 v = ((const float4*)src)[tid];
    float s = v.x + v.y + v.z + v.w;
    float q = v.x*v.x + v.y*v.y + v.z*v.z + v.w*v.w;
    #pragma unroll
    for (int o = 32; o > 0; o >>= 1) { s += __shfl_down(s, o); q += __shfl_down(q, o); }
    __shared__ float ls[4], lq[4];
    if ((tid & 63) == 0) { ls[tid >> 6] = s; lq[tid >> 6] = q; }
    __syncthreads();
    s = ls[0] + ls[1] + ls[2] + ls[3];
    q = lq[0] + lq[1] + lq[2] + lq[3];
    const float mu = s * (1.f / Ee);
    const float rstd = rsqrtf(q * (1.f / Ee) - mu * mu + 1e-5f);
    const int e0 = tid << 2;
    float h0 = (v.x - mu) * rstd, h1 = (v.y - mu) * rstd,
          h2 = (v.z - mu) * rstd, h3 = (v.w - mu) * rstd;
    if (isx) {
      bf16x4v o;
      o[0] = (__bf16)(h0 * qg[e0]   + qb[e0]);
      o[1] = (__bf16)(h1 * qg[e0+1] + qb[e0+1]);
      o[2] = (__bf16)(h2 * qg[e0+2] + qb[e0+2]);
      o[3] = (__bf16)(h3 * qg[e0+3] + qb[e0+3]);
      *(bf16x4v*)(xn + (size_t)row * Ee + e0) = o;
    } else {
      bf16x4v ok, ov;
      ok[0] = (__bf16)(h0 * kg[e0]   + kb[e0]);
      ok[1] = (__bf16)(h1 * kg[e0+1] + kb[e0+1]);
      ok[2] = (__bf16)(h2 * kg[e0+2] + kb[e0+2]);
      ok[3] = (__bf16)(h3 * kg[e0+3] + kb[e0+3]);
      ov[0] = (__bf16)(h0 * vg[e0]   + vb[e0]);
      ov[1] = (__bf16)(h1 * vg[e0+1] + vb[e0+1]);
      ov[2] = (__bf16)(h2 * vg[e0+2] + vb[e0+2]);
      ov[3] = (__bf16)(h3 * vg[e0+3] + vb[e0+3]);
      *(bf16x4v*)(ynk + (size_t)row * Ee + e0) = ok;
      *(bf16x4v*)(ynv + (size_t)row * Ee + e0) = ov;
    }
    return;
  }
  // ---------- prep segment ----------
  int u = blockIdx.x * 256 + tid;
  if (u < 3407872) {                       // 7 weight arrays, float4 units
    int seg = u >> 19, r = u & 524287;
    const float* s; __bf16* d;
    if      (seg == 0) { s = s0; d = d0; }
    else if (seg == 1) { s = s1; d = d1; }
    else if (seg == 2) { s = s2; d = d2; }
    else if (seg == 3) { s = s3; d = d3; }
    else if (seg == 4) { s = s4; d = d4; }
    else if (seg == 5) { s = s5; d = d5; }
    else               { s = s6; d = d6; }
    float4 v = ((const float4*)s)[r];
    bf16x4v o; o[0]=(__bf16)v.x; o[1]=(__bf16)v.y; o[2]=(__bf16)v.z; o[3]=(__bf16)v.w;
    ((bf16x4v*)d)[r] = o;
  } else if (u < 3686400) {                // fused proj weight [1024][1088]
    int p = u - 3407872;
    int row = p / 272, c4 = p - row * 272;
    float4 v = (c4 < 256) ? ((const float4*)pw1)[row * 256 + c4]
                          : ((const float4*)pw2)[row * 16 + (c4 - 256)];
    bf16x4v o; o[0]=(__bf16)v.x; o[1]=(__bf16)v.y; o[2]=(__bf16)v.z; o[3]=(__bf16)v.w;
    *(bf16x4v*)(wp + (size_t)row * 1088 + (c4 << 2)) = o;
  } else if (u < 4734976) {                // mask f32 -> bf16
    int q = u - 3686400;
    float4 v = ((const float4*)mask)[q];
    bf16x4v o; o[0]=(__bf16)v.x; o[1]=(__bf16)v.y; o[2]=(__bf16)v.z; o[3]=(__bf16)v.w;
    ((bf16x4v*)mb)[q] = o;
  } else {                                 // ypT [B][4][L]
    int t0 = (u - 4734976) << 2;
    #pragma unroll
    for (int k = 0; k < 4; k++) {
      int i = t0 + k;
      int b = i >> 13, d = (i >> 11) & 3, l = i & 2047;
      ypT[i] = (__bf16)yp[(((size_t)b << 11) + l) * 4 + d];
    }
  }
}

// ============ 4-phase interleaved GEMM pipeline (T3+T4+T5), BK=64, piece-major LDS ============
#define STAGE_A(BM_, A_, lda_, kt_, kh_, buf_)                                        \
  _Pragma("unroll")                                                                   \
  for (int jj = 0; jj < (BM_) / 128; jj++) {                                          \
    int c = (jj << 9) + tid;                                                          \
    int row_ = c >> 2, j_ = c & 3;                                                    \
    int col_ = ((kt_) << 6) + ((kh_) << 5) + ((j_ ^ (row_ & 3)) << 3);                \
    gl2l(A_ + (size_t)(m0 + row_) * (lda_) + col_,                                    \
         As + ((((buf_) << 1) + (kh_)) * ((BM_) * 32)) + (c << 3));                   \
  }

#define STAGE_B(W_, ldw_, kt_, kh_, buf_)                                             \
  _Pragma("unroll")                                                                   \
  for (int jj = 0; jj < 2; jj++) {                                                    \
    int c = (jj << 9) + tid;                                                          \
    int row_ = c >> 2, j_ = c & 3;                                                    \
    int col_ = ((kt_) << 6) + ((kh_) << 5) + ((j_ ^ (row_ & 3)) << 3);                \
    gl2l(W_ + (size_t)(n0 + row_) * (ldw_) + col_,                                    \
         Bs + ((((buf_) << 1) + (kh_)) * 8192) + (c << 3));                           \
  }

#define LOAD_A(BM_, buf_, ks_)                                                        \
  _Pragma("unroll")                                                                   \
  for (int i = 0; i < (BM_) / 32; i++) {                                              \
    int ra = wm + (i << 4) + li;                                                      \
    af[i] = *(const bf16x8*)(As + ((((buf_) << 1) + (ks_)) * ((BM_) * 32))            \
             + ra * 32 + ((g ^ (ra & 3)) << 3));                                      \
  }

#define LOAD_B(buf_, ks_, qn_)                                                        \
  _Pragma("unroll")                                                                   \
  for (int jj = 0; jj < 2; jj++) {                                                    \
    int rb = wn + ((qn_) << 5) + (jj << 4) + li;                                      \
    bw[jj] = *(const bf16x8*)(Bs + ((((buf_) << 1) + (ks_)) * 8192)                   \
             + rb * 32 + ((g ^ (rb & 3)) << 3));                                      \
  }

#define MFMA_Q(BM_, qn_)                                                              \
  __builtin_amdgcn_s_setprio(1);                                                      \
  _Pragma("unroll")                                                                   \
  for (int i = 0; i < (BM_) / 32; i++) {                                              \
    acc[i][((qn_) << 1)]     = __builtin_amdgcn_mfma_f32_16x16x32_bf16(af[i], bw[0], acc[i][((qn_) << 1)], 0, 0, 0);     \
    acc[i][((qn_) << 1) + 1] = __builtin_amdgcn_mfma_f32_16x16x32_bf16(af[i], bw[1], acc[i][((qn_) << 1) + 1], 0, 0, 0); \
  }                                                                                   \
  __builtin_amdgcn_s_setprio(0);

#define PH_SYNC                                                                       \
  __builtin_amdgcn_s_barrier();                                                       \
  asm volatile("s_waitcnt lgkmcnt(0)" ::: "memory");                                  \
  __builtin_amdgcn_sched_barrier(0);

#define PH_END __builtin_amdgcn_s_barrier();

#define GEMM_PIPE(BM_, A_, lda_, W_, ldw_, K_)                                        \
  const int w = tid >> 6, lane = tid & 63, g = lane >> 4, li = lane & 15;             \
  const int wm = (w >> 2) * ((BM_) / 2), wn = (w & 3) << 6;                           \
  constexpr int MI_ = (BM_) / 32;                                                     \
  constexpr int VMC = (BM_) / 128 + 2;                                                \
  f32x4 acc[MI_][4];                                                                  \
  _Pragma("unroll")                                                                   \
  for (int i = 0; i < MI_; i++)                                                       \
    _Pragma("unroll")                                                                 \
    for (int j = 0; j < 4; j++) acc[i][j] = (f32x4)0.f;                               \
  STAGE_A(BM_, A_, lda_, 0, 0, 0) STAGE_B(W_, ldw_, 0, 0, 0)                          \
  STAGE_A(BM_, A_, lda_, 0, 1, 0) STAGE_B(W_, ldw_, 0, 1, 0)                          \
  STAGE_A(BM_, A_, lda_, 1, 0, 1) STAGE_B(W_, ldw_, 1, 0, 1)                          \
  asm volatile("s_waitcnt vmcnt(%0)" :: "i"(VMC) : "memory");                         \
  __builtin_amdgcn_s_barrier();                                                       \
  const int NT = (K_) >> 6;                                                           \
  bf16x8 af[MI_], bw[2];                                                              \
  for (int t = 0; t < NT; t++) {                                                      \
    const int buf = t & 1, nbuf = buf ^ 1;                                            \
    const bool sB = (t + 1 < NT);                                                     \
    const bool sA = (t + 2 < NT);                                                     \
    LOAD_A(BM_, buf, 0) LOAD_B(buf, 0, 0)                                             \
    if (sB) { STAGE_A(BM_, A_, lda_, t + 1, 1, nbuf) }                                \
    PH_SYNC MFMA_Q(BM_, 0) PH_END                                                     \
    LOAD_B(buf, 0, 1)                                                                 \
    if (sB) {                                                                         \
      STAGE_B(W_, ldw_, t + 1, 1, nbuf)                                               \
      asm volatile("s_waitcnt vmcnt(%0)" :: "i"(VMC) : "memory");                     \
    } else {                                                                          \
      asm volatile("s_waitcnt vmcnt(0)" ::: "memory");                                \
    }                                                                                 \
    PH_SYNC MFMA_Q(BM_, 1) PH_END                                                     \
    LOAD_A(BM_, buf, 1) LOAD_B(buf, 1, 0)                                             \
    if (sA) { STAGE_A(BM_, A_, lda_, t + 2, 0, buf) }                                 \
    PH_SYNC MFMA_Q(BM_, 0) PH_END                                                     \
    LOAD_B(buf, 1, 1)                                                                 \
    if (sA) {                                                                         \
      STAGE_B(W_, ldw_, t + 2, 0, buf)                                                \
      asm volatile("s_waitcnt vmcnt(%0)" :: "i"(VMC) : "memory");                     \
    } else if (t + 1 < NT) {                                                          \
      asm volatile("s_waitcnt vmcnt(0)" ::: "memory");                                \
    }                                                                                 \
    PH_SYNC MFMA_Q(BM_, 1) PH_END                                                     \
  }

// Launch A: blocks 0..255: xn@w1122 (256x256, N=4096, gelu, split bias) -> h12
//           blocks 256..511: ynk@wk1 (128x256, N=2048, gelu) -> h3
__launch_bounds__(512, 2)
__global__ void gemm_mlp1(const __bf16* __restrict__ xn, const __bf16* __restrict__ ynk,
                          const __bf16* __restrict__ w1122, const __bf16* __restrict__ wk1,
                          const float* __restrict__ qb1, const float* __restrict__ qb2,
                          const float* __restrict__ kb1,
                          __bf16* __restrict__ h12, __bf16* __restrict__ h3) {
  __shared__ __align__(16) __bf16 As[2 * 2 * 256 * 32];
  __shared__ __align__(16) __bf16 Bs[2 * 2 * 256 * 32];
  const int tid = threadIdx.x, bid = blockIdx.x;
  if (bid < 256) {
    const int m0 = (bid >> 4) << 8, n0 = (bid & 15) << 8;
    GEMM_PIPE(256, xn, 1024, w1122, 1024, 1024)
    #pragma unroll
    for (int j = 0; j < 4; j++) {
      int n = n0 + wn + (j << 4) + li;
      float bias = (n < 2048) ? qb1[n] : qb2[n - 2048];
      #pragma unroll
      for (int i = 0; i < MI_; i++) {
        #pragma unroll
        for (int r = 0; r < 4; r++) {
          int m = m0 + wm + (i << 4) + (g << 2) + r;
          h12[(size_t)m * 4096 + n] = (__bf16)gelu_f(acc[i][j][r] + bias);
        }
      }
    }
  } else {
    const int rr = bid - 256;
    const int m0 = (rr >> 3) << 7, n0 = (rr & 7) << 8;
    GEMM_PIPE(128, ynk, 1024, wk1, 1024, 1024)
    #pragma unroll
    for (int j = 0; j < 4; j++) {
      int n = n0 + wn + (j << 4) + li;
      float bias = kb1[n];
      #pragma unroll
      for (int i = 0; i < MI_; i++) {
        #pragma unroll
        for (int r = 0; r < 4; r++) {
          int m = m0 + wm + (i << 4) + (g << 2) + r;
          h3[(size_t)m * 2048 + n] = (__bf16)gelu_f(acc[i][j][r] + bias);
        }
      }
    }
  }
}

// Launch B: seg0 x1=h1@w12, seg1 x2=h2@w22, seg2 y1=h3@wk2 (K=2048), seg3 vT=ynv@wv (K=1024)
__launch_bounds__(512, 2)
__global__ void gemm_mlp2(const __bf16* __restrict__ h12, const __bf16* __restrict__ h3,
                          const __bf16* __restrict__ ynv,
                          const __bf16* __restrict__ w12, const __bf16* __restrict__ w22,
                          const __bf16* __restrict__ wk2, const __bf16* __restrict__ wv,
                          const float* __restrict__ bx1, const float* __restrict__ bx2,
                          const float* __restrict__ by1, const float* __restrict__ bv,
                          __bf16* __restrict__ x1, __bf16* __restrict__ x2,
                          __bf16* __restrict__ y1, __bf16* __restrict__ vT) {
  __shared__ __align__(16) __bf16 As[2 * 2 * 256 * 32];
  __shared__ __align__(16) __bf16 Bs[2 * 2 * 256 * 32];
  const int tid = threadIdx.x, bid = blockIdx.x;
  const int seg = bid >> 6, rr = bid & 63;
  const int m0 = (rr >> 2) << 8, n0 = (rr & 3) << 8;
  const __bf16* A; const __bf16* W; const float* bias; __bf16* out; int lda, K;
  if      (seg == 0) { A = h12;        lda = 4096; W = w12; bias = bx1; out = x1; K = 2048; }
  else if (seg == 1) { A = h12 + 2048; lda = 4096; W = w22; bias = bx2; out = x2; K = 2048; }
  else if (seg == 2) { A = h3;         lda = 2048; W = wk2; bias = by1; out = y1; K = 2048; }
  else               { A = ynv;        lda = 1024; W = wv;  bias = bv;  out = vT; K = 1024; }
  GEMM_PIPE(256, A, lda, W, K, K)
  #pragma unroll
  for (int j = 0; j < 4; j++) {
    int n = n0 + wn + (j << 4) + li;
    float bs = bias[n];
    #pragma unroll
    for (int i = 0; i < MI_; i++) {
      #pragma unroll
      for (int r = 0; r < 4; r++) {
        int m = m0 + wm + (i << 4) + (g << 2) + r;
        float v = acc[i][j][r] + bs;
        if (seg == 3) {        // vT: [B*H][64][2048]
          int bb = m >> 11, l = m & 2047, hh = n >> 6, cc = n & 63;
          vT[(((size_t)(bb * Hh + hh) * 64 + cc) << 11) + l] = (__bf16)v;
        } else {
          out[(size_t)m * 1024 + n] = (__bf16)v;
        }
      }
    }
  }
}

// ---------------- merged build q + k (vectorized swizzled stores) ----------------
__launch_bounds__(256)
__global__ void build_qk(const __bf16* __restrict__ x1, const __bf16* __restrict__ x2,
                         const float* __restrict__ xp,
                         const __bf16* __restrict__ y1, const float* __restrict__ yp,
                         const float* __restrict__ pw1, const float* __restrict__ pb1,
                         const float* __restrict__ pw2, const float* __restrict__ pb2,
                         __bf16* __restrict__ q_ws, __bf16* __restrict__ k_ws) {
  const bool isq = blockIdx.x < 2048;
  const int bid = isq ? blockIdx.x : blockIdx.x - 2048;
  const int t = (bid << 1) + (threadIdx.x >> 7);
  const int tl = threadIdx.x & 127;
  const int b = t >> 11, n = t & 2047;
  const int hh = tl >> 3, ch = tl & 7;
  const int e0 = (hh << 6) + (ch << 3);
  const float* pos = isq ? xp : yp;
  const float p0 = pos[(size_t)t*4], p1 = pos[(size_t)t*4+1],
              p2 = pos[(size_t)t*4+2], p3 = pos[(size_t)t*4+3];
  bf16x8 o0, o1, o2, o3;
  if (isq) {
    bf16x8 v1 = *(const bf16x8*)(x1 + (size_t)t * Ee + e0);
    bf16x8 v2 = *(const bf16x8*)(x2 + (size_t)t * Ee + e0);
    #pragma unroll
    for (int sub = 0; sub < 8; sub++) {
      int e = e0 + sub;
      float a1 = pw1[e*4]*p0 + pw1[e*4+1]*p1 + pw1[e*4+2]*p2 + pw1[e*4+3]*p3 + pb1[e];
      float a2 = pw2[e*4]*p0 + pw2[e*4+1]*p1 + pw2[e*4+2]*p2 + pw2[e*4+3]*p3 + pb2[e];
      float s1, c1, s2, c2;
      __sincosf(a1, &s1, &c1); __sincosf(a2, &s2, &c2);
      float xv1 = (float)v1[sub], xv2 = (float)v2[sub];
      o0[sub] = (__bf16)(xv1 * c1); o1[sub] = (__bf16)(xv1 * s1);
      o2[sub] = (__bf16)(xv2 * c2); o3[sub] = (__bf16)(xv2 * s2);
    }
  } else {
    bf16x8 v1 = *(const bf16x8*)(y1 + (size_t)t * Ee + e0);
    #pragma unroll
    for (int sub = 0; sub < 8; sub++) {
      int e = e0 + sub;
      float a1 = pw1[e*4]*p0 + pw1[e*4+1]*p1 + pw1[e*4+2]*p2 + pw1[e*4+3]*p3;
      float a2 = pw2[e*4]*p0 + pw2[e*4+1]*p1 + pw2[e*4+2]*p2 + pw2[e*4+3]*p3;
      float s1, c1, s2, c2;
      __sincosf(a1, &s1, &c1); __sincosf(a2, &s2, &c2);
      float yv = (float)v1[sub];
      o0[sub] = (__bf16)(yv * c1); o1[sub] = (__bf16)(yv * s1);
      o2[sub] = (__bf16)c2;        o3[sub] = (__bf16)s2;
    }
  }
  const int k = n & 7, bc = ch ^ k;
  __bf16* base = (isq ? q_ws : k_ws) + ((((size_t)b * Hh + hh) * Nn + n) << 8);
  *(bf16x8*)(base + ((bc          ) << 3)) = o0;
  *(bf16x8*)(base + (((8  ^ k) ^ ch) << 3)) = o1;
  *(bf16x8*)(base + (((16 ^ k) ^ ch) << 3)) = o2;
  *(bf16x8*)(base + (((24 ^ k) ^ ch) << 3)) = o3;
}

// ---------------- fused flash attention (single QK^T pass, no max) ----------------
// 256 q-rows/block, 8 waves x 32 rows (2 frags), KVBLK=32, double-buffered K staging.
// Mask is NOT LDS-staged: consumed in the em-store pass via coalesced global bf16x8
// loads (8MB array, L2/L3-resident, issued early to hide under QK^T). The exp loop
// stores UNMASKED e to pT; the store pass computes em=e*mask in registers, writes
// em to global + back to pT (wave-private rows -> lgkmcnt only), so PV reads masked.
// te (masked row-sum) is accumulated in store-pass lanes; transposed via te_s at end.
__launch_bounds__(512, 1)
__global__ void attn_fused(const __bf16* __restrict__ q_ws, const __bf16* __restrict__ k_ws,
                           const __bf16* __restrict__ vT_ws, const __bf16* __restrict__ ypT_g,
                           const __bf16* __restrict__ mask_bf, const float* __restrict__ xp,
                           __bf16* __restrict__ em_g, float* __restrict__ dinv_g,
                           __bf16* __restrict__ avz) {
  __shared__ __align__(16) __bf16 kq[2][32 * 256];   // 32 KB
  __shared__ __align__(16) __bf16 vt[2][64 * 40];    // 10 KB
  __shared__ __align__(16) __bf16 pT[256 * 40];      // 20 KB
  __shared__ __align__(16) __bf16 ypl[2][16 * 40];   // 2.5 KB
  __shared__ float te_s[256];                        // 1 KB
  const int tid = threadIdx.x, w = tid >> 6, lane = tid & 63, g = lane >> 4, li = lane & 15;
  const int logical = ((blockIdx.x & 7) << 5) + (blockIdx.x >> 3);  // XCD-chunked
  const int bh = logical >> 3, nt = logical & 7;
  const int b = bh >> 4, h = bh & 15;
  const int n0 = nt << 8;
  const __bf16* qb = q_ws + (((size_t)bh * Nn + n0) << 8);
  const __bf16* kb = k_ws + (((size_t)bh * Ll) << 8);
  const __bf16* vb = vT_ws + ((size_t)bh << 17);
  const __bf16* yb = ypT_g + ((size_t)b << 13);
  const __bf16* mb = mask_bf + ((size_t)n0 << 11);

  // per-lane row/col for the store/mask pass: j in {0,1} -> row (w<<5)+(j<<4)+(lane>>2)
  const int srow = lane >> 2, sch = lane & 3;

  bf16x8 aq[2][8];
  #pragma unroll
  for (int rf = 0; rf < 2; rf++) {
    const int nloc = (w << 5) + (rf << 4) + li;
    #pragma unroll
    for (int s = 0; s < 8; s++)
      aq[rf][s] = *(const bf16x8*)(qb + ((size_t)nloc << 8) + ((((s << 2) + g) ^ (nloc & 7)) << 3));
  }
  for (int i = tid; i < 960; i += 512) {
    int buf = i / 480, idx = i - buf * 480;
    ypl[buf][160 + idx] = (__bf16)0.f;
  }
  {
    const int vc = tid >> 3, vl = (tid & 7) << 2;
    bf16x4v vreg = *(const bf16x4v*)(vb + ((size_t)vc << 11) + vl);
    bf16x4v ypreg;
    if (tid < 32) ypreg = *(const bf16x4v*)(yb + ((size_t)(tid >> 3) << 11) + ((tid & 7) << 2));
    #pragma unroll
    for (int j = 0; j < 2; j++) {
      int c = (j << 9) + tid;
      gl2l(kb + (size_t)(c >> 5) * 256 + ((c & 31) << 3), kq[0] + ((c - lane) << 3));
    }
    *(bf16x4v*)(vt[0] + vc * 40 + vl) = vreg;
    if (tid < 32) *(bf16x4v*)(ypl[0] + (tid >> 3) * 40 + ((tid & 7) << 2)) = ypreg;
  }
  __syncthreads();

  float se[2][4];
  float teq0 = 0.f, teq1 = 0.f;
  f32x4 accv[2][4], accp[2];
  #pragma unroll
  for (int rf = 0; rf < 2; rf++) {
    #pragma unroll
    for (int r = 0; r < 4; r++) se[rf][r] = 0.f;
    #pragma unroll
    for (int cb = 0; cb < 4; cb++) accv[rf][cb] = (f32x4)0.f;
    accp[rf] = (f32x4)0.f;
  }

  for (int t = 0; t < 64; ++t) {
    const int l0 = t << 5, cur = t & 1, nxt = cur ^ 1;
    const bool more = (t < 63);
    // early mask loads for THIS tile (hide latency under QK^T)
    bf16x8 mk0 = *(const bf16x8*)(mb + (size_t)((w << 5) + srow) * 2048 + l0 + (sch << 3));
    bf16x8 mk1 = *(const bf16x8*)(mb + (size_t)((w << 5) + 16 + srow) * 2048 + l0 + (sch << 3));
    bf16x4v vreg, ypreg;
    if (more) {
      const int l1 = l0 + 32;
      vreg = *(const bf16x4v*)(vb + ((size_t)(tid >> 3) << 11) + l1 + ((tid & 7) << 2));
      if (tid < 32) ypreg = *(const bf16x4v*)(yb + ((size_t)(tid >> 3) << 11) + l1 + ((tid & 7) << 2));
      #pragma unroll
      for (int j = 0; j < 2; j++) {
        int c = (j << 9) + tid;
        gl2l(kb + (size_t)(l1 + (c >> 5)) * 256 + ((c & 31) << 3), kq[nxt] + ((c - lane) << 3));
      }
    }
    // QK^T: K-fragment reads shared across both row-fragments
    f32x4 Cs[2][2];
    Cs[0][0] = (f32x4)0.f; Cs[0][1] = (f32x4)0.f; Cs[1][0] = (f32x4)0.f; Cs[1][1] = (f32x4)0.f;
    #pragma unroll
    for (int lb = 0; lb < 2; lb++) {
      const int kr = (lb << 4) + li;
      #pragma unroll
      for (int s = 0; s < 8; s++) {
        bf16x8 bk = *(const bf16x8*)(kq[cur] + kr * 256 + ((((s << 2) + g) ^ (kr & 7)) << 3));
        Cs[0][lb] = __builtin_amdgcn_mfma_f32_16x16x32_bf16(aq[0][s], bk, Cs[0][lb], 0, 0, 0);
        Cs[1][lb] = __builtin_amdgcn_mfma_f32_16x16x32_bf16(aq[1][s], bk, Cs[1][lb], 0, 0, 0);
      }
    }
    // exp (UNMASKED) + se + pT store
    #pragma unroll
    for (int rf = 0; rf < 2; rf++) {
      #pragma unroll
      for (int lb = 0; lb < 2; lb++) {
        #pragma unroll
        for (int r = 0; r < 4; r++) {
          const int row = (w << 5) + (rf << 4) + (g << 2) + r;
          float e = __expf(Cs[rf][lb][r] * SCALE);
          se[rf][r] += e;
          pT[row * 40 + (lb << 4) + li] = (__bf16)e;
        }
      }
    }
    asm volatile("s_waitcnt lgkmcnt(0)" ::: "memory");
    __builtin_amdgcn_sched_barrier(0);
    // mask + em store + pT write-back + te (per j: rows (w<<5)+(j<<4)+srow)
    #pragma unroll
    for (int j = 0; j < 2; j++) {
      const int row = (j << 4) + srow;
      bf16x8 pv = *(const bf16x8*)(pT + ((w << 5) + row) * 40 + (sch << 3));
      bf16x8 mk = j ? mk1 : mk0;
      bf16x8 emv;
      float tp = 0.f;
      #pragma unroll
      for (int i = 0; i < 8; i++) {
        float p = (float)pv[i] * (float)mk[i];
        emv[i] = (__bf16)p;
        tp += p;
      }
      tp += __shfl_xor(tp, 1);
      tp += __shfl_xor(tp, 2);
      if (j) teq1 += tp; else teq0 += tp;
      *(bf16x8*)(em_g + ((size_t)bh << 22) + ((size_t)(n0 + (w << 5) + row) << 11) + l0 + (sch << 3)) = emv;
      *(bf16x8*)(pT + ((w << 5) + row) * 40 + (sch << 3)) = emv;
    }
    asm volatile("s_waitcnt lgkmcnt(0)" ::: "memory");
    __builtin_amdgcn_sched_barrier(0);
    // PV + attn@yp (pT now masked)
    bf16x8 vv[4];
    #pragma unroll
    for (int cb = 0; cb < 4; cb++)
      vv[cb] = *(const bf16x8*)(vt[cur] + ((cb << 4) + li) * 40 + (g << 3));
    bf16x8 yy = *(const bf16x8*)(ypl[cur] + li * 40 + (g << 3));
    #pragma unroll
    for (int rf = 0; rf < 2; rf++) {
      bf16x8 pa = *(const bf16x8*)(pT + ((w << 5) + (rf << 4) + li) * 40 + (g << 3));
      #pragma unroll
      for (int cb = 0; cb < 4; cb++)
        accv[rf][cb] = __builtin_amdgcn_mfma_f32_16x16x32_bf16(pa, vv[cb], accv[rf][cb], 0, 0, 0);
      accp[rf] = __builtin_amdgcn_mfma_f32_16x16x32_bf16(pa, yy, accp[rf], 0, 0, 0);
    }
    if (more) {
      *(bf16x4v*)(vt[nxt] + (tid >> 3) * 40 + ((tid & 7) << 2)) = vreg;
      if (tid < 32) *(bf16x4v*)(ypl[nxt] + (tid >> 3) * 40 + ((tid & 7) << 2)) = ypreg;
    }
    __syncthreads();
  }

  // te transpose: store-pass lanes -> epilogue pattern (wave-private slice)
  if ((lane & 3) == 0) {
    te_s[(w << 5) + srow]      = teq0;
    te_s[(w << 5) + 16 + srow] = teq1;
  }
  asm volatile("s_waitcnt lgkmcnt(0)" ::: "memory");
  __builtin_amdgcn_sched_barrier(0);
  __syncthreads();

  // epilogue: reduce se, combine with te, write dinv + avz
  #pragma unroll
  for (int rf = 0; rf < 2; rf++) {
    #pragma unroll
    for (int r = 0; r < 4; r++) {
      float s = se[rf][r];
      #pragma unroll
      for (int o = 1; o < 16; o <<= 1) s += __shfl_xor(s, o);
      float tt = te_s[(w << 5) + (rf << 4) + (g << 2) + r];
      float dinv = 1.f / (tt + 1e-8f * s);
      const int n = n0 + (w << 5) + (rf << 4) + (g << 2) + r;
      if (li == 0) dinv_g[((size_t)bh << 11) + n] = dinv;
      #pragma unroll
      for (int cb = 0; cb < 4; cb++)
        avz[((size_t)b * Nn + n) * 1088 + (h << 6) + (cb << 4) + li] = (__bf16)(accv[rf][cb][r] * dinv);
      if (li < 4) {
        float z = accp[rf][r] * dinv - xp[(((size_t)b * Nn + n) << 2) + li];
        avz[((size_t)b * Nn + n) * 1088 + 1024 + (h << 2) + li] = (__bf16)z;
      }
    }
  }
}

// ---------------- merged finalize + output projection ----------------
__launch_bounds__(256)
__global__ void fin_proj(const __bf16* __restrict__ A, const __bf16* __restrict__ W,
                         const float* __restrict__ bias1, const float* __restrict__ bias2,
                         float* __restrict__ out,
                         const __bf16* __restrict__ em_g, const float* __restrict__ dinv_g,
                         float* __restrict__ attn_out,
                         const float* __restrict__ xp, float* __restrict__ xp_out) {
  constexpr int N = 1024, K = 1088;
  __shared__ __align__(16) __bf16 As[2][128 * 32];
  __shared__ __align__(16) __bf16 Bs[2][64 * 32];
  const int tid = threadIdx.x;
  if (blockIdx.x >= 512) {
    const int sbid = blockIdx.x - 512;
    if (sbid < 64) {
      int idx = sbid * 256 + tid;
      ((float4*)xp_out)[idx] = ((const float4*)xp)[idx];
    }
    for (size_t i8 = sbid * 256ul + tid; i8 < 16777216ul; i8 += 524288ul) {
      bf16x8 v = ((const bf16x8*)em_g)[i8];
      float dv = dinv_g[i8 >> 8];
      float4 o0, o1;
      o0.x = (float)v[0] * dv; o0.y = (float)v[1] * dv; o0.z = (float)v[2] * dv; o0.w = (float)v[3] * dv;
      o1.x = (float)v[4] * dv; o1.y = (float)v[5] * dv; o1.z = (float)v[6] * dv; o1.w = (float)v[7] * dv;
      ((float4*)attn_out)[i8 * 2]     = o0;
      ((float4*)attn_out)[i8 * 2 + 1] = o1;
    }
    return;
  }
  const int w = tid >> 6, lane = tid & 63, g = lane >> 4, li = lane & 15;
  const int bt = blockIdx.x >> 4;
  const int m0 = bt << 7, n0 = (blockIdx.x & 15) << 6;
  const int wm = (w >> 1) << 6, wn = (w & 1) << 5;
  f32x4 acc[4][2];
  #pragma unroll
  for (int i = 0; i < 4; i++) { acc[i][0] = (f32x4)0.f; acc[i][1] = (f32x4)0.f; }
  auto stage = [&](int buf, int kt) {
    const int col0 = kt << 5;
    #pragma unroll
    for (int j = 0; j < 2; j++) {
      int c = (j << 8) + tid;
      int row = c >> 2, sl = c & 3;
      int col = col0 + ((sl ^ (row & 3)) << 3);
      gl2l(A + (size_t)(m0 + row) * K + col, As[buf] + ((c - lane) << 3));
    }
    {
      int c = tid;
      int row = c >> 2, sl = c & 3;
      int col = col0 + ((sl ^ (row & 3)) << 3);
      gl2l(W + (size_t)(n0 + row) * K + col, Bs[buf] + ((c - lane) << 3));
    }
  };
  const int NT = K >> 5;   // 34
  stage(0, 0);
  for (int kt = 0; kt < NT; kt++) {
    const int cur = kt & 1;
    if (kt + 1 < NT) {
      stage(cur ^ 1, kt + 1);
      asm volatile("s_waitcnt vmcnt(3)" ::: "memory");
    } else {
      asm volatile("s_waitcnt vmcnt(0)" ::: "memory");
    }
    __builtin_amdgcn_s_barrier();
    __builtin_amdgcn_sched_barrier(0);
    bf16x8 af[4], bw[2];
    #pragma unroll
    for (int i = 0; i < 4; i++) {
      int ra = wm + (i << 4) + li;
      af[i] = *(const bf16x8*)(As[cur] + ra * 32 + ((g ^ (ra & 3)) << 3));
    }
    #pragma unroll
    for (int j = 0; j < 2; j++) {
      int rb = wn + (j << 4) + li;
      bw[j] = *(const bf16x8*)(Bs[cur] + rb * 32 + ((g ^ (rb & 3)) << 3));
    }
    #pragma unroll
    for (int i = 0; i < 4; i++)
      #pragma unroll
      for (int j = 0; j < 2; j++)
        acc[i][j] = __builtin_amdgcn_mfma_f32_16x16x32_bf16(af[i], bw[j], acc[i][j], 0, 0, 0);
    asm volatile("s_waitcnt lgkmcnt(0)" ::: "memory");
    __builtin_amdgcn_sched_barrier(0);
    __builtin_amdgcn_s_barrier();
  }
  #pragma unroll
  for (int j = 0; j < 2; j++) {
    int n = n0 + wn + (j << 4) + li;
    float bias = bias1[n] + bias2[n];
    #pragma unroll
    for (int i = 0; i < 4; i++) {
      #pragma unroll
      for (int r = 0; r < 4; r++) {
        int m = m0 + wm + (i << 4) + (g << 2) + r;
        out[(size_t)m * N + n] = acc[i][j][r] + bias;
      }
    }
  }
}

// ---------------- host ----------------
extern "C" void kernel_launch(void* const* d_in, const int* in_sizes, int n_in,
                              void* d_out, int out_size, void* d_ws, size_t ws_size,
                              hipStream_t stream) {
  (void)in_sizes; (void)n_in; (void)out_size; (void)ws_size;
  const float* x       = (const float*)d_in[0];
  const float* xp      = (const float*)d_in[1];
  const float* y       = (const float*)d_in[2];
  const float* yp      = (const float*)d_in[3];
  const float* mask    = (const float*)d_in[4];
  const float* p_w1    = (const float*)d_in[5];
  const float* p_b1    = (const float*)d_in[6];
  const float* p_w2    = (const float*)d_in[7];
  const float* p_b2    = (const float*)d_in[8];
  const float* q_ln_g  = (const float*)d_in[9];
  const float* q_ln_b  = (const float*)d_in[10];
  const float* q_m1_w1 = (const float*)d_in[11];
  const float* q_m1_b1 = (const float*)d_in[12];
  const float* q_m1_w2 = (const float*)d_in[13];
  const float* q_m1_b2 = (const float*)d_in[14];
  const float* q_m2_w1 = (const float*)d_in[15];
  const float* q_m2_b1 = (const float*)d_in[16];
  const float* q_m2_w2 = (const float*)d_in[17];
  const float* q_m2_b2 = (const float*)d_in[18];
  const float* k_ln_g  = (const float*)d_in[19];
  const float* k_ln_b  = (const float*)d_in[20];
  const float* k_m1_w1 = (const float*)d_in[21];
  const float* k_m1_b1 = (const float*)d_in[22];
  const float* k_m1_w2 = (const float*)d_in[23];
  const float* k_m1_b2 = (const float*)d_in[24];
  const float* v_ln_g  = (const float*)d_in[25];
  const float* v_ln_b  = (const float*)d_in[26];
  const float* v_w     = (const float*)d_in[27];
  const float* v_b     = (const float*)d_in[28];
  const float* proj1_w = (const float*)d_in[29];
  const float* proj1_b = (const float*)d_in[30];
  const float* proj2_w = (const float*)d_in[31];
  const float* proj2_b = (const float*)d_in[32];

  char* ws = (char*)d_ws;
  __bf16* xn    = (__bf16*)(ws + OFF_XN);
  __bf16* ynk   = (__bf16*)(ws + OFF_YNK);
  __bf16* ynv   = (__bf16*)(ws + OFF_YNV);
  __bf16* h12   = (__bf16*)(ws + OFF_H12);
  __bf16* h3    = (__bf16*)(ws + OFF_H3);
  __bf16* x1    = (__bf16*)(ws + OFF_X1);
  __bf16* x2    = (__bf16*)(ws + OFF_X2);
  __bf16* y1    = (__bf16*)(ws + OFF_Y1);
  __bf16* q_ws  = (__bf16*)(ws + OFF_QWS);
  __bf16* k_ws  = (__bf16*)(ws + OFF_KWS);
  __bf16* vT_ws = (__bf16*)(ws + OFF_VWS);
  float*  dinv  = (float*)(ws + OFF_DNV);
  __bf16* ypT   = (__bf16*)(ws + OFF_YPT);
  __bf16* mskb  = (__bf16*)(ws + OFF_MSK);
  __bf16* avz   = (__bf16*)(ws + OFF_AVZ);
  __bf16* w1122 = (__bf16*)(ws + OFF_W1122);
  __bf16* w12   = (__bf16*)(ws + OFF_W12);
  __bf16* w22   = (__bf16*)(ws + OFF_W22);
  __bf16* wk1   = (__bf16*)(ws + OFF_WK1);
  __bf16* wk2   = (__bf16*)(ws + OFF_WK2);
  __bf16* wv    = (__bf16*)(ws + OFF_WV);
  __bf16* wp    = (__bf16*)(ws + OFF_WP);
  __bf16* em    = (__bf16*)(ws + OFF_EM);

  float* out0     = (float*)d_out;
  float* attn_out = out0 + (size_t)4194304;
  float* xp_out   = out0 + (size_t)138412032;

  // 1. merged prep (weights + proj + mask bf16 + ypT) + layernorms
  prep_ln<<<26704, 256, 0, stream>>>(q_m1_w1, q_m2_w1, q_m1_w2, q_m2_w2, k_m1_w1, k_m1_w2, v_w,
                                     w1122, w1122 + 2097152, w12, w22, wk1, wk2, wv,
                                     proj1_w, proj2_w, wp, mask, mskb, yp, ypT,
                                     x, y, q_ln_g, q_ln_b, k_ln_g, k_ln_b, v_ln_g, v_ln_b,
                                     xn, ynk, ynv);
  // 2. mlp stage 1 (4-phase interleaved pipeline)
  gemm_mlp1<<<512, 512, 0, stream>>>(xn, ynk, w1122, wk1, q_m1_b1, q_m2_b1, k_m1_b1, h12, h3);
  // 3. mlp stage 2 + V projection
  gemm_mlp2<<<256, 512, 0, stream>>>(h12, h3, ynv, w12, w22, wk2, wv,
                                     q_m1_b2, q_m2_b2, k_m1_b2, v_b, x1, x2, y1, vT_ws);
  // 4. q/k assembly
  build_qk<<<4096, 256, 0, stream>>>(x1, x2, xp, y1, yp, p_w1, p_b1, p_w2, p_b2, q_ws, k_ws);
  // 5. fused flash attention (mask de-staged from LDS)
  attn_fused<<<256, 512, 0, stream>>>(q_ws, k_ws, vT_ws, ypT, mskb, xp, em, dinv, avz);
  // 6. merged finalize (attn = em*dinv + xp passthrough) + output projection
  fin_proj<<<2560, 256, 0, stream>>>(avz, wp, proj1_b, proj2_b, out0,
                                     em, dinv, attn_out, xp, xp_out);
}

// Round 11
// 623.232 us; speedup vs baseline: 1.1775x; 1.1057x over previous
//
#include <hip/hip_runtime.h>
#include <math.h>
#include <stdint.h>

#define DEV static __device__ __forceinline__

typedef __bf16 bf16x8 __attribute__((ext_vector_type(8)));
typedef __bf16 bf16x4v __attribute__((ext_vector_type(4)));
typedef float f32x4 __attribute__((ext_vector_type(4)));

// problem dims
constexpr int Nn = 2048, Ll = 2048, Ee = 1024, Hh = 16;
constexpr float SCALE = 0.0625f;   // (4C)^-0.5 = 1/16

// ---------------- workspace layout (bytes) ----------------
constexpr size_t OFF_XN   = 0;                    // [4096][1024] bf16
constexpr size_t OFF_YNK  = 8388608;
constexpr size_t OFF_YNV  = 16777216;
constexpr size_t OFF_H12  = 25165824;             // [4096][4096] bf16
constexpr size_t OFF_H3   = 58720256;             // [4096][2048] bf16
constexpr size_t OFF_X1   = 75497472;             // [4096][1024] bf16
constexpr size_t OFF_X2   = 83886080;
constexpr size_t OFF_Y1   = 92274688;
constexpr size_t OFF_QWS  = 100663296;            // [B][H][N][256] bf16, pre-swizzled
constexpr size_t OFF_KWS  = 134217728;            // [B][H][L][256] bf16, pre-swizzled
constexpr size_t OFF_VWS  = 167772160;            // vT: [B*H][64][2048] bf16
constexpr size_t OFF_DNV  = 176160768;            // f32 [B*H*N]
constexpr size_t OFF_YPT  = 176422912;            // ypT [B][4][2048] bf16
constexpr size_t OFF_MSK  = 176685056;            // mask bf16 [2048][2048]
constexpr size_t OFF_AVZ  = 185073664;            // [4096][1088] bf16
constexpr size_t OFF_W1122= 193986560;            // [4096][1024] bf16 (w11 ; w21)
constexpr size_t OFF_W12  = 202375168;
constexpr size_t OFF_W22  = 206569472;
constexpr size_t OFF_WK1  = 210763776;
constexpr size_t OFF_WK2  = 214958080;
constexpr size_t OFF_WV   = 219152384;
constexpr size_t OFF_WP   = 221249536;            // [1024][1088] bf16
constexpr size_t OFF_EM   = 223477760;            // em bf16, 268 MB

DEV void gl2l(const void* g, void* l) {
  __builtin_amdgcn_global_load_lds((const __attribute__((address_space(1))) void*)g,
                                   (__attribute__((address_space(3))) void*)l, 16, 0, 0);
}

// exact-erf GELU via Abramowitz-Stegun 7.1.26 (|eps|<1.5e-7, way below bf16)
DEV float gelu_f(float v) {
  float x = v * 0.70710678118654752f;
  float ax = fabsf(x);
  float t = 1.f / fmaf(0.3275911f, ax, 1.f);
  float y = t * fmaf(t, fmaf(t, fmaf(t, fmaf(t, 1.061405429f, -1.453152027f),
                                     1.421413741f), -0.284496736f), 0.254829592f);
  float er = 1.f - y * __expf(-x * x);
  er = (x < 0.f) ? -er : er;
  return 0.5f * v * (1.f + er);
}

// ---------------- merged prep (weights + proj + mask + ypT) + LayerNorms ----------------
__launch_bounds__(256)
__global__ void prep_ln(const float* __restrict__ s0, const float* __restrict__ s1,
                        const float* __restrict__ s2, const float* __restrict__ s3,
                        const float* __restrict__ s4, const float* __restrict__ s5,
                        const float* __restrict__ s6,
                        __bf16* __restrict__ d0, __bf16* __restrict__ d1,
                        __bf16* __restrict__ d2, __bf16* __restrict__ d3,
                        __bf16* __restrict__ d4, __bf16* __restrict__ d5,
                        __bf16* __restrict__ d6,
                        const float* __restrict__ pw1, const float* __restrict__ pw2,
                        __bf16* __restrict__ wp,
                        const float* __restrict__ mask, __bf16* __restrict__ mb,
                        const float* __restrict__ yp, __bf16* __restrict__ ypT,
                        const float* __restrict__ x, const float* __restrict__ y,
                        const float* __restrict__ qg, const float* __restrict__ qb,
                        const float* __restrict__ kg, const float* __restrict__ kb,
                        const float* __restrict__ vg, const float* __restrict__ vb,
                        __bf16* __restrict__ xn, __bf16* __restrict__ ynk,
                        __bf16* __restrict__ ynv) {
  const int tid = threadIdx.x;
  if (blockIdx.x >= 18512) {
    const int t = blockIdx.x - 18512;
    const bool isx = t < 4096;
    const int row = isx ? t : t - 4096;
    const float* src = (isx ? x : y) + (size_t)row * Ee;
    const float4 v = ((const float4*)src)[tid];
    float s = v.x + v.y + v.z + v.w;
    float q = v.x*v.x + v.y*v.y + v.z*v.z + v.w*v.w;
    #pragma unroll
    for (int o = 32; o > 0; o >>= 1) { s += __shfl_down(s, o); q += __shfl_down(q, o); }
    __shared__ float ls[4], lq[4];
    if ((tid & 63) == 0) { ls[tid >> 6] = s; lq[tid >> 6] = q; }
    __syncthreads();
    s = ls[0] + ls[1] + ls[2] + ls[3];
    q = lq[0] + lq[1] + lq[2] + lq[3];
    const float mu = s * (1.f / Ee);
    const float rstd = rsqrtf(q * (1.f / Ee) - mu * mu + 1e-5f);
    const int e0 = tid << 2;
    float h0 = (v.x - mu) * rstd, h1 = (v.y - mu) * rstd,
          h2 = (v.z - mu) * rstd, h3 = (v.w - mu) * rstd;
    if (isx) {
      bf16x4v o;
      o[0] = (__bf16)(h0 * qg[e0]   + qb[e0]);
      o[1] = (__bf16)(h1 * qg[e0+1] + qb[e0+1]);
      o[2] = (__bf16)(h2 * qg[e0+2] + qb[e0+2]);
      o[3] = (__bf16)(h3 * qg[e0+3] + qb[e0+3]);
      *(bf16x4v*)(xn + (size_t)row * Ee + e0) = o;
    } else {
      bf16x4v ok, ov;
      ok[0] = (__bf16)(h0 * kg[e0]   + kb[e0]);
      ok[1] = (__bf16)(h1 * kg[e0+1] + kb[e0+1]);
      ok[2] = (__bf16)(h2 * kg[e0+2] + kb[e0+2]);
      ok[3] = (__bf16)(h3 * kg[e0+3] + kb[e0+3]);
      ov[0] = (__bf16)(h0 * vg[e0]   + vb[e0]);
      ov[1] = (__bf16)(h1 * vg[e0+1] + vb[e0+1]);
      ov[2] = (__bf16)(h2 * vg[e0+2] + vb[e0+2]);
      ov[3] = (__bf16)(h3 * vg[e0+3] + vb[e0+3]);
      *(bf16x4v*)(ynk + (size_t)row * Ee + e0) = ok;
      *(bf16x4v*)(ynv + (size_t)row * Ee + e0) = ov;
    }
    return;
  }
  int u = blockIdx.x * 256 + tid;
  if (u < 3407872) {
    int seg = u >> 19, r = u & 524287;
    const float* s; __bf16* d;
    if      (seg == 0) { s = s0; d = d0; }
    else if (seg == 1) { s = s1; d = d1; }
    else if (seg == 2) { s = s2; d = d2; }
    else if (seg == 3) { s = s3; d = d3; }
    else if (seg == 4) { s = s4; d = d4; }
    else if (seg == 5) { s = s5; d = d5; }
    else               { s = s6; d = d6; }
    float4 v = ((const float4*)s)[r];
    bf16x4v o; o[0]=(__bf16)v.x; o[1]=(__bf16)v.y; o[2]=(__bf16)v.z; o[3]=(__bf16)v.w;
    ((bf16x4v*)d)[r] = o;
  } else if (u < 3686400) {
    int p = u - 3407872;
    int row = p / 272, c4 = p - row * 272;
    float4 v = (c4 < 256) ? ((const float4*)pw1)[row * 256 + c4]
                          : ((const float4*)pw2)[row * 16 + (c4 - 256)];
    bf16x4v o; o[0]=(__bf16)v.x; o[1]=(__bf16)v.y; o[2]=(__bf16)v.z; o[3]=(__bf16)v.w;
    *(bf16x4v*)(wp + (size_t)row * 1088 + (c4 << 2)) = o;
  } else if (u < 4734976) {
    int q = u - 3686400;
    float4 v = ((const float4*)mask)[q];
    bf16x4v o; o[0]=(__bf16)v.x; o[1]=(__bf16)v.y; o[2]=(__bf16)v.z; o[3]=(__bf16)v.w;
    ((bf16x4v*)mb)[q] = o;
  } else {
    int t0 = (u - 4734976) << 2;
    #pragma unroll
    for (int k = 0; k < 4; k++) {
      int i = t0 + k;
      int b = i >> 13, d = (i >> 11) & 3, l = i & 2047;
      ypT[i] = (__bf16)yp[(((size_t)b << 11) + l) * 4 + d];
    }
  }
}

// ============ 4-phase interleaved GEMM pipeline (T3+T4+T5), BK=64, piece-major LDS ============
#define STAGE_A(BM_, A_, lda_, kt_, kh_, buf_)                                        \
  _Pragma("unroll")                                                                   \
  for (int jj = 0; jj < (BM_) / 128; jj++) {                                          \
    int c = (jj << 9) + tid;                                                          \
    int row_ = c >> 2, j_ = c & 3;                                                    \
    int col_ = ((kt_) << 6) + ((kh_) << 5) + ((j_ ^ (row_ & 3)) << 3);                \
    gl2l(A_ + (size_t)(m0 + row_) * (lda_) + col_,                                    \
         As + ((((buf_) << 1) + (kh_)) * ((BM_) * 32)) + (c << 3));                   \
  }

#define STAGE_B(W_, ldw_, kt_, kh_, buf_)                                             \
  _Pragma("unroll")                                                                   \
  for (int jj = 0; jj < 2; jj++) {                                                    \
    int c = (jj << 9) + tid;                                                          \
    int row_ = c >> 2, j_ = c & 3;                                                    \
    int col_ = ((kt_) << 6) + ((kh_) << 5) + ((j_ ^ (row_ & 3)) << 3);                \
    gl2l(W_ + (size_t)(n0 + row_) * (ldw_) + col_,                                    \
         Bs + ((((buf_) << 1) + (kh_)) * 8192) + (c << 3));                           \
  }

#define LOAD_A(BM_, buf_, ks_)                                                        \
  _Pragma("unroll")                                                                   \
  for (int i = 0; i < (BM_) / 32; i++) {                                              \
    int ra = wm + (i << 4) + li;                                                      \
    af[i] = *(const bf16x8*)(As + ((((buf_) << 1) + (ks_)) * ((BM_) * 32))            \
             + ra * 32 + ((g ^ (ra & 3)) << 3));                                      \
  }

#define LOAD_B(buf_, ks_, qn_)                                                        \
  _Pragma("unroll")                                                                   \
  for (int jj = 0; jj < 2; jj++) {                                                    \
    int rb = wn + ((qn_) << 5) + (jj << 4) + li;                                      \
    bw[jj] = *(const bf16x8*)(Bs + ((((buf_) << 1) + (ks_)) * 8192)                   \
             + rb * 32 + ((g ^ (rb & 3)) << 3));                                      \
  }

#define MFMA_Q(BM_, qn_)                                                              \
  __builtin_amdgcn_s_setprio(1);                                                      \
  _Pragma("unroll")                                                                   \
  for (int i = 0; i < (BM_) / 32; i++) {                                              \
    acc[i][((qn_) << 1)]     = __builtin_amdgcn_mfma_f32_16x16x32_bf16(af[i], bw[0], acc[i][((qn_) << 1)], 0, 0, 0);     \
    acc[i][((qn_) << 1) + 1] = __builtin_amdgcn_mfma_f32_16x16x32_bf16(af[i], bw[1], acc[i][((qn_) << 1) + 1], 0, 0, 0); \
  }                                                                                   \
  __builtin_amdgcn_s_setprio(0);

#define PH_SYNC                                                                       \
  __builtin_amdgcn_s_barrier();                                                       \
  asm volatile("s_waitcnt lgkmcnt(0)" ::: "memory");                                  \
  __builtin_amdgcn_sched_barrier(0);

#define PH_END __builtin_amdgcn_s_barrier();

#define GEMM_PIPE(BM_, A_, lda_, W_, ldw_, K_)                                        \
  const int w = tid >> 6, lane = tid & 63, g = lane >> 4, li = lane & 15;             \
  const int wm = (w >> 2) * ((BM_) / 2), wn = (w & 3) << 6;                           \
  constexpr int MI_ = (BM_) / 32;                                                     \
  constexpr int VMC = (BM_) / 128 + 2;                                                \
  f32x4 acc[MI_][4];                                                                  \
  _Pragma("unroll")                                                                   \
  for (int i = 0; i < MI_; i++)                                                       \
    _Pragma("unroll")                                                                 \
    for (int j = 0; j < 4; j++) acc[i][j] = (f32x4)0.f;                               \
  STAGE_A(BM_, A_, lda_, 0, 0, 0) STAGE_B(W_, ldw_, 0, 0, 0)                          \
  STAGE_A(BM_, A_, lda_, 0, 1, 0) STAGE_B(W_, ldw_, 0, 1, 0)                          \
  STAGE_A(BM_, A_, lda_, 1, 0, 1) STAGE_B(W_, ldw_, 1, 0, 1)                          \
  asm volatile("s_waitcnt vmcnt(%0)" :: "i"(VMC) : "memory");                         \
  __builtin_amdgcn_s_barrier();                                                       \
  const int NT = (K_) >> 6;                                                           \
  bf16x8 af[MI_], bw[2];                                                              \
  for (int t = 0; t < NT; t++) {                                                      \
    const int buf = t & 1, nbuf = buf ^ 1;                                            \
    const bool sB = (t + 1 < NT);                                                     \
    const bool sA = (t + 2 < NT);                                                     \
    LOAD_A(BM_, buf, 0) LOAD_B(buf, 0, 0)                                             \
    if (sB) { STAGE_A(BM_, A_, lda_, t + 1, 1, nbuf) }                                \
    PH_SYNC MFMA_Q(BM_, 0) PH_END                                                     \
    LOAD_B(buf, 0, 1)                                                                 \
    if (sB) {                                                                         \
      STAGE_B(W_, ldw_, t + 1, 1, nbuf)                                               \
      asm volatile("s_waitcnt vmcnt(%0)" :: "i"(VMC) : "memory");                     \
    } else {                                                                          \
      asm volatile("s_waitcnt vmcnt(0)" ::: "memory");                                \
    }                                                                                 \
    PH_SYNC MFMA_Q(BM_, 1) PH_END                                                     \
    LOAD_A(BM_, buf, 1) LOAD_B(buf, 1, 0)                                             \
    if (sA) { STAGE_A(BM_, A_, lda_, t + 2, 0, buf) }                                 \
    PH_SYNC MFMA_Q(BM_, 0) PH_END                                                     \
    LOAD_B(buf, 1, 1)                                                                 \
    if (sA) {                                                                         \
      STAGE_B(W_, ldw_, t + 2, 0, buf)                                                \
      asm volatile("s_waitcnt vmcnt(%0)" :: "i"(VMC) : "memory");                     \
    } else if (t + 1 < NT) {                                                          \
      asm volatile("s_waitcnt vmcnt(0)" ::: "memory");                                \
    }                                                                                 \
    PH_SYNC MFMA_Q(BM_, 1) PH_END                                                     \
  }

// Launch A: blocks 0..255: xn@w1122 (256x256, N=4096, gelu, split bias) -> h12
//           blocks 256..511: ynk@wk1 (128x256, N=2048, gelu) -> h3
__launch_bounds__(512, 2)
__global__ void gemm_mlp1(const __bf16* __restrict__ xn, const __bf16* __restrict__ ynk,
                          const __bf16* __restrict__ w1122, const __bf16* __restrict__ wk1,
                          const float* __restrict__ qb1, const float* __restrict__ qb2,
                          const float* __restrict__ kb1,
                          __bf16* __restrict__ h12, __bf16* __restrict__ h3) {
  __shared__ __align__(16) __bf16 As[2 * 2 * 256 * 32];
  __shared__ __align__(16) __bf16 Bs[2 * 2 * 256 * 32];
  const int tid = threadIdx.x, bid = blockIdx.x;
  if (bid < 256) {
    const int m0 = (bid >> 4) << 8, n0 = (bid & 15) << 8;
    GEMM_PIPE(256, xn, 1024, w1122, 1024, 1024)
    #pragma unroll
    for (int j = 0; j < 4; j++) {
      int n = n0 + wn + (j << 4) + li;
      float bias = (n < 2048) ? qb1[n] : qb2[n - 2048];
      #pragma unroll
      for (int i = 0; i < MI_; i++) {
        #pragma unroll
        for (int r = 0; r < 4; r++) {
          int m = m0 + wm + (i << 4) + (g << 2) + r;
          h12[(size_t)m * 4096 + n] = (__bf16)gelu_f(acc[i][j][r] + bias);
        }
      }
    }
  } else {
    const int rr = bid - 256;
    const int m0 = (rr >> 3) << 7, n0 = (rr & 7) << 8;
    GEMM_PIPE(128, ynk, 1024, wk1, 1024, 1024)
    #pragma unroll
    for (int j = 0; j < 4; j++) {
      int n = n0 + wn + (j << 4) + li;
      float bias = kb1[n];
      #pragma unroll
      for (int i = 0; i < MI_; i++) {
        #pragma unroll
        for (int r = 0; r < 4; r++) {
          int m = m0 + wm + (i << 4) + (g << 2) + r;
          h3[(size_t)m * 2048 + n] = (__bf16)gelu_f(acc[i][j][r] + bias);
        }
      }
    }
  }
}

// Launch B: seg0 x1=h1@w12, seg1 x2=h2@w22, seg2 y1=h3@wk2 (K=2048), seg3 vT=ynv@wv (K=1024)
__launch_bounds__(512, 2)
__global__ void gemm_mlp2(const __bf16* __restrict__ h12, const __bf16* __restrict__ h3,
                          const __bf16* __restrict__ ynv,
                          const __bf16* __restrict__ w12, const __bf16* __restrict__ w22,
                          const __bf16* __restrict__ wk2, const __bf16* __restrict__ wv,
                          const float* __restrict__ bx1, const float* __restrict__ bx2,
                          const float* __restrict__ by1, const float* __restrict__ bv,
                          __bf16* __restrict__ x1, __bf16* __restrict__ x2,
                          __bf16* __restrict__ y1, __bf16* __restrict__ vT) {
  __shared__ __align__(16) __bf16 As[2 * 2 * 256 * 32];
  __shared__ __align__(16) __bf16 Bs[2 * 2 * 256 * 32];
  const int tid = threadIdx.x, bid = blockIdx.x;
  const int seg = bid >> 6, rr = bid & 63;
  const int m0 = (rr >> 2) << 8, n0 = (rr & 3) << 8;
  const __bf16* A; const __bf16* W; const float* bias; __bf16* out; int lda, K;
  if      (seg == 0) { A = h12;        lda = 4096; W = w12; bias = bx1; out = x1; K = 2048; }
  else if (seg == 1) { A = h12 + 2048; lda = 4096; W = w22; bias = bx2; out = x2; K = 2048; }
  else if (seg == 2) { A = h3;         lda = 2048; W = wk2; bias = by1; out = y1; K = 2048; }
  else               { A = ynv;        lda = 1024; W = wv;  bias = bv;  out = vT; K = 1024; }
  GEMM_PIPE(256, A, lda, W, K, K)
  #pragma unroll
  for (int j = 0; j < 4; j++) {
    int n = n0 + wn + (j << 4) + li;
    float bs = bias[n];
    #pragma unroll
    for (int i = 0; i < MI_; i++) {
      #pragma unroll
      for (int r = 0; r < 4; r++) {
        int m = m0 + wm + (i << 4) + (g << 2) + r;
        float v = acc[i][j][r] + bs;
        if (seg == 3) {        // vT: [B*H][64][2048]
          int bb = m >> 11, l = m & 2047, hh = n >> 6, cc = n & 63;
          vT[(((size_t)(bb * Hh + hh) * 64 + cc) << 11) + l] = (__bf16)v;
        } else {
          out[(size_t)m * 1024 + n] = (__bf16)v;
        }
      }
    }
  }
}

// ---------------- merged build q + k (vectorized swizzled stores) ----------------
__launch_bounds__(256)
__global__ void build_qk(const __bf16* __restrict__ x1, const __bf16* __restrict__ x2,
                         const float* __restrict__ xp,
                         const __bf16* __restrict__ y1, const float* __restrict__ yp,
                         const float* __restrict__ pw1, const float* __restrict__ pb1,
                         const float* __restrict__ pw2, const float* __restrict__ pb2,
                         __bf16* __restrict__ q_ws, __bf16* __restrict__ k_ws) {
  const bool isq = blockIdx.x < 2048;
  const int bid = isq ? blockIdx.x : blockIdx.x - 2048;
  const int t = (bid << 1) + (threadIdx.x >> 7);
  const int tl = threadIdx.x & 127;
  const int b = t >> 11, n = t & 2047;
  const int hh = tl >> 3, ch = tl & 7;
  const int e0 = (hh << 6) + (ch << 3);
  const float* pos = isq ? xp : yp;
  const float p0 = pos[(size_t)t*4], p1 = pos[(size_t)t*4+1],
              p2 = pos[(size_t)t*4+2], p3 = pos[(size_t)t*4+3];
  bf16x8 o0, o1, o2, o3;
  if (isq) {
    bf16x8 v1 = *(const bf16x8*)(x1 + (size_t)t * Ee + e0);
    bf16x8 v2 = *(const bf16x8*)(x2 + (size_t)t * Ee + e0);
    #pragma unroll
    for (int sub = 0; sub < 8; sub++) {
      int e = e0 + sub;
      float a1 = pw1[e*4]*p0 + pw1[e*4+1]*p1 + pw1[e*4+2]*p2 + pw1[e*4+3]*p3 + pb1[e];
      float a2 = pw2[e*4]*p0 + pw2[e*4+1]*p1 + pw2[e*4+2]*p2 + pw2[e*4+3]*p3 + pb2[e];
      float s1, c1, s2, c2;
      __sincosf(a1, &s1, &c1); __sincosf(a2, &s2, &c2);
      float xv1 = (float)v1[sub], xv2 = (float)v2[sub];
      o0[sub] = (__bf16)(xv1 * c1); o1[sub] = (__bf16)(xv1 * s1);
      o2[sub] = (__bf16)(xv2 * c2); o3[sub] = (__bf16)(xv2 * s2);
    }
  } else {
    bf16x8 v1 = *(const bf16x8*)(y1 + (size_t)t * Ee + e0);
    #pragma unroll
    for (int sub = 0; sub < 8; sub++) {
      int e = e0 + sub;
      float a1 = pw1[e*4]*p0 + pw1[e*4+1]*p1 + pw1[e*4+2]*p2 + pw1[e*4+3]*p3;
      float a2 = pw2[e*4]*p0 + pw2[e*4+1]*p1 + pw2[e*4+2]*p2 + pw2[e*4+3]*p3;
      float s1, c1, s2, c2;
      __sincosf(a1, &s1, &c1); __sincosf(a2, &s2, &c2);
      float yv = (float)v1[sub];
      o0[sub] = (__bf16)(yv * c1); o1[sub] = (__bf16)(yv * s1);
      o2[sub] = (__bf16)c2;        o3[sub] = (__bf16)s2;
    }
  }
  const int k = n & 7, bc = ch ^ k;
  __bf16* base = (isq ? q_ws : k_ws) + ((((size_t)b * Hh + hh) * Nn + n) << 8);
  *(bf16x8*)(base + ((bc          ) << 3)) = o0;
  *(bf16x8*)(base + (((8  ^ k) ^ ch) << 3)) = o1;
  *(bf16x8*)(base + (((16 ^ k) ^ ch) << 3)) = o2;
  *(bf16x8*)(base + (((24 ^ k) ^ ch) << 3)) = o3;
}

// ---------------- fused flash attention (single QK^T pass, no max), KVBLK=64 ----------------
// 256 q-rows/block, 8 waves x 32 rows (2 frags), 32 KV iterations (halved barrier count).
// Mask via registers from global (L2/L3-resident); exp loop stores unmasked e to pT; mask
// pass computes em=e*mask, writes em_g + pT write-back (wave-private rows, lgkm-only sync).
__launch_bounds__(512, 1)
__global__ void attn_fused(const __bf16* __restrict__ q_ws, const __bf16* __restrict__ k_ws,
                           const __bf16* __restrict__ vT_ws, const __bf16* __restrict__ ypT_g,
                           const __bf16* __restrict__ mask_bf, const float* __restrict__ xp,
                           __bf16* __restrict__ em_g, float* __restrict__ dinv_g,
                           __bf16* __restrict__ avz) {
  __shared__ __align__(16) __bf16 kq[2][64 * 256];   // 64 KB
  __shared__ __align__(16) __bf16 vt[2][64 * 72];    // 18 KB (padded rows)
  __shared__ __align__(16) __bf16 pT[256 * 72];      // 36 KB (padded rows)
  __shared__ __align__(16) __bf16 ypl[2][16 * 72];   // 4.5 KB
  __shared__ float te_s[256];                        // 1 KB
  const int tid = threadIdx.x, w = tid >> 6, lane = tid & 63, g = lane >> 4, li = lane & 15;
  const int logical = ((blockIdx.x & 7) << 5) + (blockIdx.x >> 3);  // XCD-chunked
  const int bh = logical >> 3, nt = logical & 7;
  const int b = bh >> 4, h = bh & 15;
  const int n0 = nt << 8;
  const __bf16* qb = q_ws + (((size_t)bh * Nn + n0) << 8);
  const __bf16* kb = k_ws + (((size_t)bh * Ll) << 8);
  const __bf16* vb = vT_ws + ((size_t)bh << 17);
  const __bf16* yb = ypT_g + ((size_t)b << 13);
  const __bf16* mb = mask_bf + ((size_t)n0 << 11);

  bf16x8 aq[2][8];
  #pragma unroll
  for (int rf = 0; rf < 2; rf++) {
    const int nloc = (w << 5) + (rf << 4) + li;
    #pragma unroll
    for (int s = 0; s < 8; s++)
      aq[rf][s] = *(const bf16x8*)(qb + ((size_t)nloc << 8) + ((((s << 2) + g) ^ (nloc & 7)) << 3));
  }
  // zero ypl rows 4..15 (both buffers): rows 4..15 span els 288..1151 per buffer
  for (int i = tid; i < 1728; i += 512) {
    int buf = i / 864, idx = i - buf * 864;
    ypl[buf][288 + idx] = (__bf16)0.f;
  }
  // prologue: stage tile 0 (64 KV rows)
  {
    const int vc = tid >> 3, vl = (tid & 7) << 3;
    bf16x8 vreg = *(const bf16x8*)(vb + ((size_t)vc << 11) + vl);
    bf16x8 ypreg;
    if (tid < 32) ypreg = *(const bf16x8*)(yb + ((size_t)(tid >> 3) << 11) + ((tid & 7) << 3));
    #pragma unroll
    for (int j = 0; j < 4; j++) {
      int c = (j << 9) + tid;
      gl2l(kb + (size_t)(c >> 5) * 256 + ((c & 31) << 3), kq[0] + ((c - lane) << 3));
    }
    *(bf16x8*)(vt[0] + vc * 72 + vl) = vreg;
    if (tid < 32) *(bf16x8*)(ypl[0] + (tid >> 3) * 72 + ((tid & 7) << 3)) = ypreg;
  }
  __syncthreads();

  float se[2][4];
  float te[4] = {0.f, 0.f, 0.f, 0.f};
  f32x4 accv[2][4], accp[2];
  #pragma unroll
  for (int rf = 0; rf < 2; rf++) {
    #pragma unroll
    for (int r = 0; r < 4; r++) se[rf][r] = 0.f;
    #pragma unroll
    for (int cb = 0; cb < 4; cb++) accv[rf][cb] = (f32x4)0.f;
    accp[rf] = (f32x4)0.f;
  }

  for (int t = 0; t < 32; ++t) {
    const int l0 = t << 6, cur = t & 1, nxt = cur ^ 1;
    const bool more = (t < 31);
    // early mask loads for THIS tile (32 rows x 8 chunks per wave; 4 chunks/lane)
    bf16x8 mk[4];
    #pragma unroll
    for (int j = 0; j < 4; j++) {
      int q = (j << 6) + lane;
      mk[j] = *(const bf16x8*)(mb + (size_t)((w << 5) + (q >> 3)) * 2048 + l0 + ((q & 7) << 3));
    }
    bf16x8 vreg, ypreg;
    if (more) {
      const int l1 = l0 + 64;
      vreg = *(const bf16x8*)(vb + ((size_t)(tid >> 3) << 11) + l1 + ((tid & 7) << 3));
      if (tid < 32) ypreg = *(const bf16x8*)(yb + ((size_t)(tid >> 3) << 11) + l1 + ((tid & 7) << 3));
      #pragma unroll
      for (int j = 0; j < 4; j++) {
        int c = (j << 9) + tid;
        gl2l(kb + (size_t)(l1 + (c >> 5)) * 256 + ((c & 31) << 3), kq[nxt] + ((c - lane) << 3));
      }
    }
    // QK^T: K-fragment reads shared across both row-fragments
    f32x4 Cs[2][4];
    #pragma unroll
    for (int lb = 0; lb < 4; lb++) { Cs[0][lb] = (f32x4)0.f; Cs[1][lb] = (f32x4)0.f; }
    #pragma unroll
    for (int lb = 0; lb < 4; lb++) {
      const int kr = (lb << 4) + li;
      #pragma unroll
      for (int s = 0; s < 8; s++) {
        bf16x8 bk = *(const bf16x8*)(kq[cur] + kr * 256 + ((((s << 2) + g) ^ (kr & 7)) << 3));
        Cs[0][lb] = __builtin_amdgcn_mfma_f32_16x16x32_bf16(aq[0][s], bk, Cs[0][lb], 0, 0, 0);
        Cs[1][lb] = __builtin_amdgcn_mfma_f32_16x16x32_bf16(aq[1][s], bk, Cs[1][lb], 0, 0, 0);
      }
    }
    // exp (UNMASKED) + se + pT store
    #pragma unroll
    for (int rf = 0; rf < 2; rf++) {
      #pragma unroll
      for (int lb = 0; lb < 4; lb++) {
        #pragma unroll
        for (int r = 0; r < 4; r++) {
          const int row = (w << 5) + (rf << 4) + (g << 2) + r;
          float e = __expf(Cs[rf][lb][r] * SCALE);
          se[rf][r] += e;
          pT[row * 72 + (lb << 4) + li] = (__bf16)e;
        }
      }
    }
    asm volatile("s_waitcnt lgkmcnt(0)" ::: "memory");
    __builtin_amdgcn_sched_barrier(0);
    // mask + em store + pT write-back + te
    #pragma unroll
    for (int j = 0; j < 4; j++) {
      const int q = (j << 6) + lane;
      const int row = q >> 3, ch = q & 7;      // row 0..31 within wave slice
      bf16x8 pv = *(const bf16x8*)(pT + ((w << 5) + row) * 72 + (ch << 3));
      bf16x8 emv;
      float tp = 0.f;
      #pragma unroll
      for (int i = 0; i < 8; i++) {
        float p = (float)pv[i] * (float)mk[j][i];
        emv[i] = (__bf16)p;
        tp += p;
      }
      tp += __shfl_xor(tp, 1);
      tp += __shfl_xor(tp, 2);
      tp += __shfl_xor(tp, 4);
      te[j] += tp;
      *(bf16x8*)(em_g + ((size_t)bh << 22) + ((size_t)(n0 + (w << 5) + row) << 11) + l0 + (ch << 3)) = emv;
      *(bf16x8*)(pT + ((w << 5) + row) * 72 + (ch << 3)) = emv;
    }
    asm volatile("s_waitcnt lgkmcnt(0)" ::: "memory");
    __builtin_amdgcn_sched_barrier(0);
    // PV + attn@yp (pT now masked); kc = l-halves of the 64-wide tile
    #pragma unroll
    for (int kc = 0; kc < 2; kc++) {
      bf16x8 vv[4];
      #pragma unroll
      for (int cb = 0; cb < 4; cb++)
        vv[cb] = *(const bf16x8*)(vt[cur] + ((cb << 4) + li) * 72 + (kc << 5) + (g << 3));
      bf16x8 yy = *(const bf16x8*)(ypl[cur] + li * 72 + (kc << 5) + (g << 3));
      #pragma unroll
      for (int rf = 0; rf < 2; rf++) {
        bf16x8 pa = *(const bf16x8*)(pT + ((w << 5) + (rf << 4) + li) * 72 + (kc << 5) + (g << 3));
        #pragma unroll
        for (int cb = 0; cb < 4; cb++)
          accv[rf][cb] = __builtin_amdgcn_mfma_f32_16x16x32_bf16(pa, vv[cb], accv[rf][cb], 0, 0, 0);
        accp[rf] = __builtin_amdgcn_mfma_f32_16x16x32_bf16(pa, yy, accp[rf], 0, 0, 0);
      }
    }
    if (more) {
      *(bf16x8*)(vt[nxt] + (tid >> 3) * 72 + ((tid & 7) << 3)) = vreg;
      if (tid < 32) *(bf16x8*)(ypl[nxt] + (tid >> 3) * 72 + ((tid & 7) << 3)) = ypreg;
    }
    __syncthreads();
  }

  // te -> te_s (rows (j<<3)+(lane>>3) of the wave slice; all 8 chunk-lanes hold full sum)
  if ((lane & 7) == 0) {
    #pragma unroll
    for (int j = 0; j < 4; j++)
      te_s[(w << 5) + (j << 3) + (lane >> 3)] = te[j];
  }
  asm volatile("s_waitcnt lgkmcnt(0)" ::: "memory");
  __builtin_amdgcn_sched_barrier(0);
  __syncthreads();

  // epilogue: reduce se, combine with te, write dinv + avz
  #pragma unroll
  for (int rf = 0; rf < 2; rf++) {
    #pragma unroll
    for (int r = 0; r < 4; r++) {
      float s = se[rf][r];
      #pragma unroll
      for (int o = 1; o < 16; o <<= 1) s += __shfl_xor(s, o);
      float tt = te_s[(w << 5) + (rf << 4) + (g << 2) + r];
      float dinv = 1.f / (tt + 1e-8f * s);
      const int n = n0 + (w << 5) + (rf << 4) + (g << 2) + r;
      if (li == 0) dinv_g[((size_t)bh << 11) + n] = dinv;
      #pragma unroll
      for (int cb = 0; cb < 4; cb++)
        avz[((size_t)b * Nn + n) * 1088 + (h << 6) + (cb << 4) + li] = (__bf16)(accv[rf][cb][r] * dinv);
      if (li < 4) {
        float z = accp[rf][r] * dinv - xp[(((size_t)b * Nn + n) << 2) + li];
        avz[((size_t)b * Nn + n) * 1088 + 1024 + (h << 2) + li] = (__bf16)z;
      }
    }
  }
}

// ---------------- merged finalize + output projection ----------------
__launch_bounds__(256)
__global__ void fin_proj(const __bf16* __restrict__ A, const __bf16* __restrict__ W,
                         const float* __restrict__ bias1, const float* __restrict__ bias2,
                         float* __restrict__ out,
                         const __bf16* __restrict__ em_g, const float* __restrict__ dinv_g,
                         float* __restrict__ attn_out,
                         const float* __restrict__ xp, float* __restrict__ xp_out) {
  constexpr int N = 1024, K = 1088;
  __shared__ __align__(16) __bf16 As[2][128 * 32];
  __shared__ __align__(16) __bf16 Bs[2][64 * 32];
  const int tid = threadIdx.x;
  if (blockIdx.x >= 512) {
    const int sbid = blockIdx.x - 512;
    if (sbid < 64) {
      int idx = sbid * 256 + tid;
      ((float4*)xp_out)[idx] = ((const float4*)xp)[idx];
    }
    for (size_t i8 = sbid * 256ul + tid; i8 < 16777216ul; i8 += 524288ul) {
      bf16x8 v = ((const bf16x8*)em_g)[i8];
      float dv = dinv_g[i8 >> 8];
      float4 o0, o1;
      o0.x = (float)v[0] * dv; o0.y = (float)v[1] * dv; o0.z = (float)v[2] * dv; o0.w = (float)v[3] * dv;
      o1.x = (float)v[4] * dv; o1.y = (float)v[5] * dv; o1.z = (float)v[6] * dv; o1.w = (float)v[7] * dv;
      ((float4*)attn_out)[i8 * 2]     = o0;
      ((float4*)attn_out)[i8 * 2 + 1] = o1;
    }
    return;
  }
  const int w = tid >> 6, lane = tid & 63, g = lane >> 4, li = lane & 15;
  const int bt = blockIdx.x >> 4;
  const int m0 = bt << 7, n0 = (blockIdx.x & 15) << 6;
  const int wm = (w >> 1) << 6, wn = (w & 1) << 5;
  f32x4 acc[4][2];
  #pragma unroll
  for (int i = 0; i < 4; i++) { acc[i][0] = (f32x4)0.f; acc[i][1] = (f32x4)0.f; }
  auto stage = [&](int buf, int kt) {
    const int col0 = kt << 5;
    #pragma unroll
    for (int j = 0; j < 2; j++) {
      int c = (j << 8) + tid;
      int row = c >> 2, sl = c & 3;
      int col = col0 + ((sl ^ (row & 3)) << 3);
      gl2l(A + (size_t)(m0 + row) * K + col, As[buf] + ((c - lane) << 3));
    }
    {
      int c = tid;
      int row = c >> 2, sl = c & 3;
      int col = col0 + ((sl ^ (row & 3)) << 3);
      gl2l(W + (size_t)(n0 + row) * K + col, Bs[buf] + ((c - lane) << 3));
    }
  };
  const int NT = K >> 5;   // 34
  stage(0, 0);
  for (int kt = 0; kt < NT; kt++) {
    const int cur = kt & 1;
    if (kt + 1 < NT) {
      stage(cur ^ 1, kt + 1);
      asm volatile("s_waitcnt vmcnt(3)" ::: "memory");
    } else {
      asm volatile("s_waitcnt vmcnt(0)" ::: "memory");
    }
    __builtin_amdgcn_s_barrier();
    __builtin_amdgcn_sched_barrier(0);
    bf16x8 af[4], bw[2];
    #pragma unroll
    for (int i = 0; i < 4; i++) {
      int ra = wm + (i << 4) + li;
      af[i] = *(const bf16x8*)(As[cur] + ra * 32 + ((g ^ (ra & 3)) << 3));
    }
    #pragma unroll
    for (int j = 0; j < 2; j++) {
      int rb = wn + (j << 4) + li;
      bw[j] = *(const bf16x8*)(Bs[cur] + rb * 32 + ((g ^ (rb & 3)) << 3));
    }
    #pragma unroll
    for (int i = 0; i < 4; i++)
      #pragma unroll
      for (int j = 0; j < 2; j++)
        acc[i][j] = __builtin_amdgcn_mfma_f32_16x16x32_bf16(af[i], bw[j], acc[i][j], 0, 0, 0);
    asm volatile("s_waitcnt lgkmcnt(0)" ::: "memory");
    __builtin_amdgcn_sched_barrier(0);
    __builtin_amdgcn_s_barrier();
  }
  #pragma unroll
  for (int j = 0; j < 2; j++) {
    int n = n0 + wn + (j << 4) + li;
    float bias = bias1[n] + bias2[n];
    #pragma unroll
    for (int i = 0; i < 4; i++) {
      #pragma unroll
      for (int r = 0; r < 4; r++) {
        int m = m0 + wm + (i << 4) + (g << 2) + r;
        out[(size_t)m * N + n] = acc[i][j][r] + bias;
      }
    }
  }
}

// ---------------- host ----------------
extern "C" void kernel_launch(void* const* d_in, const int* in_sizes, int n_in,
                              void* d_out, int out_size, void* d_ws, size_t ws_size,
                              hipStream_t stream) {
  (void)in_sizes; (void)n_in; (void)out_size; (void)ws_size;
  const float* x       = (const float*)d_in[0];
  const float* xp      = (const float*)d_in[1];
  const float* y       = (const float*)d_in[2];
  const float* yp      = (const float*)d_in[3];
  const float* mask    = (const float*)d_in[4];
  const float* p_w1    = (const float*)d_in[5];
  const float* p_b1    = (const float*)d_in[6];
  const float* p_w2    = (const float*)d_in[7];
  const float* p_b2    = (const float*)d_in[8];
  const float* q_ln_g  = (const float*)d_in[9];
  const float* q_ln_b  = (const float*)d_in[10];
  const float* q_m1_w1 = (const float*)d_in[11];
  const float* q_m1_b1 = (const float*)d_in[12];
  const float* q_m1_w2 = (const float*)d_in[13];
  const float* q_m1_b2 = (const float*)d_in[14];
  const float* q_m2_w1 = (const float*)d_in[15];
  const float* q_m2_b1 = (const float*)d_in[16];
  const float* q_m2_w2 = (const float*)d_in[17];
  const float* q_m2_b2 = (const float*)d_in[18];
  const float* k_ln_g  = (const float*)d_in[19];
  const float* k_ln_b  = (const float*)d_in[20];
  const float* k_m1_w1 = (const float*)d_in[21];
  const float* k_m1_b1 = (const float*)d_in[22];
  const float* k_m1_w2 = (const float*)d_in[23];
  const float* k_m1_b2 = (const float*)d_in[24];
  const float* v_ln_g  = (const float*)d_in[25];
  const float* v_ln_b  = (const float*)d_in[26];
  const float* v_w     = (const float*)d_in[27];
  const float* v_b     = (const float*)d_in[28];
  const float* proj1_w = (const float*)d_in[29];
  const float* proj1_b = (const float*)d_in[30];
  const float* proj2_w = (const float*)d_in[31];
  const float* proj2_b = (const float*)d_in[32];

  char* ws = (char*)d_ws;
  __bf16* xn    = (__bf16*)(ws + OFF_XN);
  __bf16* ynk   = (__bf16*)(ws + OFF_YNK);
  __bf16* ynv   = (__bf16*)(ws + OFF_YNV);
  __bf16* h12   = (__bf16*)(ws + OFF_H12);
  __bf16* h3    = (__bf16*)(ws + OFF_H3);
  __bf16* x1    = (__bf16*)(ws + OFF_X1);
  __bf16* x2    = (__bf16*)(ws + OFF_X2);
  __bf16* y1    = (__bf16*)(ws + OFF_Y1);
  __bf16* q_ws  = (__bf16*)(ws + OFF_QWS);
  __bf16* k_ws  = (__bf16*)(ws + OFF_KWS);
  __bf16* vT_ws = (__bf16*)(ws + OFF_VWS);
  float*  dinv  = (float*)(ws + OFF_DNV);
  __bf16* ypT   = (__bf16*)(ws + OFF_YPT);
  __bf16* mskb  = (__bf16*)(ws + OFF_MSK);
  __bf16* avz   = (__bf16*)(ws + OFF_AVZ);
  __bf16* w1122 = (__bf16*)(ws + OFF_W1122);
  __bf16* w12   = (__bf16*)(ws + OFF_W12);
  __bf16* w22   = (__bf16*)(ws + OFF_W22);
  __bf16* wk1   = (__bf16*)(ws + OFF_WK1);
  __bf16* wk2   = (__bf16*)(ws + OFF_WK2);
  __bf16* wv    = (__bf16*)(ws + OFF_WV);
  __bf16* wp    = (__bf16*)(ws + OFF_WP);
  __bf16* em    = (__bf16*)(ws + OFF_EM);

  float* out0     = (float*)d_out;
  float* attn_out = out0 + (size_t)4194304;
  float* xp_out   = out0 + (size_t)138412032;

  // 1. merged prep (weights + proj + mask bf16 + ypT) + layernorms
  prep_ln<<<26704, 256, 0, stream>>>(q_m1_w1, q_m2_w1, q_m1_w2, q_m2_w2, k_m1_w1, k_m1_w2, v_w,
                                     w1122, w1122 + 2097152, w12, w22, wk1, wk2, wv,
                                     proj1_w, proj2_w, wp, mask, mskb, yp, ypT,
                                     x, y, q_ln_g, q_ln_b, k_ln_g, k_ln_b, v_ln_g, v_ln_b,
                                     xn, ynk, ynv);
  // 2. mlp stage 1 (4-phase interleaved pipeline)
  gemm_mlp1<<<512, 512, 0, stream>>>(xn, ynk, w1122, wk1, q_m1_b1, q_m2_b1, k_m1_b1, h12, h3);
  // 3. mlp stage 2 + V projection
  gemm_mlp2<<<256, 512, 0, stream>>>(h12, h3, ynv, w12, w22, wk2, wv,
                                     q_m1_b2, q_m2_b2, k_m1_b2, v_b, x1, x2, y1, vT_ws);
  // 4. q/k assembly
  build_qk<<<4096, 256, 0, stream>>>(x1, x2, xp, y1, yp, p_w1, p_b1, p_w2, p_b2, q_ws, k_ws);
  // 5. fused flash attention (KVBLK=64, 32 iterations)
  attn_fused<<<256, 512, 0, stream>>>(q_ws, k_ws, vT_ws, ypT, mskb, xp, em, dinv, avz);
  // 6. merged finalize (attn = em*dinv + xp passthrough) + output projection
  fin_proj<<<2560, 256, 0, stream>>>(avz, wp, proj1_b, proj2_b, out0,
                                     em, dinv, attn_out, xp, xp_out);
}

// Round 12
// 593.087 us; speedup vs baseline: 1.2373x; 1.0508x over previous
//
#include <hip/hip_runtime.h>
#include <math.h>
#include <stdint.h>

#define DEV static __device__ __forceinline__

typedef __bf16 bf16x8 __attribute__((ext_vector_type(8)));
typedef __bf16 bf16x4v __attribute__((ext_vector_type(4)));
typedef float f32x4 __attribute__((ext_vector_type(4)));

// problem dims
constexpr int Nn = 2048, Ll = 2048, Ee = 1024, Hh = 16;
constexpr float SCALE = 0.0625f;   // (4C)^-0.5 = 1/16

// ---------------- workspace layout (bytes) ----------------
constexpr size_t OFF_XN   = 0;                    // [4096][1024] bf16
constexpr size_t OFF_YNK  = 8388608;
constexpr size_t OFF_YNV  = 16777216;
constexpr size_t OFF_H12  = 25165824;             // [4096][4096] bf16
constexpr size_t OFF_H3   = 58720256;             // [4096][2048] bf16
constexpr size_t OFF_X1   = 75497472;             // [4096][1024] bf16
constexpr size_t OFF_X2   = 83886080;
constexpr size_t OFF_Y1   = 92274688;
constexpr size_t OFF_QWS  = 100663296;            // [B][H][N][256] bf16, pre-swizzled
constexpr size_t OFF_KWS  = 134217728;            // [B][H][L][256] bf16, pre-swizzled
constexpr size_t OFF_VWS  = 167772160;            // vT: [B*H][64][2048] bf16
constexpr size_t OFF_DNV  = 176160768;            // f32 [B*H*N]
constexpr size_t OFF_YPT  = 176422912;            // ypT [B][4][2048] bf16
constexpr size_t OFF_MSK  = 176685056;            // mask bf16 [2048][2048]
constexpr size_t OFF_AVZ  = 185073664;            // [4096][1088] bf16
constexpr size_t OFF_W1122= 193986560;            // [4096][1024] bf16 (w11 ; w21)
constexpr size_t OFF_W12  = 202375168;
constexpr size_t OFF_W22  = 206569472;
constexpr size_t OFF_WK1  = 210763776;
constexpr size_t OFF_WK2  = 214958080;
constexpr size_t OFF_WV   = 219152384;
constexpr size_t OFF_WP   = 221249536;            // [1024][1088] bf16
constexpr size_t OFF_EM   = 223477760;            // em bf16, 268 MB

DEV void gl2l(const void* g, void* l) {
  __builtin_amdgcn_global_load_lds((const __attribute__((address_space(1))) void*)g,
                                   (__attribute__((address_space(3))) void*)l, 16, 0, 0);
}

// exact-erf GELU via Abramowitz-Stegun 7.1.26 (|eps|<1.5e-7, way below bf16)
DEV float gelu_f(float v) {
  float x = v * 0.70710678118654752f;
  float ax = fabsf(x);
  float t = 1.f / fmaf(0.3275911f, ax, 1.f);
  float y = t * fmaf(t, fmaf(t, fmaf(t, fmaf(t, 1.061405429f, -1.453152027f),
                                     1.421413741f), -0.284496736f), 0.254829592f);
  float er = 1.f - y * __expf(-x * x);
  er = (x < 0.f) ? -er : er;
  return 0.5f * v * (1.f + er);
}

// ---------------- merged prep (weights + proj + mask + ypT) + LayerNorms ----------------
__launch_bounds__(256)
__global__ void prep_ln(const float* __restrict__ s0, const float* __restrict__ s1,
                        const float* __restrict__ s2, const float* __restrict__ s3,
                        const float* __restrict__ s4, const float* __restrict__ s5,
                        const float* __restrict__ s6,
                        __bf16* __restrict__ d0, __bf16* __restrict__ d1,
                        __bf16* __restrict__ d2, __bf16* __restrict__ d3,
                        __bf16* __restrict__ d4, __bf16* __restrict__ d5,
                        __bf16* __restrict__ d6,
                        const float* __restrict__ pw1, const float* __restrict__ pw2,
                        __bf16* __restrict__ wp,
                        const float* __restrict__ mask, __bf16* __restrict__ mb,
                        const float* __restrict__ yp, __bf16* __restrict__ ypT,
                        const float* __restrict__ x, const float* __restrict__ y,
                        const float* __restrict__ qg, const float* __restrict__ qb,
                        const float* __restrict__ kg, const float* __restrict__ kb,
                        const float* __restrict__ vg, const float* __restrict__ vb,
                        __bf16* __restrict__ xn, __bf16* __restrict__ ynk,
                        __bf16* __restrict__ ynv) {
  const int tid = threadIdx.x;
  if (blockIdx.x >= 18512) {
    const int t = blockIdx.x - 18512;
    const bool isx = t < 4096;
    const int row = isx ? t : t - 4096;
    const float* src = (isx ? x : y) + (size_t)row * Ee;
    const float4 v = ((const float4*)src)[tid];
    float s = v.x + v.y + v.z + v.w;
    float q = v.x*v.x + v.y*v.y + v.z*v.z + v.w*v.w;
    #pragma unroll
    for (int o = 32; o > 0; o >>= 1) { s += __shfl_down(s, o); q += __shfl_down(q, o); }
    __shared__ float ls[4], lq[4];
    if ((tid & 63) == 0) { ls[tid >> 6] = s; lq[tid >> 6] = q; }
    __syncthreads();
    s = ls[0] + ls[1] + ls[2] + ls[3];
    q = lq[0] + lq[1] + lq[2] + lq[3];
    const float mu = s * (1.f / Ee);
    const float rstd = rsqrtf(q * (1.f / Ee) - mu * mu + 1e-5f);
    const int e0 = tid << 2;
    float h0 = (v.x - mu) * rstd, h1 = (v.y - mu) * rstd,
          h2 = (v.z - mu) * rstd, h3 = (v.w - mu) * rstd;
    if (isx) {
      bf16x4v o;
      o[0] = (__bf16)(h0 * qg[e0]   + qb[e0]);
      o[1] = (__bf16)(h1 * qg[e0+1] + qb[e0+1]);
      o[2] = (__bf16)(h2 * qg[e0+2] + qb[e0+2]);
      o[3] = (__bf16)(h3 * qg[e0+3] + qb[e0+3]);
      *(bf16x4v*)(xn + (size_t)row * Ee + e0) = o;
    } else {
      bf16x4v ok, ov;
      ok[0] = (__bf16)(h0 * kg[e0]   + kb[e0]);
      ok[1] = (__bf16)(h1 * kg[e0+1] + kb[e0+1]);
      ok[2] = (__bf16)(h2 * kg[e0+2] + kb[e0+2]);
      ok[3] = (__bf16)(h3 * kg[e0+3] + kb[e0+3]);
      ov[0] = (__bf16)(h0 * vg[e0]   + vb[e0]);
      ov[1] = (__bf16)(h1 * vg[e0+1] + vb[e0+1]);
      ov[2] = (__bf16)(h2 * vg[e0+2] + vb[e0+2]);
      ov[3] = (__bf16)(h3 * vg[e0+3] + vb[e0+3]);
      *(bf16x4v*)(ynk + (size_t)row * Ee + e0) = ok;
      *(bf16x4v*)(ynv + (size_t)row * Ee + e0) = ov;
    }
    return;
  }
  int u = blockIdx.x * 256 + tid;
  if (u < 3407872) {
    int seg = u >> 19, r = u & 524287;
    const float* s; __bf16* d;
    if      (seg == 0) { s = s0; d = d0; }
    else if (seg == 1) { s = s1; d = d1; }
    else if (seg == 2) { s = s2; d = d2; }
    else if (seg == 3) { s = s3; d = d3; }
    else if (seg == 4) { s = s4; d = d4; }
    else if (seg == 5) { s = s5; d = d5; }
    else               { s = s6; d = d6; }
    float4 v = ((const float4*)s)[r];
    bf16x4v o; o[0]=(__bf16)v.x; o[1]=(__bf16)v.y; o[2]=(__bf16)v.z; o[3]=(__bf16)v.w;
    ((bf16x4v*)d)[r] = o;
  } else if (u < 3686400) {
    int p = u - 3407872;
    int row = p / 272, c4 = p - row * 272;
    float4 v = (c4 < 256) ? ((const float4*)pw1)[row * 256 + c4]
                          : ((const float4*)pw2)[row * 16 + (c4 - 256)];
    bf16x4v o; o[0]=(__bf16)v.x; o[1]=(__bf16)v.y; o[2]=(__bf16)v.z; o[3]=(__bf16)v.w;
    *(bf16x4v*)(wp + (size_t)row * 1088 + (c4 << 2)) = o;
  } else if (u < 4734976) {
    int q = u - 3686400;
    float4 v = ((const float4*)mask)[q];
    bf16x4v o; o[0]=(__bf16)v.x; o[1]=(__bf16)v.y; o[2]=(__bf16)v.z; o[3]=(__bf16)v.w;
    ((bf16x4v*)mb)[q] = o;
  } else {
    int t0 = (u - 4734976) << 2;
    #pragma unroll
    for (int k = 0; k < 4; k++) {
      int i = t0 + k;
      int b = i >> 13, d = (i >> 11) & 3, l = i & 2047;
      ypT[i] = (__bf16)yp[(((size_t)b << 11) + l) * 4 + d];
    }
  }
}

// ============ 4-phase interleaved GEMM pipeline (T3+T4+T5), BK=64, piece-major LDS ============
#define STAGE_A(BM_, A_, lda_, kt_, kh_, buf_)                                        \
  _Pragma("unroll")                                                                   \
  for (int jj = 0; jj < (BM_) / 128; jj++) {                                          \
    int c = (jj << 9) + tid;                                                          \
    int row_ = c >> 2, j_ = c & 3;                                                    \
    int col_ = ((kt_) << 6) + ((kh_) << 5) + ((j_ ^ (row_ & 3)) << 3);                \
    gl2l(A_ + (size_t)(m0 + row_) * (lda_) + col_,                                    \
         As + ((((buf_) << 1) + (kh_)) * ((BM_) * 32)) + (c << 3));                   \
  }

#define STAGE_B(W_, ldw_, kt_, kh_, buf_)                                             \
  _Pragma("unroll")                                                                   \
  for (int jj = 0; jj < 2; jj++) {                                                    \
    int c = (jj << 9) + tid;                                                          \
    int row_ = c >> 2, j_ = c & 3;                                                    \
    int col_ = ((kt_) << 6) + ((kh_) << 5) + ((j_ ^ (row_ & 3)) << 3);                \
    gl2l(W_ + (size_t)(n0 + row_) * (ldw_) + col_,                                    \
         Bs + ((((buf_) << 1) + (kh_)) * 8192) + (c << 3));                           \
  }

#define LOAD_A(BM_, buf_, ks_)                                                        \
  _Pragma("unroll")                                                                   \
  for (int i = 0; i < (BM_) / 32; i++) {                                              \
    int ra = wm + (i << 4) + li;                                                      \
    af[i] = *(const bf16x8*)(As + ((((buf_) << 1) + (ks_)) * ((BM_) * 32))            \
             + ra * 32 + ((g ^ (ra & 3)) << 3));                                      \
  }

#define LOAD_B(buf_, ks_, qn_)                                                        \
  _Pragma("unroll")                                                                   \
  for (int jj = 0; jj < 2; jj++) {                                                    \
    int rb = wn + ((qn_) << 5) + (jj << 4) + li;                                      \
    bw[jj] = *(const bf16x8*)(Bs + ((((buf_) << 1) + (ks_)) * 8192)                   \
             + rb * 32 + ((g ^ (rb & 3)) << 3));                                      \
  }

#define MFMA_Q(BM_, qn_)                                                              \
  __builtin_amdgcn_s_setprio(1);                                                      \
  _Pragma("unroll")                                                                   \
  for (int i = 0; i < (BM_) / 32; i++) {                                              \
    acc[i][((qn_) << 1)]     = __builtin_amdgcn_mfma_f32_16x16x32_bf16(af[i], bw[0], acc[i][((qn_) << 1)], 0, 0, 0);     \
    acc[i][((qn_) << 1) + 1] = __builtin_amdgcn_mfma_f32_16x16x32_bf16(af[i], bw[1], acc[i][((qn_) << 1) + 1], 0, 0, 0); \
  }                                                                                   \
  __builtin_amdgcn_s_setprio(0);

#define PH_SYNC                                                                       \
  __builtin_amdgcn_s_barrier();                                                       \
  asm volatile("s_waitcnt lgkmcnt(0)" ::: "memory");                                  \
  __builtin_amdgcn_sched_barrier(0);

#define PH_END __builtin_amdgcn_s_barrier();

#define GEMM_PIPE(BM_, A_, lda_, W_, ldw_, K_)                                        \
  const int w = tid >> 6, lane = tid & 63, g = lane >> 4, li = lane & 15;             \
  const int wm = (w >> 2) * ((BM_) / 2), wn = (w & 3) << 6;                           \
  constexpr int MI_ = (BM_) / 32;                                                     \
  constexpr int VMC = (BM_) / 128 + 2;                                                \
  f32x4 acc[MI_][4];                                                                  \
  _Pragma("unroll")                                                                   \
  for (int i = 0; i < MI_; i++)                                                       \
    _Pragma("unroll")                                                                 \
    for (int j = 0; j < 4; j++) acc[i][j] = (f32x4)0.f;                               \
  STAGE_A(BM_, A_, lda_, 0, 0, 0) STAGE_B(W_, ldw_, 0, 0, 0)                          \
  STAGE_A(BM_, A_, lda_, 0, 1, 0) STAGE_B(W_, ldw_, 0, 1, 0)                          \
  STAGE_A(BM_, A_, lda_, 1, 0, 1) STAGE_B(W_, ldw_, 1, 0, 1)                          \
  asm volatile("s_waitcnt vmcnt(%0)" :: "i"(VMC) : "memory");                         \
  __builtin_amdgcn_s_barrier();                                                       \
  const int NT = (K_) >> 6;                                                           \
  bf16x8 af[MI_], bw[2];                                                              \
  for (int t = 0; t < NT; t++) {                                                      \
    const int buf = t & 1, nbuf = buf ^ 1;                                            \
    const bool sB = (t + 1 < NT);                                                     \
    const bool sA = (t + 2 < NT);                                                     \
    LOAD_A(BM_, buf, 0) LOAD_B(buf, 0, 0)                                             \
    if (sB) { STAGE_A(BM_, A_, lda_, t + 1, 1, nbuf) }                                \
    PH_SYNC MFMA_Q(BM_, 0) PH_END                                                     \
    LOAD_B(buf, 0, 1)                                                                 \
    if (sB) {                                                                         \
      STAGE_B(W_, ldw_, t + 1, 1, nbuf)                                               \
      asm volatile("s_waitcnt vmcnt(%0)" :: "i"(VMC) : "memory");                     \
    } else {                                                                          \
      asm volatile("s_waitcnt vmcnt(0)" ::: "memory");                                \
    }                                                                                 \
    PH_SYNC MFMA_Q(BM_, 1) PH_END                                                     \
    LOAD_A(BM_, buf, 1) LOAD_B(buf, 1, 0)                                             \
    if (sA) { STAGE_A(BM_, A_, lda_, t + 2, 0, buf) }                                 \
    PH_SYNC MFMA_Q(BM_, 0) PH_END                                                     \
    LOAD_B(buf, 1, 1)                                                                 \
    if (sA) {                                                                         \
      STAGE_B(W_, ldw_, t + 2, 0, buf)                                                \
      asm volatile("s_waitcnt vmcnt(%0)" :: "i"(VMC) : "memory");                     \
    } else if (t + 1 < NT) {                                                          \
      asm volatile("s_waitcnt vmcnt(0)" ::: "memory");                                \
    }                                                                                 \
    PH_SYNC MFMA_Q(BM_, 1) PH_END                                                     \
  }

// Launch A: blocks 0..255: xn@w1122 (256x256, N=4096, gelu, split bias) -> h12
//           blocks 256..511: ynk@wk1 (128x256, N=2048, gelu) -> h3
__launch_bounds__(512, 2)
__global__ void gemm_mlp1(const __bf16* __restrict__ xn, const __bf16* __restrict__ ynk,
                          const __bf16* __restrict__ w1122, const __bf16* __restrict__ wk1,
                          const float* __restrict__ qb1, const float* __restrict__ qb2,
                          const float* __restrict__ kb1,
                          __bf16* __restrict__ h12, __bf16* __restrict__ h3) {
  __shared__ __align__(16) __bf16 As[2 * 2 * 256 * 32];
  __shared__ __align__(16) __bf16 Bs[2 * 2 * 256 * 32];
  const int tid = threadIdx.x, bid = blockIdx.x;
  if (bid < 256) {
    const int m0 = (bid >> 4) << 8, n0 = (bid & 15) << 8;
    GEMM_PIPE(256, xn, 1024, w1122, 1024, 1024)
    #pragma unroll
    for (int j = 0; j < 4; j++) {
      int n = n0 + wn + (j << 4) + li;
      float bias = (n < 2048) ? qb1[n] : qb2[n - 2048];
      #pragma unroll
      for (int i = 0; i < MI_; i++) {
        #pragma unroll
        for (int r = 0; r < 4; r++) {
          int m = m0 + wm + (i << 4) + (g << 2) + r;
          h12[(size_t)m * 4096 + n] = (__bf16)gelu_f(acc[i][j][r] + bias);
        }
      }
    }
  } else {
    const int rr = bid - 256;
    const int m0 = (rr >> 3) << 7, n0 = (rr & 7) << 8;
    GEMM_PIPE(128, ynk, 1024, wk1, 1024, 1024)
    #pragma unroll
    for (int j = 0; j < 4; j++) {
      int n = n0 + wn + (j << 4) + li;
      float bias = kb1[n];
      #pragma unroll
      for (int i = 0; i < MI_; i++) {
        #pragma unroll
        for (int r = 0; r < 4; r++) {
          int m = m0 + wm + (i << 4) + (g << 2) + r;
          h3[(size_t)m * 2048 + n] = (__bf16)gelu_f(acc[i][j][r] + bias);
        }
      }
    }
  }
}

// Launch B: seg0 x1=h1@w12, seg1 x2=h2@w22, seg2 y1=h3@wk2 (K=2048), seg3 vT=ynv@wv (K=1024)
__launch_bounds__(512, 2)
__global__ void gemm_mlp2(const __bf16* __restrict__ h12, const __bf16* __restrict__ h3,
                          const __bf16* __restrict__ ynv,
                          const __bf16* __restrict__ w12, const __bf16* __restrict__ w22,
                          const __bf16* __restrict__ wk2, const __bf16* __restrict__ wv,
                          const float* __restrict__ bx1, const float* __restrict__ bx2,
                          const float* __restrict__ by1, const float* __restrict__ bv,
                          __bf16* __restrict__ x1, __bf16* __restrict__ x2,
                          __bf16* __restrict__ y1, __bf16* __restrict__ vT) {
  __shared__ __align__(16) __bf16 As[2 * 2 * 256 * 32];
  __shared__ __align__(16) __bf16 Bs[2 * 2 * 256 * 32];
  const int tid = threadIdx.x, bid = blockIdx.x;
  const int seg = bid >> 6, rr = bid & 63;
  const int m0 = (rr >> 2) << 8, n0 = (rr & 3) << 8;
  const __bf16* A; const __bf16* W; const float* bias; __bf16* out; int lda, K;
  if      (seg == 0) { A = h12;        lda = 4096; W = w12; bias = bx1; out = x1; K = 2048; }
  else if (seg == 1) { A = h12 + 2048; lda = 4096; W = w22; bias = bx2; out = x2; K = 2048; }
  else if (seg == 2) { A = h3;         lda = 2048; W = wk2; bias = by1; out = y1; K = 2048; }
  else               { A = ynv;        lda = 1024; W = wv;  bias = bv;  out = vT; K = 1024; }
  GEMM_PIPE(256, A, lda, W, K, K)
  #pragma unroll
  for (int j = 0; j < 4; j++) {
    int n = n0 + wn + (j << 4) + li;
    float bs = bias[n];
    #pragma unroll
    for (int i = 0; i < MI_; i++) {
      #pragma unroll
      for (int r = 0; r < 4; r++) {
        int m = m0 + wm + (i << 4) + (g << 2) + r;
        float v = acc[i][j][r] + bs;
        if (seg == 3) {        // vT: [B*H][64][2048]
          int bb = m >> 11, l = m & 2047, hh = n >> 6, cc = n & 63;
          vT[(((size_t)(bb * Hh + hh) * 64 + cc) << 11) + l] = (__bf16)v;
        } else {
          out[(size_t)m * 1024 + n] = (__bf16)v;
        }
      }
    }
  }
}

// ---------------- merged build q + k (vectorized swizzled stores) ----------------
__launch_bounds__(256)
__global__ void build_qk(const __bf16* __restrict__ x1, const __bf16* __restrict__ x2,
                         const float* __restrict__ xp,
                         const __bf16* __restrict__ y1, const float* __restrict__ yp,
                         const float* __restrict__ pw1, const float* __restrict__ pb1,
                         const float* __restrict__ pw2, const float* __restrict__ pb2,
                         __bf16* __restrict__ q_ws, __bf16* __restrict__ k_ws) {
  const bool isq = blockIdx.x < 2048;
  const int bid = isq ? blockIdx.x : blockIdx.x - 2048;
  const int t = (bid << 1) + (threadIdx.x >> 7);
  const int tl = threadIdx.x & 127;
  const int b = t >> 11, n = t & 2047;
  const int hh = tl >> 3, ch = tl & 7;
  const int e0 = (hh << 6) + (ch << 3);
  const float* pos = isq ? xp : yp;
  const float p0 = pos[(size_t)t*4], p1 = pos[(size_t)t*4+1],
              p2 = pos[(size_t)t*4+2], p3 = pos[(size_t)t*4+3];
  bf16x8 o0, o1, o2, o3;
  if (isq) {
    bf16x8 v1 = *(const bf16x8*)(x1 + (size_t)t * Ee + e0);
    bf16x8 v2 = *(const bf16x8*)(x2 + (size_t)t * Ee + e0);
    #pragma unroll
    for (int sub = 0; sub < 8; sub++) {
      int e = e0 + sub;
      float a1 = pw1[e*4]*p0 + pw1[e*4+1]*p1 + pw1[e*4+2]*p2 + pw1[e*4+3]*p3 + pb1[e];
      float a2 = pw2[e*4]*p0 + pw2[e*4+1]*p1 + pw2[e*4+2]*p2 + pw2[e*4+3]*p3 + pb2[e];
      float s1, c1, s2, c2;
      __sincosf(a1, &s1, &c1); __sincosf(a2, &s2, &c2);
      float xv1 = (float)v1[sub], xv2 = (float)v2[sub];
      o0[sub] = (__bf16)(xv1 * c1); o1[sub] = (__bf16)(xv1 * s1);
      o2[sub] = (__bf16)(xv2 * c2); o3[sub] = (__bf16)(xv2 * s2);
    }
  } else {
    bf16x8 v1 = *(const bf16x8*)(y1 + (size_t)t * Ee + e0);
    #pragma unroll
    for (int sub = 0; sub < 8; sub++) {
      int e = e0 + sub;
      float a1 = pw1[e*4]*p0 + pw1[e*4+1]*p1 + pw1[e*4+2]*p2 + pw1[e*4+3]*p3;
      float a2 = pw2[e*4]*p0 + pw2[e*4+1]*p1 + pw2[e*4+2]*p2 + pw2[e*4+3]*p3;
      float s1, c1, s2, c2;
      __sincosf(a1, &s1, &c1); __sincosf(a2, &s2, &c2);
      float yv = (float)v1[sub];
      o0[sub] = (__bf16)(yv * c1); o1[sub] = (__bf16)(yv * s1);
      o2[sub] = (__bf16)c2;        o3[sub] = (__bf16)s2;
    }
  }
  const int k = n & 7, bc = ch ^ k;
  __bf16* base = (isq ? q_ws : k_ws) + ((((size_t)b * Hh + hh) * Nn + n) << 8);
  *(bf16x8*)(base + ((bc          ) << 3)) = o0;
  *(bf16x8*)(base + (((8  ^ k) ^ ch) << 3)) = o1;
  *(bf16x8*)(base + (((16 ^ k) ^ ch) << 3)) = o2;
  *(bf16x8*)(base + (((24 ^ k) ^ ch) << 3)) = o3;
}

// ---------------- fused flash attention + in-kernel finalize, KVBLK=64 ----------------
// 256 q-rows/block, 8 waves x 32 rows, 32 KV iterations. After the KV loop each block
// finalizes its OWN 256x2048 slice: attn_out = em * dinv (em read back through L2/HBM,
// stream overlaps with other blocks' compute). xp passthrough spread over blocks.
__launch_bounds__(512, 1)
__global__ void attn_fused(const __bf16* __restrict__ q_ws, const __bf16* __restrict__ k_ws,
                           const __bf16* __restrict__ vT_ws, const __bf16* __restrict__ ypT_g,
                           const __bf16* __restrict__ mask_bf, const float* __restrict__ xp,
                           __bf16* __restrict__ em_g, float* __restrict__ dinv_g,
                           __bf16* __restrict__ avz, float* __restrict__ attn_out,
                           float* __restrict__ xp_out) {
  __shared__ __align__(16) __bf16 kq[2][64 * 256];   // 64 KB
  __shared__ __align__(16) __bf16 vt[2][64 * 72];    // 18 KB (padded rows)
  __shared__ __align__(16) __bf16 pT[256 * 72];      // 36 KB (padded rows)
  __shared__ __align__(16) __bf16 ypl[2][16 * 72];   // 4.5 KB
  __shared__ float te_s[256];                        // 1 KB (te, then dinv)
  const int tid = threadIdx.x, w = tid >> 6, lane = tid & 63, g = lane >> 4, li = lane & 15;
  const int logical = ((blockIdx.x & 7) << 5) + (blockIdx.x >> 3);  // XCD-chunked
  const int bh = logical >> 3, nt = logical & 7;
  const int b = bh >> 4, h = bh & 15;
  const int n0 = nt << 8;
  const __bf16* qb = q_ws + (((size_t)bh * Nn + n0) << 8);
  const __bf16* kb = k_ws + (((size_t)bh * Ll) << 8);
  const __bf16* vb = vT_ws + ((size_t)bh << 17);
  const __bf16* yb = ypT_g + ((size_t)b << 13);
  const __bf16* mb = mask_bf + ((size_t)n0 << 11);

  // xp passthrough: 16384 float4 over 256 blocks = 64 per block
  {
    int idx = (blockIdx.x << 6) + (tid & 63);
    if (tid < 64) ((float4*)xp_out)[idx] = ((const float4*)xp)[idx];
  }

  bf16x8 aq[2][8];
  #pragma unroll
  for (int rf = 0; rf < 2; rf++) {
    const int nloc = (w << 5) + (rf << 4) + li;
    #pragma unroll
    for (int s = 0; s < 8; s++)
      aq[rf][s] = *(const bf16x8*)(qb + ((size_t)nloc << 8) + ((((s << 2) + g) ^ (nloc & 7)) << 3));
  }
  for (int i = tid; i < 1728; i += 512) {
    int buf = i / 864, idx = i - buf * 864;
    ypl[buf][288 + idx] = (__bf16)0.f;
  }
  {
    const int vc = tid >> 3, vl = (tid & 7) << 3;
    bf16x8 vreg = *(const bf16x8*)(vb + ((size_t)vc << 11) + vl);
    bf16x8 ypreg;
    if (tid < 32) ypreg = *(const bf16x8*)(yb + ((size_t)(tid >> 3) << 11) + ((tid & 7) << 3));
    #pragma unroll
    for (int j = 0; j < 4; j++) {
      int c = (j << 9) + tid;
      gl2l(kb + (size_t)(c >> 5) * 256 + ((c & 31) << 3), kq[0] + ((c - lane) << 3));
    }
    *(bf16x8*)(vt[0] + vc * 72 + vl) = vreg;
    if (tid < 32) *(bf16x8*)(ypl[0] + (tid >> 3) * 72 + ((tid & 7) << 3)) = ypreg;
  }
  __syncthreads();

  float se[2][4];
  float te[4] = {0.f, 0.f, 0.f, 0.f};
  f32x4 accv[2][4], accp[2];
  #pragma unroll
  for (int rf = 0; rf < 2; rf++) {
    #pragma unroll
    for (int r = 0; r < 4; r++) se[rf][r] = 0.f;
    #pragma unroll
    for (int cb = 0; cb < 4; cb++) accv[rf][cb] = (f32x4)0.f;
    accp[rf] = (f32x4)0.f;
  }

  for (int t = 0; t < 32; ++t) {
    const int l0 = t << 6, cur = t & 1, nxt = cur ^ 1;
    const bool more = (t < 31);
    bf16x8 mk[4];
    #pragma unroll
    for (int j = 0; j < 4; j++) {
      int q = (j << 6) + lane;
      mk[j] = *(const bf16x8*)(mb + (size_t)((w << 5) + (q >> 3)) * 2048 + l0 + ((q & 7) << 3));
    }
    bf16x8 vreg, ypreg;
    if (more) {
      const int l1 = l0 + 64;
      vreg = *(const bf16x8*)(vb + ((size_t)(tid >> 3) << 11) + l1 + ((tid & 7) << 3));
      if (tid < 32) ypreg = *(const bf16x8*)(yb + ((size_t)(tid >> 3) << 11) + l1 + ((tid & 7) << 3));
      #pragma unroll
      for (int j = 0; j < 4; j++) {
        int c = (j << 9) + tid;
        gl2l(kb + (size_t)(l1 + (c >> 5)) * 256 + ((c & 31) << 3), kq[nxt] + ((c - lane) << 3));
      }
    }
    f32x4 Cs[2][4];
    #pragma unroll
    for (int lb = 0; lb < 4; lb++) { Cs[0][lb] = (f32x4)0.f; Cs[1][lb] = (f32x4)0.f; }
    #pragma unroll
    for (int lb = 0; lb < 4; lb++) {
      const int kr = (lb << 4) + li;
      #pragma unroll
      for (int s = 0; s < 8; s++) {
        bf16x8 bk = *(const bf16x8*)(kq[cur] + kr * 256 + ((((s << 2) + g) ^ (kr & 7)) << 3));
        Cs[0][lb] = __builtin_amdgcn_mfma_f32_16x16x32_bf16(aq[0][s], bk, Cs[0][lb], 0, 0, 0);
        Cs[1][lb] = __builtin_amdgcn_mfma_f32_16x16x32_bf16(aq[1][s], bk, Cs[1][lb], 0, 0, 0);
      }
    }
    #pragma unroll
    for (int rf = 0; rf < 2; rf++) {
      #pragma unroll
      for (int lb = 0; lb < 4; lb++) {
        #pragma unroll
        for (int r = 0; r < 4; r++) {
          const int row = (w << 5) + (rf << 4) + (g << 2) + r;
          float e = __expf(Cs[rf][lb][r] * SCALE);
          se[rf][r] += e;
          pT[row * 72 + (lb << 4) + li] = (__bf16)e;
        }
      }
    }
    asm volatile("s_waitcnt lgkmcnt(0)" ::: "memory");
    __builtin_amdgcn_sched_barrier(0);
    #pragma unroll
    for (int j = 0; j < 4; j++) {
      const int q = (j << 6) + lane;
      const int row = q >> 3, ch = q & 7;
      bf16x8 pv = *(const bf16x8*)(pT + ((w << 5) + row) * 72 + (ch << 3));
      bf16x8 emv;
      float tp = 0.f;
      #pragma unroll
      for (int i = 0; i < 8; i++) {
        float p = (float)pv[i] * (float)mk[j][i];
        emv[i] = (__bf16)p;
        tp += p;
      }
      tp += __shfl_xor(tp, 1);
      tp += __shfl_xor(tp, 2);
      tp += __shfl_xor(tp, 4);
      te[j] += tp;
      *(bf16x8*)(em_g + ((size_t)bh << 22) + ((size_t)(n0 + (w << 5) + row) << 11) + l0 + (ch << 3)) = emv;
      *(bf16x8*)(pT + ((w << 5) + row) * 72 + (ch << 3)) = emv;
    }
    asm volatile("s_waitcnt lgkmcnt(0)" ::: "memory");
    __builtin_amdgcn_sched_barrier(0);
    #pragma unroll
    for (int kc = 0; kc < 2; kc++) {
      bf16x8 vv[4];
      #pragma unroll
      for (int cb = 0; cb < 4; cb++)
        vv[cb] = *(const bf16x8*)(vt[cur] + ((cb << 4) + li) * 72 + (kc << 5) + (g << 3));
      bf16x8 yy = *(const bf16x8*)(ypl[cur] + li * 72 + (kc << 5) + (g << 3));
      #pragma unroll
      for (int rf = 0; rf < 2; rf++) {
        bf16x8 pa = *(const bf16x8*)(pT + ((w << 5) + (rf << 4) + li) * 72 + (kc << 5) + (g << 3));
        #pragma unroll
        for (int cb = 0; cb < 4; cb++)
          accv[rf][cb] = __builtin_amdgcn_mfma_f32_16x16x32_bf16(pa, vv[cb], accv[rf][cb], 0, 0, 0);
        accp[rf] = __builtin_amdgcn_mfma_f32_16x16x32_bf16(pa, yy, accp[rf], 0, 0, 0);
      }
    }
    if (more) {
      *(bf16x8*)(vt[nxt] + (tid >> 3) * 72 + ((tid & 7) << 3)) = vreg;
      if (tid < 32) *(bf16x8*)(ypl[nxt] + (tid >> 3) * 72 + ((tid & 7) << 3)) = ypreg;
    }
    __syncthreads();
  }

  // te -> te_s
  if ((lane & 7) == 0) {
    #pragma unroll
    for (int j = 0; j < 4; j++)
      te_s[(w << 5) + (j << 3) + (lane >> 3)] = te[j];
  }
  asm volatile("s_waitcnt lgkmcnt(0)" ::: "memory");
  __builtin_amdgcn_sched_barrier(0);
  __syncthreads();

  // epilogue: reduce se, combine with te, write dinv + avz; stash dinv in te_s
  #pragma unroll
  for (int rf = 0; rf < 2; rf++) {
    #pragma unroll
    for (int r = 0; r < 4; r++) {
      float s = se[rf][r];
      #pragma unroll
      for (int o = 1; o < 16; o <<= 1) s += __shfl_xor(s, o);
      float tt = te_s[(w << 5) + (rf << 4) + (g << 2) + r];
      float dinv = 1.f / (tt + 1e-8f * s);
      const int n = n0 + (w << 5) + (rf << 4) + (g << 2) + r;
      if (li == 0) {
        dinv_g[((size_t)bh << 11) + n] = dinv;
        te_s[(w << 5) + (rf << 4) + (g << 2) + r] = dinv;   // wave-private slot, reused below
      }
      #pragma unroll
      for (int cb = 0; cb < 4; cb++)
        avz[((size_t)b * Nn + n) * 1088 + (h << 6) + (cb << 4) + li] = (__bf16)(accv[rf][cb][r] * dinv);
      if (li < 4) {
        float z = accp[rf][r] * dinv - xp[(((size_t)b * Nn + n) << 2) + li];
        avz[((size_t)b * Nn + n) * 1088 + 1024 + (h << 2) + li] = (__bf16)z;
      }
    }
  }
  __syncthreads();

  // in-kernel finalize: stream this block's 256x2048 em slice -> attn_out f32
  const __bf16* em_base = em_g + ((size_t)bh << 22) + ((size_t)n0 << 11);
  float* ao_base = attn_out + ((size_t)bh << 22) + ((size_t)n0 << 11);
  for (int p = 0; p < 128; p++) {
    int c = (p << 9) + tid;            // chunk id: row = c>>8 (256 rows), ch = c&255
    int row = c >> 8, ch = c & 255;
    bf16x8 v = *(const bf16x8*)(em_base + ((size_t)row << 11) + (ch << 3));
    float dv = te_s[row];
    float4 o0, o1;
    o0.x = (float)v[0] * dv; o0.y = (float)v[1] * dv; o0.z = (float)v[2] * dv; o0.w = (float)v[3] * dv;
    o1.x = (float)v[4] * dv; o1.y = (float)v[5] * dv; o1.z = (float)v[6] * dv; o1.w = (float)v[7] * dv;
    float* dst = ao_base + ((size_t)row << 11) + (ch << 3);
    *(float4*)dst = o0;
    *(float4*)(dst + 4) = o1;
  }
}

// ---------------- output projection (standalone, 128x64 2-phase) ----------------
__launch_bounds__(256)
__global__ void gemm_proj(const __bf16* __restrict__ A, const __bf16* __restrict__ W,
                          const float* __restrict__ bias1, const float* __restrict__ bias2,
                          float* __restrict__ out) {
  constexpr int N = 1024, K = 1088;
  __shared__ __align__(16) __bf16 As[2][128 * 32];
  __shared__ __align__(16) __bf16 Bs[2][64 * 32];
  const int tid = threadIdx.x;
  const int w = tid >> 6, lane = tid & 63, g = lane >> 4, li = lane & 15;
  const int bt = blockIdx.x >> 4;
  const int m0 = bt << 7, n0 = (blockIdx.x & 15) << 6;
  const int wm = (w >> 1) << 6, wn = (w & 1) << 5;
  f32x4 acc[4][2];
  #pragma unroll
  for (int i = 0; i < 4; i++) { acc[i][0] = (f32x4)0.f; acc[i][1] = (f32x4)0.f; }
  auto stage = [&](int buf, int kt) {
    const int col0 = kt << 5;
    #pragma unroll
    for (int j = 0; j < 2; j++) {
      int c = (j << 8) + tid;
      int row = c >> 2, sl = c & 3;
      int col = col0 + ((sl ^ (row & 3)) << 3);
      gl2l(A + (size_t)(m0 + row) * K + col, As[buf] + ((c - lane) << 3));
    }
    {
      int c = tid;
      int row = c >> 2, sl = c & 3;
      int col = col0 + ((sl ^ (row & 3)) << 3);
      gl2l(W + (size_t)(n0 + row) * K + col, Bs[buf] + ((c - lane) << 3));
    }
  };
  const int NT = K >> 5;   // 34
  stage(0, 0);
  for (int kt = 0; kt < NT; kt++) {
    const int cur = kt & 1;
    if (kt + 1 < NT) {
      stage(cur ^ 1, kt + 1);
      asm volatile("s_waitcnt vmcnt(3)" ::: "memory");
    } else {
      asm volatile("s_waitcnt vmcnt(0)" ::: "memory");
    }
    __builtin_amdgcn_s_barrier();
    __builtin_amdgcn_sched_barrier(0);
    bf16x8 af[4], bw[2];
    #pragma unroll
    for (int i = 0; i < 4; i++) {
      int ra = wm + (i << 4) + li;
      af[i] = *(const bf16x8*)(As[cur] + ra * 32 + ((g ^ (ra & 3)) << 3));
    }
    #pragma unroll
    for (int j = 0; j < 2; j++) {
      int rb = wn + (j << 4) + li;
      bw[j] = *(const bf16x8*)(Bs[cur] + rb * 32 + ((g ^ (rb & 3)) << 3));
    }
    #pragma unroll
    for (int i = 0; i < 4; i++)
      #pragma unroll
      for (int j = 0; j < 2; j++)
        acc[i][j] = __builtin_amdgcn_mfma_f32_16x16x32_bf16(af[i], bw[j], acc[i][j], 0, 0, 0);
    asm volatile("s_waitcnt lgkmcnt(0)" ::: "memory");
    __builtin_amdgcn_sched_barrier(0);
    __builtin_amdgcn_s_barrier();
  }
  #pragma unroll
  for (int j = 0; j < 2; j++) {
    int n = n0 + wn + (j << 4) + li;
    float bias = bias1[n] + bias2[n];
    #pragma unroll
    for (int i = 0; i < 4; i++) {
      #pragma unroll
      for (int r = 0; r < 4; r++) {
        int m = m0 + wm + (i << 4) + (g << 2) + r;
        out[(size_t)m * N + n] = acc[i][j][r] + bias;
      }
    }
  }
}

// ---------------- host ----------------
extern "C" void kernel_launch(void* const* d_in, const int* in_sizes, int n_in,
                              void* d_out, int out_size, void* d_ws, size_t ws_size,
                              hipStream_t stream) {
  (void)in_sizes; (void)n_in; (void)out_size; (void)ws_size;
  const float* x       = (const float*)d_in[0];
  const float* xp      = (const float*)d_in[1];
  const float* y       = (const float*)d_in[2];
  const float* yp      = (const float*)d_in[3];
  const float* mask    = (const float*)d_in[4];
  const float* p_w1    = (const float*)d_in[5];
  const float* p_b1    = (const float*)d_in[6];
  const float* p_w2    = (const float*)d_in[7];
  const float* p_b2    = (const float*)d_in[8];
  const float* q_ln_g  = (const float*)d_in[9];
  const float* q_ln_b  = (const float*)d_in[10];
  const float* q_m1_w1 = (const float*)d_in[11];
  const float* q_m1_b1 = (const float*)d_in[12];
  const float* q_m1_w2 = (const float*)d_in[13];
  const float* q_m1_b2 = (const float*)d_in[14];
  const float* q_m2_w1 = (const float*)d_in[15];
  const float* q_m2_b1 = (const float*)d_in[16];
  const float* q_m2_w2 = (const float*)d_in[17];
  const float* q_m2_b2 = (const float*)d_in[18];
  const float* k_ln_g  = (const float*)d_in[19];
  const float* k_ln_b  = (const float*)d_in[20];
  const float* k_m1_w1 = (const float*)d_in[21];
  const float* k_m1_b1 = (const float*)d_in[22];
  const float* k_m1_w2 = (const float*)d_in[23];
  const float* k_m1_b2 = (const float*)d_in[24];
  const float* v_ln_g  = (const float*)d_in[25];
  const float* v_ln_b  = (const float*)d_in[26];
  const float* v_w     = (const float*)d_in[27];
  const float* v_b     = (const float*)d_in[28];
  const float* proj1_w = (const float*)d_in[29];
  const float* proj1_b = (const float*)d_in[30];
  const float* proj2_w = (const float*)d_in[31];
  const float* proj2_b = (const float*)d_in[32];

  char* ws = (char*)d_ws;
  __bf16* xn    = (__bf16*)(ws + OFF_XN);
  __bf16* ynk   = (__bf16*)(ws + OFF_YNK);
  __bf16* ynv   = (__bf16*)(ws + OFF_YNV);
  __bf16* h12   = (__bf16*)(ws + OFF_H12);
  __bf16* h3    = (__bf16*)(ws + OFF_H3);
  __bf16* x1    = (__bf16*)(ws + OFF_X1);
  __bf16* x2    = (__bf16*)(ws + OFF_X2);
  __bf16* y1    = (__bf16*)(ws + OFF_Y1);
  __bf16* q_ws  = (__bf16*)(ws + OFF_QWS);
  __bf16* k_ws  = (__bf16*)(ws + OFF_KWS);
  __bf16* vT_ws = (__bf16*)(ws + OFF_VWS);
  float*  dinv  = (float*)(ws + OFF_DNV);
  __bf16* ypT   = (__bf16*)(ws + OFF_YPT);
  __bf16* mskb  = (__bf16*)(ws + OFF_MSK);
  __bf16* avz   = (__bf16*)(ws + OFF_AVZ);
  __bf16* w1122 = (__bf16*)(ws + OFF_W1122);
  __bf16* w12   = (__bf16*)(ws + OFF_W12);
  __bf16* w22   = (__bf16*)(ws + OFF_W22);
  __bf16* wk1   = (__bf16*)(ws + OFF_WK1);
  __bf16* wk2   = (__bf16*)(ws + OFF_WK2);
  __bf16* wv    = (__bf16*)(ws + OFF_WV);
  __bf16* wp    = (__bf16*)(ws + OFF_WP);
  __bf16* em    = (__bf16*)(ws + OFF_EM);

  float* out0     = (float*)d_out;
  float* attn_out = out0 + (size_t)4194304;
  float* xp_out   = out0 + (size_t)138412032;

  // 1. merged prep (weights + proj + mask bf16 + ypT) + layernorms
  prep_ln<<<26704, 256, 0, stream>>>(q_m1_w1, q_m2_w1, q_m1_w2, q_m2_w2, k_m1_w1, k_m1_w2, v_w,
                                     w1122, w1122 + 2097152, w12, w22, wk1, wk2, wv,
                                     proj1_w, proj2_w, wp, mask, mskb, yp, ypT,
                                     x, y, q_ln_g, q_ln_b, k_ln_g, k_ln_b, v_ln_g, v_ln_b,
                                     xn, ynk, ynv);
  // 2. mlp stage 1
  gemm_mlp1<<<512, 512, 0, stream>>>(xn, ynk, w1122, wk1, q_m1_b1, q_m2_b1, k_m1_b1, h12, h3);
  // 3. mlp stage 2 + V projection
  gemm_mlp2<<<256, 512, 0, stream>>>(h12, h3, ynv, w12, w22, wk2, wv,
                                     q_m1_b2, q_m2_b2, k_m1_b2, v_b, x1, x2, y1, vT_ws);
  // 4. q/k assembly
  build_qk<<<4096, 256, 0, stream>>>(x1, x2, xp, y1, yp, p_w1, p_b1, p_w2, p_b2, q_ws, k_ws);
  // 5. fused flash attention + in-kernel finalize + xp passthrough
  attn_fused<<<256, 512, 0, stream>>>(q_ws, k_ws, vT_ws, ypT, mskb, xp, em, dinv, avz,
                                      attn_out, xp_out);
  // 6. output projection
  gemm_proj<<<512, 256, 0, stream>>>(avz, wp, proj1_b, proj2_b, out0);
}